// Round 5
// baseline (139.987 us; speedup 1.0000x reference)
//
#include <hip/hip_runtime.h>
#include <hip/hip_bf16.h>
#include <cstdint>
#include <math.h>

#define LSEQ 2048
#define BATCH 2
#define NHEAD 16
#define DHEAD 64
#define DMODEL 1024
#define ROWS (BATCH*LSEQ)

typedef __bf16 bf16x8 __attribute__((ext_vector_type(8)));
typedef float f32x4 __attribute__((ext_vector_type(4)));
typedef unsigned short u16;

#define GLD(lds_base, src_g) \
  __builtin_amdgcn_global_load_lds((const __attribute__((address_space(1))) void*)(src_g), \
                                   (__attribute__((address_space(3))) void*)(lds_base), 16, 0, 0)

__device__ __forceinline__ u16 f2bf(float f) {
  unsigned int u = __float_as_uint(f);
  u += 0x7fffu + ((u >> 16) & 1u);
  return (u16)(u >> 16);
}
__device__ __forceinline__ float bf2f(u16 u) {
  return __uint_as_float(((unsigned)u) << 16);
}

// ---------------- transpose + fp32->bf16 convert: out[c][r] = bf16(in[r][c]) ----
__global__ void k_transpose_cvt(const float* __restrict__ in, u16* __restrict__ out, int R, int C) {
  __shared__ float tile[32][33];
  int c0 = blockIdx.x * 32, r0 = blockIdx.y * 32;
  int tx = threadIdx.x, ty = threadIdx.y;
#pragma unroll
  for (int i = 0; i < 32; i += 8)
    tile[ty + i][tx] = in[(size_t)(r0 + ty + i) * C + (c0 + tx)];
  __syncthreads();
#pragma unroll
  for (int i = 0; i < 32; i += 8)
    out[(size_t)(c0 + ty + i) * R + (r0 + tx)] = f2bf(tile[tx][ty + i]);
}

// ---------------- u16 transpose per head: in [L][64] -> out [64][L] ------------
__global__ void k_transpose_u16(const u16* __restrict__ in, u16* __restrict__ out) {
  __shared__ u16 tile[32][33];
  int hd = blockIdx.z;
  int l0 = blockIdx.y * 32, d0 = blockIdx.x * 32;
  const u16* ip = in + (size_t)hd * LSEQ * DHEAD;
  u16* op = out + (size_t)hd * LSEQ * DHEAD;
  int tx = threadIdx.x, ty = threadIdx.y;
#pragma unroll
  for (int i = 0; i < 32; i += 8)
    tile[ty + i][tx] = ip[(size_t)(l0 + ty + i) * DHEAD + d0 + tx];
  __syncthreads();
#pragma unroll
  for (int i = 0; i < 32; i += 8)
    op[(size_t)(d0 + ty + i) * LSEQ + l0 + tx] = tile[tx][ty + i];
}

// ---------------- RoPE tables + segment bounds (fused) -------------------------
__global__ void k_rope_tables(float* __restrict__ cosb, float* __restrict__ sinb,
                              const int* __restrict__ seq, int* __restrict__ bnd) {
  if (blockIdx.x == 0 && threadIdx.x < BATCH * 5) {
    int b = threadIdx.x / 5, s = threadIdx.x % 5;
    const int* row = seq + b * LSEQ;
    int lo = 0, hi = LSEQ;
    while (lo < hi) { int mid = (lo + hi) >> 1; if (row[mid] < s) lo = mid + 1; else hi = mid; }
    bnd[b * 5 + s] = lo;
  }
  int idx = blockIdx.x * blockDim.x + threadIdx.x;
  if (idx >= LSEQ * 32) return;
  int l = idx >> 5, f = idx & 31;
  double inv = pow(10000.0, -(double)f / 32.0);
  float ang = (float)l * (float)inv;
  cosb[idx] = cosf(ang);
  sinb[idx] = sinf(ang);
}

// ---------------- LN1: h = bf16(layernorm(x, w, b)) ----------------------------
__global__ __launch_bounds__(256) void k_ln1(const float* __restrict__ x, const float* __restrict__ w,
                                             const float* __restrict__ bias, u16* __restrict__ h) {
  int row = blockIdx.x, t = threadIdx.x;
  const float4 xv = ((const float4*)(x + (size_t)row * DMODEL))[t];
  float s = xv.x + xv.y + xv.z + xv.w;
  float s2 = xv.x * xv.x + xv.y * xv.y + xv.z * xv.z + xv.w * xv.w;
#pragma unroll
  for (int m2 = 1; m2 < 64; m2 <<= 1) { s += __shfl_xor(s, m2); s2 += __shfl_xor(s2, m2); }
  __shared__ float rb[2][4];
  int wv = t >> 6;
  if ((t & 63) == 0) { rb[0][wv] = s; rb[1][wv] = s2; }
  __syncthreads();
  s  = rb[0][0] + rb[0][1] + rb[0][2] + rb[0][3];
  s2 = rb[1][0] + rb[1][1] + rb[1][2] + rb[1][3];
  float mu = s * (1.0f / DMODEL);
  float rs = rsqrtf(s2 * (1.0f / DMODEL) - mu * mu + 1e-5f);
  const float4 wv4 = ((const float4*)w)[t];
  const float4 bv4 = ((const float4*)bias)[t];
  ushort4 o;
  o.x = f2bf((xv.x - mu) * rs * wv4.x + bv4.x);
  o.y = f2bf((xv.y - mu) * rs * wv4.y + bv4.y);
  o.z = f2bf((xv.z - mu) * rs * wv4.z + bv4.z);
  o.w = f2bf((xv.w - mu) * rs * wv4.w + bv4.w);
  ((ushort4*)(h + (size_t)row * DMODEL))[t] = o;
}

// ================ 256x256 8-phase GEMM (T2+T3+T4+T5), C = A @ B^T ==============
// 512 thr = 8 waves (2M x 4N). BK=64, 2 K-tiles/iter, counted vmcnt(4) at p4/p8.
// Buffer stride 32768 B (256 rows x 64 cols x 2B); half stride 16384 B.
template<int OUTMODE>
__global__ __launch_bounds__(512, 2) void k_gemm256(const u16* __restrict__ A, const u16* __restrict__ B,
                                                    void* __restrict__ Cv, int M, int N, int K) {
  __shared__ __align__(16) u16 As[2][256 * 64];
  __shared__ __align__(16) u16 Bs[2][256 * 64];
  const int t = threadIdx.x, lane = t & 63, w = t >> 6;
  const int wr = w >> 2, wc = w & 3;
  const int nbx = N >> 8;
  const int nwg = nbx * (M >> 8);
  const int cpx = nwg >> 3;
  const int bid = blockIdx.x;
  const int sw = (bid & 7) * cpx + (bid >> 3);   // XCD swizzle (nwg % 8 == 0)
  const int m0 = (sw / nbx) * 256, n0 = (sw % nbx) * 256;
  const int NT = K >> 6;                          // 16 (even)
  const int cg16 = (lane >> 4) * 16;

  f32x4 acc[8][4] = {};
  const u16* Ap = A + (size_t)m0 * K;
  const u16* Bp = B + (size_t)n0 * K;
  // stage addressing: rr = t>>3 (row in half); inverse-swizzled source col
  const int rr0 = t >> 3;
  const int sz = ((t & 7) * 8) ^ ((rr0 & 7) << 3);   // u16 units; rr+64 keeps rr&7
  const u16* Asrc = Ap + (size_t)rr0 * K + sz;
  const u16* Bsrc = Bp + (size_t)rr0 * K + sz;

#define SA(buf, h, kt) do { \
    GLD((char*)As + (buf)*32768 + (h)*16384 + w*1024,        Asrc + (size_t)((h)*128      ) * K + (kt)*64); \
    GLD((char*)As + (buf)*32768 + (h)*16384 + 8192 + w*1024, Asrc + (size_t)((h)*128 + 64 ) * K + (kt)*64); \
  } while (0)
#define SB(buf, h, kt) do { \
    GLD((char*)Bs + (buf)*32768 + (h)*16384 + w*1024,        Bsrc + (size_t)((h)*128      ) * K + (kt)*64); \
    GLD((char*)Bs + (buf)*32768 + (h)*16384 + 8192 + w*1024, Bsrc + (size_t)((h)*128 + 64 ) * K + (kt)*64); \
  } while (0)

#define PHASE(asb, bsb, mh, nh, STG, WVM) do { \
    bf16x8 af_[4][2], bf_[2][2]; \
    _Pragma("unroll") for (int i2 = 0; i2 < 4; i2++) { \
      const int fi = (mh)*4 + i2; \
      const int rowA = (fi*2 + wr)*16 + (lane & 15); \
      const int sA = (rowA & 7) << 4; \
      _Pragma("unroll") for (int kk = 0; kk < 2; kk++) \
        af_[i2][kk] = *(const bf16x8*)((const char*)(asb) + (rowA & 127)*128 + ((kk*64 + cg16) ^ sA)); \
    } \
    _Pragma("unroll") for (int j2 = 0; j2 < 2; j2++) { \
      const int fj = (nh)*2 + j2; \
      const int rowB = (fj*4 + wc)*16 + (lane & 15); \
      const int sB = (rowB & 7) << 4; \
      _Pragma("unroll") for (int kk = 0; kk < 2; kk++) \
        bf_[j2][kk] = *(const bf16x8*)((const char*)(bsb) + (rowB & 127)*128 + ((kk*64 + cg16) ^ sB)); \
    } \
    STG; \
    __builtin_amdgcn_s_barrier(); \
    asm volatile("s_waitcnt lgkmcnt(0)" ::: "memory"); \
    __builtin_amdgcn_s_setprio(1); \
    _Pragma("unroll") for (int i2 = 0; i2 < 4; i2++) \
      _Pragma("unroll") for (int j2 = 0; j2 < 2; j2++) \
        _Pragma("unroll") for (int kk = 0; kk < 2; kk++) \
          acc[(mh)*4+i2][(nh)*2+j2] = __builtin_amdgcn_mfma_f32_16x16x32_bf16( \
              af_[i2][kk], bf_[j2][kk], acc[(mh)*4+i2][(nh)*2+j2], 0, 0, 0); \
    __builtin_amdgcn_s_setprio(0); \
    WVM; \
    __builtin_amdgcn_s_barrier(); \
  } while (0)

  // prologue: all of tile0 (buf0), then h0 halves of tile1 (buf1)
  SA(0, 0, 0); SB(0, 0, 0); SA(0, 1, 0); SB(0, 1, 0);
  SA(1, 0, 1); SB(1, 0, 1);
  asm volatile("s_waitcnt vmcnt(4)" ::: "memory");
  __builtin_amdgcn_s_barrier();

  // half-tile base pointers: quadrant (mh,nh) reads rows mh*128.. of buf
  const char* a0 = (const char*)As;
  const char* a0h = a0 + 16384;
  const char* a1 = (const char*)As + 32768;
  const char* a1h = a1 + 16384;
  const char* b0 = (const char*)Bs;
  const char* b0h = b0 + 16384;
  const char* b1 = (const char*)Bs + 32768;
  const char* b1h = b1 + 16384;
  const int NIT = NT >> 1;
  for (int i = 0; i < NIT; i++) {
    const int t1 = 2 * i + 1, nt0 = 2 * i + 2, nt1 = 2 * i + 3;
    const bool lst = (i == NIT - 1);
    PHASE(a0,  b0,  0, 0, SA(1, 1, t1), );
    PHASE(a0,  b0h, 0, 1, SB(1, 1, t1), );
    PHASE(a0h, b0,  1, 0, if (!lst) SA(0, 0, nt0), );
    PHASE(a0h, b0h, 1, 1, if (!lst) SB(0, 0, nt0),
          if (lst) { asm volatile("s_waitcnt vmcnt(0)" ::: "memory"); }
          else     { asm volatile("s_waitcnt vmcnt(4)" ::: "memory"); } );
    PHASE(a1,  b1,  0, 0, if (!lst) SA(0, 1, nt0), );
    PHASE(a1,  b1h, 0, 1, if (!lst) SB(0, 1, nt0), );
    PHASE(a1h, b1,  1, 0, if (!lst) SA(1, 0, nt1), );
    PHASE(a1h, b1h, 1, 1, if (!lst) SB(1, 0, nt1),
          if (!lst) { asm volatile("s_waitcnt vmcnt(4)" ::: "memory"); } );
  }
#undef PHASE
#undef SA
#undef SB

  const int cr = (lane >> 4) * 4, cc = lane & 15;
#pragma unroll
  for (int fi = 0; fi < 8; fi++)
#pragma unroll
    for (int fj = 0; fj < 4; fj++) {
      const size_t roff = (size_t)(m0 + (fi * 2 + wr) * 16 + cr) * N + (n0 + (fj * 4 + wc) * 16 + cc);
      if (OUTMODE == 0) {
        float* Cp = (float*)Cv + roff;
#pragma unroll
        for (int r = 0; r < 4; r++) Cp[(size_t)r * N] = acc[fi][fj][r];
      } else {
        u16* Cp = (u16*)Cv + roff;
#pragma unroll
        for (int r = 0; r < 4; r++) Cp[(size_t)r * N] = f2bf(acc[fi][fj][r]);
      }
    }
}

// ---------------- bf16 GEMM 128^2 2-phase (used for GEMM2) ---------------------
template<int OUTMODE>
__global__ __launch_bounds__(256) void k_gemm_bt(const u16* __restrict__ A, const u16* __restrict__ B,
                                                 void* __restrict__ Cv, int M, int N, int K) {
  __shared__ __align__(16) u16 As[2][128 * 64];
  __shared__ __align__(16) u16 Bs[2][128 * 64];
  const int t = threadIdx.x;
  const int lane = t & 63, w = t >> 6;
  const int m0 = blockIdx.y * 128, n0 = blockIdx.x * 128;
  const int wm = (w >> 1) * 64, wn = (w & 1) * 64;
  const int NT = K >> 6;
  f32x4 acc[4][4] = {};
  const u16* Ap = A + (size_t)m0 * K;
  const u16* Bp = B + (size_t)n0 * K;
  const int cr0 = lane >> 3, cs = lane & 7;

#define GSTAGE(bb, kt_) do { \
    _Pragma("unroll") \
    for (int s2 = 0; s2 < 4; s2++) { \
      int ch = w * 4 + s2; \
      int row = ch * 8 + cr0; \
      int cb = cs ^ (row & 7); \
      GLD((char*)As[bb] + ch * 1024, Ap + (size_t)row * K + (kt_) * 64 + cb * 8); \
      GLD((char*)Bs[bb] + ch * 1024, Bp + (size_t)row * K + (kt_) * 64 + cb * 8); \
    } } while (0)

  GSTAGE(0, 0);
  asm volatile("s_waitcnt vmcnt(0)" ::: "memory");
  __builtin_amdgcn_s_barrier();
  int cur = 0;
  for (int kt = 0; kt < NT; kt++) {
    if (kt + 1 < NT) GSTAGE(cur ^ 1, kt + 1);
    const u16* asb = As[cur];
    const u16* bsb = Bs[cur];
#pragma unroll
    for (int kk = 0; kk < 2; kk++) {
      bf16x8 af[4], bfr[4];
#pragma unroll
      for (int i = 0; i < 4; i++) {
        int rowa = wm + i * 16 + (lane & 15);
        af[i] = *(const bf16x8*)((const char*)asb + rowa * 128 + ((kk * 64 + (lane >> 4) * 16) ^ ((rowa & 7) << 4)));
        int rowb = wn + i * 16 + (lane & 15);
        bfr[i] = *(const bf16x8*)((const char*)bsb + rowb * 128 + ((kk * 64 + (lane >> 4) * 16) ^ ((rowb & 7) << 4)));
      }
#pragma unroll
      for (int mf = 0; mf < 4; mf++)
#pragma unroll
        for (int nf = 0; nf < 4; nf++)
          acc[mf][nf] = __builtin_amdgcn_mfma_f32_16x16x32_bf16(af[mf], bfr[nf], acc[mf][nf], 0, 0, 0);
    }
    asm volatile("s_waitcnt vmcnt(0)" ::: "memory");
    __builtin_amdgcn_s_barrier();
    cur ^= 1;
  }
#undef GSTAGE
  const int cr = (lane >> 4) * 4, cc = lane & 15;
#pragma unroll
  for (int mf = 0; mf < 4; mf++)
#pragma unroll
    for (int nf = 0; nf < 4; nf++) {
      if (OUTMODE == 0) {
        float* Cp = (float*)Cv + (size_t)(m0 + wm + mf * 16 + cr) * N + (n0 + wn + nf * 16 + cc);
#pragma unroll
        for (int r = 0; r < 4; r++) Cp[(size_t)r * N] = acc[mf][nf][r];
      } else {
        u16* Cp = (u16*)Cv + (size_t)(m0 + wm + mf * 16 + cr) * N + (n0 + wn + nf * 16 + cc);
#pragma unroll
        for (int r = 0; r < 4; r++) Cp[(size_t)r * N] = f2bf(acc[mf][nf][r]);
      }
    }
}

// ---------------- q/k layernorm (over full D, bf16 in) + RoPE + head split -----
__global__ __launch_bounds__(256) void k_qk_ln_rope(const u16* __restrict__ qkv,
                                                    const float* __restrict__ qw, const float* __restrict__ kw,
                                                    const float* __restrict__ cosb, const float* __restrict__ sinb,
                                                    u16* __restrict__ Q, u16* __restrict__ K, u16* __restrict__ V) {
  int row = blockIdx.x, t = threadIdx.x;
  int b = row >> 11, l = row & 2047;
  const u16* base = qkv + (size_t)row * 3072;
  ushort4 qu = ((const ushort4*)base)[t];
  ushort4 ku = ((const ushort4*)(base + 1024))[t];
  ushort4 vu = ((const ushort4*)(base + 2048))[t];
  float qx = bf2f(qu.x), qy = bf2f(qu.y), qz = bf2f(qu.z), qw_ = bf2f(qu.w);
  float kx = bf2f(ku.x), ky = bf2f(ku.y), kz = bf2f(ku.z), kw_ = bf2f(ku.w);
  float red[4];
  red[0] = qx + qy + qz + qw_;
  red[1] = qx * qx + qy * qy + qz * qz + qw_ * qw_;
  red[2] = kx + ky + kz + kw_;
  red[3] = kx * kx + ky * ky + kz * kz + kw_ * kw_;
#pragma unroll
  for (int i = 0; i < 4; i++)
#pragma unroll
    for (int m2 = 1; m2 < 64; m2 <<= 1) red[i] += __shfl_xor(red[i], m2);
  __shared__ float rb[4][4];
  int w = t >> 6;
  if ((t & 63) == 0) { rb[w][0] = red[0]; rb[w][1] = red[1]; rb[w][2] = red[2]; rb[w][3] = red[3]; }
  __syncthreads();
  float S1 = rb[0][0] + rb[1][0] + rb[2][0] + rb[3][0];
  float S2 = rb[0][1] + rb[1][1] + rb[2][1] + rb[3][1];
  float S3 = rb[0][2] + rb[1][2] + rb[2][2] + rb[3][2];
  float S4 = rb[0][3] + rb[1][3] + rb[2][3] + rb[3][3];
  float muq = S1 * (1.0f / DMODEL), rsq = rsqrtf(S2 * (1.0f / DMODEL) - muq * muq + 1e-5f);
  float muk = S3 * (1.0f / DMODEL), rsk = rsqrtf(S4 * (1.0f / DMODEL) - muk * muk + 1e-5f);
  __shared__ float qs[1024], ks[1024];
  float4 qwv = ((const float4*)qw)[t];
  float4 kwv = ((const float4*)kw)[t];
  qs[t * 4 + 0] = (qx - muq) * rsq * qwv.x;  ks[t * 4 + 0] = (kx - muk) * rsk * kwv.x;
  qs[t * 4 + 1] = (qy - muq) * rsq * qwv.y;  ks[t * 4 + 1] = (ky - muk) * rsk * kwv.y;
  qs[t * 4 + 2] = (qz - muq) * rsq * qwv.z;  ks[t * 4 + 2] = (kz - muk) * rsk * kwv.z;
  qs[t * 4 + 3] = (qw_ - muq) * rsq * qwv.w; ks[t * 4 + 3] = (kw_ - muk) * rsk * kwv.w;
  __syncthreads();
  int d0 = t * 4;
  int hh = d0 >> 6;
  union { ushort4 v4; u16 e[4]; } qo, ko;
#pragma unroll
  for (int i = 0; i < 4; i++) {
    int d = d0 + i, dd = d & 63, fr = dd & 31;
    float c = cosb[l * 32 + fr], s = sinb[l * 32 + fr];
    float q1 = qs[d], q2 = (dd < 32) ? -qs[d + 32] : qs[d - 32];
    float k1 = ks[d], k2 = (dd < 32) ? -ks[d + 32] : ks[d - 32];
    qo.e[i] = f2bf(q1 * c + q2 * s);
    ko.e[i] = f2bf(k1 * c + k2 * s);
  }
  size_t oidx = ((size_t)(b * NHEAD + hh) * LSEQ + l) * DHEAD + (d0 & 63);
  *(ushort4*)(Q + oidx) = qo.v4;
  *(ushort4*)(K + oidx) = ko.v4;
  *(ushort4*)(V + oidx) = vu;
}

// ---------------- segment-masked flash attention (swapped-QK, fixed-shift SM) --
__global__ __launch_bounds__(256) void k_attn(const u16* __restrict__ Q, const u16* __restrict__ Kb,
                                              const u16* __restrict__ VTb, const int* __restrict__ seq,
                                              const int* __restrict__ bnd, u16* __restrict__ ctx) {
  __shared__ __align__(16) u16 Ks[2][64 * 64];
  __shared__ __align__(16) u16 Vs[2][64 * 64];
  __shared__ __align__(16) u16 Pw[4][16 * 64];

  const int bid = blockIdx.x;
  const int qt = bid & 31, h = (bid >> 5) & 15, b = bid >> 9;
  const int t = threadIdx.x, l = t & 63, w = t >> 6;
  const int c = l & 15, g = l >> 4;
  const int q0 = qt * 64;
  const size_t hoff = (size_t)(b * NHEAD + h) * LSEQ * DHEAD;
  const u16* Qg = Q + hoff;
  const u16* Kg = Kb + hoff;
  const u16* Vg = VTb + hoff;   // [d][l]
  const int* seqb = seq + b * LSEQ;
  const int* bnd5 = bnd + b * 5;

  const int qw0 = q0 + w * 16;
  const int myq = qw0 + c;
  const int sq = seqb[myq];
  const int lo = bnd5[sq], hi = bnd5[sq + 1];
  const int wlo = bnd5[seqb[qw0]];
  const int whi = bnd5[seqb[qw0 + 15] + 1];
  int kbeg = bnd5[seqb[q0]] & ~63;
  int kend = (bnd5[seqb[q0 + 63] + 1] + 63) & ~63;
  if (kend > LSEQ) kend = LSEQ;

  bf16x8 qf[2];
  qf[0] = *(const bf16x8*)(Qg + (size_t)myq * 64 + g * 8);
  qf[1] = *(const bf16x8*)(Qg + (size_t)myq * 64 + 32 + g * 8);

  f32x4 acc[4] = {};
  float lsum = 0.f;

#define STAGE(bb, kt_) do { \
    int r1 = w * 16 + (l >> 3); \
    int r2 = r1 + 8; \
    GLD((char*)Ks[bb] + (w * 2    ) * 1024, Kg + (size_t)((kt_) + r1) * 64 + (((l & 7) ^ (r1 & 7)) * 8)); \
    GLD((char*)Ks[bb] + (w * 2 + 1) * 1024, Kg + (size_t)((kt_) + r2) * 64 + (((l & 7) ^ (r2 & 7)) * 8)); \
    GLD((char*)Vs[bb] + (w * 2    ) * 1024, Vg + (size_t)r1 * LSEQ + (kt_) + (((l & 7) ^ (r1 & 7)) * 8)); \
    GLD((char*)Vs[bb] + (w * 2 + 1) * 1024, Vg + (size_t)r2 * LSEQ + (kt_) + (((l & 7) ^ (r2 & 7)) * 8)); \
  } while (0)

  STAGE(0, kbeg);
  int cur = 0;
  for (int kt = kbeg; kt < kend; kt += 64) {
    const bool more = (kt + 64) < kend;
    if (more) STAGE(cur ^ 1, kt + 64);
    if (more) asm volatile("s_waitcnt vmcnt(4)" ::: "memory");
    else      asm volatile("s_waitcnt vmcnt(0)" ::: "memory");
    __builtin_amdgcn_s_barrier();
    __builtin_amdgcn_sched_barrier(0);
    if (kt < whi && kt + 64 > wlo) {
      const u16* ksb = Ks[cur];
      const u16* vsb = Vs[cur];
      f32x4 st[4] = {};
#pragma unroll
      for (int kk = 0; kk < 2; kk++) {
        bf16x8 kf[4];
#pragma unroll
        for (int i = 0; i < 4; i++) {
          int row = i * 16 + c;
          kf[i] = *(const bf16x8*)((const char*)ksb + row * 128 + ((kk * 64 + g * 16) ^ ((row & 7) << 4)));
        }
#pragma unroll
        for (int i = 0; i < 4; i++)
          st[i] = __builtin_amdgcn_mfma_f32_16x16x32_bf16(kf[i], qf[kk], st[i], 0, 0, 0);
      }
      const int kb0 = kt + g * 4;
#pragma unroll
      for (int i = 0; i < 4; i++) {
        float p[4];
#pragma unroll
        for (int r = 0; r < 4; r++) {
          int kglob = kb0 + i * 16 + r;
          bool ok = ((unsigned)(kglob - lo)) < ((unsigned)(hi - lo));
          float x = ok ? fmaf(st[i][r], 0.125f, -8.0f) : -1e30f;
          p[r] = __expf(x);
          lsum += p[r];
        }
        unsigned w0, w1;
        asm("v_cvt_pk_bf16_f32 %0, %1, %2" : "=v"(w0) : "v"(p[0]), "v"(p[1]));
        asm("v_cvt_pk_bf16_f32 %0, %1, %2" : "=v"(w1) : "v"(p[2]), "v"(p[3]));
        uint2 wp; wp.x = w0; wp.y = w1;
        *(uint2*)((char*)Pw[w] + c * 128 + ((i * 32 + g * 8) ^ ((c & 3) << 4))) = wp;
      }
#pragma unroll
      for (int kk = 0; kk < 2; kk++) {
        bf16x8 pa = *(const bf16x8*)((char*)Pw[w] + c * 128 + ((kk * 64 + g * 16) ^ ((c & 3) << 4)));
        bf16x8 vf[4];
#pragma unroll
        for (int df = 0; df < 4; df++) {
          int row = df * 16 + c;
          vf[df] = *(const bf16x8*)((const char*)vsb + row * 128 + ((kk * 64 + g * 16) ^ ((row & 7) << 4)));
        }
#pragma unroll
        for (int df = 0; df < 4; df++)
          acc[df] = __builtin_amdgcn_mfma_f32_16x16x32_bf16(pa, vf[df], acc[df], 0, 0, 0);
      }
    }
    __builtin_amdgcn_sched_barrier(0);
    __builtin_amdgcn_s_barrier();
    cur ^= 1;
  }
#undef STAGE

  lsum += __shfl_xor(lsum, 16);
  lsum += __shfl_xor(lsum, 32);
#pragma unroll
  for (int r = 0; r < 4; r++) {
    float lr = __shfl(lsum, g * 4 + r, 64);
    float rls = 1.0f / lr;
    int qrow = qw0 + g * 4 + r;
    u16* op = ctx + (size_t)(b * LSEQ + qrow) * DMODEL + h * 64 + c;
#pragma unroll
    for (int df = 0; df < 4; df++)
      op[df * 16] = f2bf(acc[df][r] * rls);
  }
}

// ---------------- launch --------------------------------------------------------
extern "C" void kernel_launch(void* const* d_in, const int* in_sizes, int n_in,
                              void* d_out, int out_size, void* d_ws, size_t ws_size,
                              hipStream_t stream) {
  const float* x    = (const float*)d_in[0];
  const int*   seq  = (const int*)d_in[1];
  const float* ln1w = (const float*)d_in[2];
  const float* ln1b = (const float*)d_in[3];
  const float* wqkv = (const float*)d_in[4];
  const float* qlnw = (const float*)d_in[5];
  const float* klnw = (const float*)d_in[6];
  const float* wout = (const float*)d_in[7];
  float* out = (float*)d_out;

  char* p = (char*)d_ws;
  u16* wqkvT = (u16*)p;  p += (size_t)3072 * 1024 * 2;
  u16* woutT = (u16*)p;  p += (size_t)1024 * 1024 * 2;
  u16* hbuf  = (u16*)p;  p += (size_t)ROWS * DMODEL * 2;
  u16* Qb    = (u16*)p;  p += (size_t)ROWS * DMODEL * 2;
  u16* Kbuf  = (u16*)p;  p += (size_t)ROWS * DMODEL * 2;
  u16* Vbuf  = (u16*)p;  p += (size_t)ROWS * DMODEL * 2;
  u16* VTbuf = (u16*)p;  p += (size_t)ROWS * DMODEL * 2;
  u16* ctxb  = (u16*)p;  p += (size_t)ROWS * DMODEL * 2;
  float* cosb = (float*)p; p += (size_t)LSEQ * 32 * 4;
  float* sinb = (float*)p; p += (size_t)LSEQ * 32 * 4;
  int* bnd   = (int*)p;  p += 256;
  u16* qkv   = (u16*)p;  p += (size_t)ROWS * 3072 * 2;

  k_transpose_cvt<<<dim3(3072 / 32, 1024 / 32), dim3(32, 8), 0, stream>>>(wqkv, wqkvT, 1024, 3072);
  k_transpose_cvt<<<dim3(1024 / 32, 1024 / 32), dim3(32, 8), 0, stream>>>(wout, woutT, 1024, 1024);
  k_rope_tables<<<(LSEQ * 32) / 256, 256, 0, stream>>>(cosb, sinb, seq, bnd);
  k_ln1<<<ROWS, 256, 0, stream>>>(x, ln1w, ln1b, hbuf);
  k_gemm256<1><<<(ROWS / 256) * (3072 / 256), 512, 0, stream>>>(hbuf, wqkvT, (void*)qkv, ROWS, 3072, 1024);
  k_qk_ln_rope<<<ROWS, 256, 0, stream>>>(qkv, qlnw, klnw, cosb, sinb, Qb, Kbuf, Vbuf);
  k_transpose_u16<<<dim3(DHEAD / 32, LSEQ / 32, BATCH * NHEAD), dim3(32, 8), 0, stream>>>(Vbuf, VTbuf);
  k_attn<<<BATCH * NHEAD * (LSEQ / 64), 256, 0, stream>>>(Qb, Kbuf, VTbuf, seq, bnd, ctxb);
  k_gemm_bt<0><<<dim3(1024 / 128, ROWS / 128), 256, 0, stream>>>(ctxb, woutT, (void*)out, ROWS, 1024, 1024);
}

// Round 7
// 137.696 us; speedup vs baseline: 1.0166x; 1.0166x over previous
//
#include <hip/hip_runtime.h>
#include <hip/hip_bf16.h>
#include <cstdint>
#include <math.h>

#define LSEQ 2048
#define BATCH 2
#define NHEAD 16
#define DHEAD 64
#define DMODEL 1024
#define ROWS (BATCH*LSEQ)

typedef __bf16 bf16x8 __attribute__((ext_vector_type(8)));
typedef float f32x4 __attribute__((ext_vector_type(4)));
typedef unsigned short u16;

#define GLD(lds_base, src_g) \
  __builtin_amdgcn_global_load_lds((const __attribute__((address_space(1))) void*)(src_g), \
                                   (__attribute__((address_space(3))) void*)(lds_base), 16, 0, 0)
#define VM(n) asm volatile("s_waitcnt vmcnt(" #n ")" ::: "memory")

__device__ __forceinline__ u16 f2bf(float f) {
  unsigned int u = __float_as_uint(f);
  u += 0x7fffu + ((u >> 16) & 1u);
  return (u16)(u >> 16);
}
__device__ __forceinline__ float bf2f(u16 u) {
  return __uint_as_float(((unsigned)u) << 16);
}

// ---------------- transpose + fp32->bf16 convert: out[c][r] = bf16(in[r][c]) ----
__global__ void k_transpose_cvt(const float* __restrict__ in, u16* __restrict__ out, int R, int C) {
  __shared__ float tile[32][33];
  int c0 = blockIdx.x * 32, r0 = blockIdx.y * 32;
  int tx = threadIdx.x, ty = threadIdx.y;
#pragma unroll
  for (int i = 0; i < 32; i += 8)
    tile[ty + i][tx] = in[(size_t)(r0 + ty + i) * C + (c0 + tx)];
  __syncthreads();
#pragma unroll
  for (int i = 0; i < 32; i += 8)
    out[(size_t)(c0 + ty + i) * R + (r0 + tx)] = f2bf(tile[tx][ty + i]);
}

// ---------------- u16 transpose per head: in [L][64] -> out [64][L] ------------
__global__ void k_transpose_u16(const u16* __restrict__ in, u16* __restrict__ out) {
  __shared__ u16 tile[32][33];
  int hd = blockIdx.z;
  int l0 = blockIdx.y * 32, d0 = blockIdx.x * 32;
  const u16* ip = in + (size_t)hd * LSEQ * DHEAD;
  u16* op = out + (size_t)hd * LSEQ * DHEAD;
  int tx = threadIdx.x, ty = threadIdx.y;
#pragma unroll
  for (int i = 0; i < 32; i += 8)
    tile[ty + i][tx] = ip[(size_t)(l0 + ty + i) * DHEAD + d0 + tx];
  __syncthreads();
#pragma unroll
  for (int i = 0; i < 32; i += 8)
    op[(size_t)(d0 + ty + i) * LSEQ + l0 + tx] = tile[tx][ty + i];
}

// ---------------- RoPE tables + segment bounds (fused) -------------------------
__global__ void k_rope_tables(float* __restrict__ cosb, float* __restrict__ sinb,
                              const int* __restrict__ seq, int* __restrict__ bnd) {
  if (blockIdx.x == 0 && threadIdx.x < BATCH * 5) {
    int b = threadIdx.x / 5, s = threadIdx.x % 5;
    const int* row = seq + b * LSEQ;
    int lo = 0, hi = LSEQ;
    while (lo < hi) { int mid = (lo + hi) >> 1; if (row[mid] < s) lo = mid + 1; else hi = mid; }
    bnd[b * 5 + s] = lo;
  }
  int idx = blockIdx.x * blockDim.x + threadIdx.x;
  if (idx >= LSEQ * 32) return;
  int l = idx >> 5, f = idx & 31;
  double inv = pow(10000.0, -(double)f / 32.0);
  float ang = (float)l * (float)inv;
  cosb[idx] = cosf(ang);
  sinb[idx] = sinf(ang);
}

// ---------------- LN1: h = bf16(layernorm(x, w, b)) ----------------------------
__global__ __launch_bounds__(256) void k_ln1(const float* __restrict__ x, const float* __restrict__ w,
                                             const float* __restrict__ bias, u16* __restrict__ h) {
  int row = blockIdx.x, t = threadIdx.x;
  const float4 xv = ((const float4*)(x + (size_t)row * DMODEL))[t];
  float s = xv.x + xv.y + xv.z + xv.w;
  float s2 = xv.x * xv.x + xv.y * xv.y + xv.z * xv.z + xv.w * xv.w;
#pragma unroll
  for (int m2 = 1; m2 < 64; m2 <<= 1) { s += __shfl_xor(s, m2); s2 += __shfl_xor(s2, m2); }
  __shared__ float rb[2][4];
  int wv = t >> 6;
  if ((t & 63) == 0) { rb[0][wv] = s; rb[1][wv] = s2; }
  __syncthreads();
  s  = rb[0][0] + rb[0][1] + rb[0][2] + rb[0][3];
  s2 = rb[1][0] + rb[1][1] + rb[1][2] + rb[1][3];
  float mu = s * (1.0f / DMODEL);
  float rs = rsqrtf(s2 * (1.0f / DMODEL) - mu * mu + 1e-5f);
  const float4 wv4 = ((const float4*)w)[t];
  const float4 bv4 = ((const float4*)bias)[t];
  ushort4 o;
  o.x = f2bf((xv.x - mu) * rs * wv4.x + bv4.x);
  o.y = f2bf((xv.y - mu) * rs * wv4.y + bv4.y);
  o.z = f2bf((xv.z - mu) * rs * wv4.z + bv4.z);
  o.w = f2bf((xv.w - mu) * rs * wv4.w + bv4.w);
  ((ushort4*)(h + (size_t)row * DMODEL))[t] = o;
}

// ================ 256x256 4-phase GEMM (merged pairs), C = A @ B^T =============
// 512 thr = 8 waves (2M x 4N). BK=64, 2 K-tiles/iter. Each phase = one mh half x
// BOTH nh halves (32 MFMA): A-frags loaded once, B h1 frags loaded mid-phase.
// Stage addressing: persistent per-lane pointers + C pointer arithmetic
// (NO global_load_lds offset immediate — round-6 NaN suspect). vmcnt(2) at P2/P4.
template<int OUTMODE>
__global__ __launch_bounds__(512, 2) void k_gemm256(const u16* __restrict__ A, const u16* __restrict__ B,
                                                    void* __restrict__ Cv, int M, int N, int K) {
  __shared__ __align__(16) u16 As[2][256 * 64];
  __shared__ __align__(16) u16 Bs[2][256 * 64];
  const int t = threadIdx.x, lane = t & 63, w = t >> 6;
  const int wr = w >> 2, wc = w & 3;
  const int nbx = N >> 8;
  const int nwg = nbx * (M >> 8);
  const int cpx = nwg >> 3;
  const int bid = blockIdx.x;
  const int sw = (bid & 7) * cpx + (bid >> 3);   // XCD swizzle (nwg % 8 == 0)
  const int m0 = (sw / nbx) * 256, n0 = (sw % nbx) * 256;
  const int NT = K >> 6;                          // 16
  const int cg16 = (lane >> 4) * 16;

  f32x4 acc[8][4] = {};
  const u16* Ap = A + (size_t)m0 * K;
  const u16* Bp = B + (size_t)n0 * K;
  const int rr0 = t >> 3;
  const int sz = ((t & 7) * 8) ^ ((rr0 & 7) << 3);   // u16 units (inverse swizzle)
  // persistent per-lane source pointers: rows rr0 + {0,64,128,192}
  const u16* pA[4] = { Ap + (size_t)rr0 * K + sz,
                       Ap + (size_t)(rr0 + 64) * K + sz,
                       Ap + (size_t)(rr0 + 128) * K + sz,
                       Ap + (size_t)(rr0 + 192) * K + sz };
  const u16* pB[4] = { Bp + (size_t)rr0 * K + sz,
                       Bp + (size_t)(rr0 + 64) * K + sz,
                       Bp + (size_t)(rr0 + 128) * K + sz,
                       Bp + (size_t)(rr0 + 192) * K + sz };

// EO = element offset (u16): tile delta vs current base kt (64 per K-tile)
#define SA2(b, h, EO) do { \
    GLD((char*)As + (b)*32768 + (h)*16384 + w*1024,        pA[(h)*2]     + (EO)); \
    GLD((char*)As + (b)*32768 + (h)*16384 + 8192 + w*1024, pA[(h)*2 + 1] + (EO)); \
  } while (0)
#define SB2(b, h, EO) do { \
    GLD((char*)Bs + (b)*32768 + (h)*16384 + w*1024,        pB[(h)*2]     + (EO)); \
    GLD((char*)Bs + (b)*32768 + (h)*16384 + 8192 + w*1024, pB[(h)*2 + 1] + (EO)); \
  } while (0)

#define PHASEM(asb, bsl, bsh, mh, STG, WVM) do { \
    bf16x8 af_[4][2], bf_[2][2]; \
    _Pragma("unroll") for (int i2 = 0; i2 < 4; i2++) { \
      const int rowA = (((mh)*4 + i2)*2 + wr)*16 + (lane & 15); \
      const int sA = (rowA & 7) << 4; \
      _Pragma("unroll") for (int kk = 0; kk < 2; kk++) \
        af_[i2][kk] = *(const bf16x8*)((const char*)(asb) + (rowA & 127)*128 + ((kk*64 + cg16) ^ sA)); \
    } \
    _Pragma("unroll") for (int j2 = 0; j2 < 2; j2++) { \
      const int rowB = (j2*4 + wc)*16 + (lane & 15); \
      const int sB = (rowB & 7) << 4; \
      _Pragma("unroll") for (int kk = 0; kk < 2; kk++) \
        bf_[j2][kk] = *(const bf16x8*)((const char*)(bsl) + (rowB & 127)*128 + ((kk*64 + cg16) ^ sB)); \
    } \
    STG; \
    __builtin_amdgcn_s_barrier(); \
    asm volatile("s_waitcnt lgkmcnt(0)" ::: "memory"); \
    __builtin_amdgcn_s_setprio(1); \
    _Pragma("unroll") for (int i2 = 0; i2 < 4; i2++) \
      _Pragma("unroll") for (int j2 = 0; j2 < 2; j2++) \
        _Pragma("unroll") for (int kk = 0; kk < 2; kk++) \
          acc[(mh)*4+i2][j2] = __builtin_amdgcn_mfma_f32_16x16x32_bf16( \
              af_[i2][kk], bf_[j2][kk], acc[(mh)*4+i2][j2], 0, 0, 0); \
    _Pragma("unroll") for (int j2 = 0; j2 < 2; j2++) { \
      const int rowB = ((2 + j2)*4 + wc)*16 + (lane & 15); \
      const int sB = (rowB & 7) << 4; \
      _Pragma("unroll") for (int kk = 0; kk < 2; kk++) \
        bf_[j2][kk] = *(const bf16x8*)((const char*)(bsh) + (rowB & 127)*128 + ((kk*64 + cg16) ^ sB)); \
    } \
    _Pragma("unroll") for (int i2 = 0; i2 < 4; i2++) \
      _Pragma("unroll") for (int j2 = 0; j2 < 2; j2++) \
        _Pragma("unroll") for (int kk = 0; kk < 2; kk++) \
          acc[(mh)*4+i2][2+j2] = __builtin_amdgcn_mfma_f32_16x16x32_bf16( \
              af_[i2][kk], bf_[j2][kk], acc[(mh)*4+i2][2+j2], 0, 0, 0); \
    __builtin_amdgcn_s_setprio(0); \
    WVM; \
    __builtin_amdgcn_s_barrier(); \
  } while (0)

  // prologue: buf0 tile0 full (8 GLD) + buf1 A h0 of tile1 (2 GLD)
  SA2(0, 0, 0); SA2(0, 1, 0); SB2(0, 0, 0); SB2(0, 1, 0);
  SA2(1, 0, 64);
  VM(2);
  __builtin_amdgcn_s_barrier();

  const char* a0  = (const char*)As;
  const char* a0h = a0 + 16384;
  const char* a1  = a0 + 32768;
  const char* a1h = a0 + 49152;
  const char* b0  = (const char*)Bs;
  const char* b0h = b0 + 16384;
  const char* b1  = b0 + 32768;
  const char* b1h = b0 + 49152;
  const int NIT = NT >> 1;
  for (int i = 0; i < NIT; i++) {
    const bool lst = (i == NIT - 1);
    PHASEM(a0,  b0, b0h, 0, { SA2(1, 1, 64); SB2(1, 0, 64); SB2(1, 1, 64); }, {});
    PHASEM(a0h, b0, b0h, 1, { if (!lst) SA2(0, 0, 128); },
                            { if (lst) VM(0); else VM(2); });
    PHASEM(a1,  b1, b1h, 0, { if (!lst) { SA2(0, 1, 128); SB2(0, 0, 128); SB2(0, 1, 128); } }, {});
    PHASEM(a1h, b1, b1h, 1, { if (!lst) SA2(1, 0, 192); },
                            { if (!lst) VM(2); });
    pA[0] += 128; pA[1] += 128; pA[2] += 128; pA[3] += 128;
    pB[0] += 128; pB[1] += 128; pB[2] += 128; pB[3] += 128;
  }
#undef PHASEM
#undef SA2
#undef SB2

  const int cr = (lane >> 4) * 4, cc = lane & 15;
#pragma unroll
  for (int fi = 0; fi < 8; fi++)
#pragma unroll
    for (int fj = 0; fj < 4; fj++) {
      const size_t roff = (size_t)(m0 + (fi * 2 + wr) * 16 + cr) * N + (n0 + (fj * 4 + wc) * 16 + cc);
      if (OUTMODE == 0) {
        float* Cp = (float*)Cv + roff;
#pragma unroll
        for (int r = 0; r < 4; r++) Cp[(size_t)r * N] = acc[fi][fj][r];
      } else {
        u16* Cp = (u16*)Cv + roff;
#pragma unroll
        for (int r = 0; r < 4; r++) Cp[(size_t)r * N] = f2bf(acc[fi][fj][r]);
      }
    }
}

// ---------------- bf16 GEMM 128^2 2-phase (used for GEMM2) ---------------------
template<int OUTMODE>
__global__ __launch_bounds__(256) void k_gemm_bt(const u16* __restrict__ A, const u16* __restrict__ B,
                                                 void* __restrict__ Cv, int M, int N, int K) {
  __shared__ __align__(16) u16 As[2][128 * 64];
  __shared__ __align__(16) u16 Bs[2][128 * 64];
  const int t = threadIdx.x;
  const int lane = t & 63, w = t >> 6;
  const int m0 = blockIdx.y * 128, n0 = blockIdx.x * 128;
  const int wm = (w >> 1) * 64, wn = (w & 1) * 64;
  const int NT = K >> 6;
  f32x4 acc[4][4] = {};
  const u16* Ap = A + (size_t)m0 * K;
  const u16* Bp = B + (size_t)n0 * K;
  const int cr0 = lane >> 3, cs = lane & 7;

#define GSTAGE(bb, kt_) do { \
    _Pragma("unroll") \
    for (int s2 = 0; s2 < 4; s2++) { \
      int ch = w * 4 + s2; \
      int row = ch * 8 + cr0; \
      int cb = cs ^ (row & 7); \
      GLD((char*)As[bb] + ch * 1024, Ap + (size_t)row * K + (kt_) * 64 + cb * 8); \
      GLD((char*)Bs[bb] + ch * 1024, Bp + (size_t)row * K + (kt_) * 64 + cb * 8); \
    } } while (0)

  GSTAGE(0, 0);
  VM(0);
  __builtin_amdgcn_s_barrier();
  int cur = 0;
  for (int kt = 0; kt < NT; kt++) {
    if (kt + 1 < NT) GSTAGE(cur ^ 1, kt + 1);
    const u16* asb = As[cur];
    const u16* bsb = Bs[cur];
#pragma unroll
    for (int kk = 0; kk < 2; kk++) {
      bf16x8 af[4], bfr[4];
#pragma unroll
      for (int i = 0; i < 4; i++) {
        int rowa = wm + i * 16 + (lane & 15);
        af[i] = *(const bf16x8*)((const char*)asb + rowa * 128 + ((kk * 64 + (lane >> 4) * 16) ^ ((rowa & 7) << 4)));
        int rowb = wn + i * 16 + (lane & 15);
        bfr[i] = *(const bf16x8*)((const char*)bsb + rowb * 128 + ((kk * 64 + (lane >> 4) * 16) ^ ((rowb & 7) << 4)));
      }
#pragma unroll
      for (int mf = 0; mf < 4; mf++)
#pragma unroll
        for (int nf = 0; nf < 4; nf++)
          acc[mf][nf] = __builtin_amdgcn_mfma_f32_16x16x32_bf16(af[mf], bfr[nf], acc[mf][nf], 0, 0, 0);
    }
    VM(0);
    __builtin_amdgcn_s_barrier();
    cur ^= 1;
  }
#undef GSTAGE
  const int cr = (lane >> 4) * 4, cc = lane & 15;
#pragma unroll
  for (int mf = 0; mf < 4; mf++)
#pragma unroll
    for (int nf = 0; nf < 4; nf++) {
      if (OUTMODE == 0) {
        float* Cp = (float*)Cv + (size_t)(m0 + wm + mf * 16 + cr) * N + (n0 + wn + nf * 16 + cc);
#pragma unroll
        for (int r = 0; r < 4; r++) Cp[(size_t)r * N] = acc[mf][nf][r];
      } else {
        u16* Cp = (u16*)Cv + (size_t)(m0 + wm + mf * 16 + cr) * N + (n0 + wn + nf * 16 + cc);
#pragma unroll
        for (int r = 0; r < 4; r++) Cp[(size_t)r * N] = f2bf(acc[mf][nf][r]);
      }
    }
}

// ---------------- q/k layernorm (over full D, bf16 in) + RoPE + head split -----
__global__ __launch_bounds__(256) void k_qk_ln_rope(const u16* __restrict__ qkv,
                                                    const float* __restrict__ qw, const float* __restrict__ kw,
                                                    const float* __restrict__ cosb, const float* __restrict__ sinb,
                                                    u16* __restrict__ Q, u16* __restrict__ K, u16* __restrict__ V) {
  int row = blockIdx.x, t = threadIdx.x;
  int b = row >> 11, l = row & 2047;
  const u16* base = qkv + (size_t)row * 3072;
  ushort4 qu = ((const ushort4*)base)[t];
  ushort4 ku = ((const ushort4*)(base + 1024))[t];
  ushort4 vu = ((const ushort4*)(base + 2048))[t];
  float qx = bf2f(qu.x), qy = bf2f(qu.y), qz = bf2f(qu.z), qw_ = bf2f(qu.w);
  float kx = bf2f(ku.x), ky = bf2f(ku.y), kz = bf2f(ku.z), kw_ = bf2f(ku.w);
  float red[4];
  red[0] = qx + qy + qz + qw_;
  red[1] = qx * qx + qy * qy + qz * qz + qw_ * qw_;
  red[2] = kx + ky + kz + kw_;
  red[3] = kx * kx + ky * ky + kz * kz + kw_ * kw_;
#pragma unroll
  for (int i = 0; i < 4; i++)
#pragma unroll
    for (int m2 = 1; m2 < 64; m2 <<= 1) red[i] += __shfl_xor(red[i], m2);
  __shared__ float rb[4][4];
  int w = t >> 6;
  if ((t & 63) == 0) { rb[w][0] = red[0]; rb[w][1] = red[1]; rb[w][2] = red[2]; rb[w][3] = red[3]; }
  __syncthreads();
  float S1 = rb[0][0] + rb[1][0] + rb[2][0] + rb[3][0];
  float S2 = rb[0][1] + rb[1][1] + rb[2][1] + rb[3][1];
  float S3 = rb[0][2] + rb[1][2] + rb[2][2] + rb[3][2];
  float S4 = rb[0][3] + rb[1][3] + rb[2][3] + rb[3][3];
  float muq = S1 * (1.0f / DMODEL), rsq = rsqrtf(S2 * (1.0f / DMODEL) - muq * muq + 1e-5f);
  float muk = S3 * (1.0f / DMODEL), rsk = rsqrtf(S4 * (1.0f / DMODEL) - muk * muk + 1e-5f);
  __shared__ float qs[1024], ks[1024];
  float4 qwv = ((const float4*)qw)[t];
  float4 kwv = ((const float4*)kw)[t];
  qs[t * 4 + 0] = (qx - muq) * rsq * qwv.x;  ks[t * 4 + 0] = (kx - muk) * rsk * kwv.x;
  qs[t * 4 + 1] = (qy - muq) * rsq * qwv.y;  ks[t * 4 + 1] = (ky - muk) * rsk * kwv.y;
  qs[t * 4 + 2] = (qz - muq) * rsq * qwv.z;  ks[t * 4 + 2] = (kz - muk) * rsk * kwv.z;
  qs[t * 4 + 3] = (qw_ - muq) * rsq * qwv.w; ks[t * 4 + 3] = (kw_ - muk) * rsk * kwv.w;
  __syncthreads();
  int d0 = t * 4;
  int hh = d0 >> 6;
  union { ushort4 v4; u16 e[4]; } qo, ko;
#pragma unroll
  for (int i = 0; i < 4; i++) {
    int d = d0 + i, dd = d & 63, fr = dd & 31;
    float c = cosb[l * 32 + fr], s = sinb[l * 32 + fr];
    float q1 = qs[d], q2 = (dd < 32) ? -qs[d + 32] : qs[d - 32];
    float k1 = ks[d], k2 = (dd < 32) ? -ks[d + 32] : ks[d - 32];
    qo.e[i] = f2bf(q1 * c + q2 * s);
    ko.e[i] = f2bf(k1 * c + k2 * s);
  }
  size_t oidx = ((size_t)(b * NHEAD + hh) * LSEQ + l) * DHEAD + (d0 & 63);
  *(ushort4*)(Q + oidx) = qo.v4;
  *(ushort4*)(K + oidx) = ko.v4;
  *(ushort4*)(V + oidx) = vu;
}

// ---------------- segment-masked flash attention (swapped-QK, fixed-shift SM) --
__global__ __launch_bounds__(256) void k_attn(const u16* __restrict__ Q, const u16* __restrict__ Kb,
                                              const u16* __restrict__ VTb, const int* __restrict__ seq,
                                              const int* __restrict__ bnd, u16* __restrict__ ctx) {
  __shared__ __align__(16) u16 Ks[2][64 * 64];
  __shared__ __align__(16) u16 Vs[2][64 * 64];
  __shared__ __align__(16) u16 Pw[4][16 * 64];

  const int bid = blockIdx.x;
  const int qt = bid & 31, h = (bid >> 5) & 15, b = bid >> 9;
  const int t = threadIdx.x, l = t & 63, w = t >> 6;
  const int c = l & 15, g = l >> 4;
  const int q0 = qt * 64;
  const size_t hoff = (size_t)(b * NHEAD + h) * LSEQ * DHEAD;
  const u16* Qg = Q + hoff;
  const u16* Kg = Kb + hoff;
  const u16* Vg = VTb + hoff;   // [d][l]
  const int* seqb = seq + b * LSEQ;
  const int* bnd5 = bnd + b * 5;

  const int qw0 = q0 + w * 16;
  const int myq = qw0 + c;
  const int sq = seqb[myq];
  const int lo = bnd5[sq], hi = bnd5[sq + 1];
  const int wlo = bnd5[seqb[qw0]];
  const int whi = bnd5[seqb[qw0 + 15] + 1];
  int kbeg = bnd5[seqb[q0]] & ~63;
  int kend = (bnd5[seqb[q0 + 63] + 1] + 63) & ~63;
  if (kend > LSEQ) kend = LSEQ;

  bf16x8 qf[2];
  qf[0] = *(const bf16x8*)(Qg + (size_t)myq * 64 + g * 8);
  qf[1] = *(const bf16x8*)(Qg + (size_t)myq * 64 + 32 + g * 8);

  f32x4 acc[4] = {};
  float lsum = 0.f;

#define STAGE(bb, kt_) do { \
    int r1 = w * 16 + (l >> 3); \
    int r2 = r1 + 8; \
    GLD((char*)Ks[bb] + (w * 2    ) * 1024, Kg + (size_t)((kt_) + r1) * 64 + (((l & 7) ^ (r1 & 7)) * 8)); \
    GLD((char*)Ks[bb] + (w * 2 + 1) * 1024, Kg + (size_t)((kt_) + r2) * 64 + (((l & 7) ^ (r2 & 7)) * 8)); \
    GLD((char*)Vs[bb] + (w * 2    ) * 1024, Vg + (size_t)r1 * LSEQ + (kt_) + (((l & 7) ^ (r1 & 7)) * 8)); \
    GLD((char*)Vs[bb] + (w * 2 + 1) * 1024, Vg + (size_t)r2 * LSEQ + (kt_) + (((l & 7) ^ (r2 & 7)) * 8)); \
  } while (0)

  STAGE(0, kbeg);
  int cur = 0;
  for (int kt = kbeg; kt < kend; kt += 64) {
    const bool more = (kt + 64) < kend;
    if (more) STAGE(cur ^ 1, kt + 64);
    if (more) VM(4);
    else      VM(0);
    __builtin_amdgcn_s_barrier();
    __builtin_amdgcn_sched_barrier(0);
    if (kt < whi && kt + 64 > wlo) {
      const u16* ksb = Ks[cur];
      const u16* vsb = Vs[cur];
      f32x4 st[4] = {};
#pragma unroll
      for (int kk = 0; kk < 2; kk++) {
        bf16x8 kf[4];
#pragma unroll
        for (int i = 0; i < 4; i++) {
          int row = i * 16 + c;
          kf[i] = *(const bf16x8*)((const char*)ksb + row * 128 + ((kk * 64 + g * 16) ^ ((row & 7) << 4)));
        }
#pragma unroll
        for (int i = 0; i < 4; i++)
          st[i] = __builtin_amdgcn_mfma_f32_16x16x32_bf16(kf[i], qf[kk], st[i], 0, 0, 0);
      }
      const int kb0 = kt + g * 4;
#pragma unroll
      for (int i = 0; i < 4; i++) {
        float p[4];
#pragma unroll
        for (int r = 0; r < 4; r++) {
          int kglob = kb0 + i * 16 + r;
          bool ok = ((unsigned)(kglob - lo)) < ((unsigned)(hi - lo));
          float x = ok ? fmaf(st[i][r], 0.125f, -8.0f) : -1e30f;
          p[r] = __expf(x);
          lsum += p[r];
        }
        unsigned w0, w1;
        asm("v_cvt_pk_bf16_f32 %0, %1, %2" : "=v"(w0) : "v"(p[0]), "v"(p[1]));
        asm("v_cvt_pk_bf16_f32 %0, %1, %2" : "=v"(w1) : "v"(p[2]), "v"(p[3]));
        uint2 wp; wp.x = w0; wp.y = w1;
        *(uint2*)((char*)Pw[w] + c * 128 + ((i * 32 + g * 8) ^ ((c & 3) << 4))) = wp;
      }
#pragma unroll
      for (int kk = 0; kk < 2; kk++) {
        bf16x8 pa = *(const bf16x8*)((char*)Pw[w] + c * 128 + ((kk * 64 + g * 16) ^ ((c & 3) << 4)));
        bf16x8 vf[4];
#pragma unroll
        for (int df = 0; df < 4; df++) {
          int row = df * 16 + c;
          vf[df] = *(const bf16x8*)((const char*)vsb + row * 128 + ((kk * 64 + g * 16) ^ ((row & 7) << 4)));
        }
#pragma unroll
        for (int df = 0; df < 4; df++)
          acc[df] = __builtin_amdgcn_mfma_f32_16x16x32_bf16(pa, vf[df], acc[df], 0, 0, 0);
      }
    }
    __builtin_amdgcn_sched_barrier(0);
    __builtin_amdgcn_s_barrier();
    cur ^= 1;
  }
#undef STAGE

  lsum += __shfl_xor(lsum, 16);
  lsum += __shfl_xor(lsum, 32);
#pragma unroll
  for (int r = 0; r < 4; r++) {
    float lr = __shfl(lsum, g * 4 + r, 64);
    float rls = 1.0f / lr;
    int qrow = qw0 + g * 4 + r;
    u16* op = ctx + (size_t)(b * LSEQ + qrow) * DMODEL + h * 64 + c;
#pragma unroll
    for (int df = 0; df < 4; df++)
      op[df * 16] = f2bf(acc[df][r] * rls);
  }
}

// ---------------- launch --------------------------------------------------------
extern "C" void kernel_launch(void* const* d_in, const int* in_sizes, int n_in,
                              void* d_out, int out_size, void* d_ws, size_t ws_size,
                              hipStream_t stream) {
  const float* x    = (const float*)d_in[0];
  const int*   seq  = (const int*)d_in[1];
  const float* ln1w = (const float*)d_in[2];
  const float* ln1b = (const float*)d_in[3];
  const float* wqkv = (const float*)d_in[4];
  const float* qlnw = (const float*)d_in[5];
  const float* klnw = (const float*)d_in[6];
  const float* wout = (const float*)d_in[7];
  float* out = (float*)d_out;

  char* p = (char*)d_ws;
  u16* wqkvT = (u16*)p;  p += (size_t)3072 * 1024 * 2;
  u16* woutT = (u16*)p;  p += (size_t)1024 * 1024 * 2;
  u16* hbuf  = (u16*)p;  p += (size_t)ROWS * DMODEL * 2;
  u16* Qb    = (u16*)p;  p += (size_t)ROWS * DMODEL * 2;
  u16* Kbuf  = (u16*)p;  p += (size_t)ROWS * DMODEL * 2;
  u16* Vbuf  = (u16*)p;  p += (size_t)ROWS * DMODEL * 2;
  u16* VTbuf = (u16*)p;  p += (size_t)ROWS * DMODEL * 2;
  u16* ctxb  = (u16*)p;  p += (size_t)ROWS * DMODEL * 2;
  float* cosb = (float*)p; p += (size_t)LSEQ * 32 * 4;
  float* sinb = (float*)p; p += (size_t)LSEQ * 32 * 4;
  int* bnd   = (int*)p;  p += 256;
  u16* qkv   = (u16*)p;  p += (size_t)ROWS * 3072 * 2;

  k_transpose_cvt<<<dim3(3072 / 32, 1024 / 32), dim3(32, 8), 0, stream>>>(wqkv, wqkvT, 1024, 3072);
  k_transpose_cvt<<<dim3(1024 / 32, 1024 / 32), dim3(32, 8), 0, stream>>>(wout, woutT, 1024, 1024);
  k_rope_tables<<<(LSEQ * 32) / 256, 256, 0, stream>>>(cosb, sinb, seq, bnd);
  k_ln1<<<ROWS, 256, 0, stream>>>(x, ln1w, ln1b, hbuf);
  k_gemm256<1><<<(ROWS / 256) * (3072 / 256), 512, 0, stream>>>(hbuf, wqkvT, (void*)qkv, ROWS, 3072, 1024);
  k_qk_ln_rope<<<ROWS, 256, 0, stream>>>(qkv, qlnw, klnw, cosb, sinb, Qb, Kbuf, Vbuf);
  k_transpose_u16<<<dim3(DHEAD / 32, LSEQ / 32, BATCH * NHEAD), dim3(32, 8), 0, stream>>>(Vbuf, VTbuf);
  k_attn<<<BATCH * NHEAD * (LSEQ / 64), 256, 0, stream>>>(Qb, Kbuf, VTbuf, seq, bnd, ctxb);
  k_gemm_bt<0><<<dim3(1024 / 128, ROWS / 128), 256, 0, stream>>>(ctxb, woutT, (void*)out, ROWS, 1024, 1024);
}

// Round 8
// 132.904 us; speedup vs baseline: 1.0533x; 1.0361x over previous
//
#include <hip/hip_runtime.h>
#include <hip/hip_bf16.h>
#include <cstdint>
#include <math.h>

#define LSEQ 2048
#define BATCH 2
#define NHEAD 16
#define DHEAD 64
#define DMODEL 1024
#define ROWS (BATCH*LSEQ)

typedef __bf16 bf16x8 __attribute__((ext_vector_type(8)));
typedef float f32x4 __attribute__((ext_vector_type(4)));
typedef unsigned short u16;

#define GLD(lds_base, src_g) \
  __builtin_amdgcn_global_load_lds((const __attribute__((address_space(1))) void*)(src_g), \
                                   (__attribute__((address_space(3))) void*)(lds_base), 16, 0, 0)
#define VM(n) asm volatile("s_waitcnt vmcnt(" #n ")" ::: "memory")

__device__ __forceinline__ u16 f2bf(float f) {
  unsigned int u = __float_as_uint(f);
  u += 0x7fffu + ((u >> 16) & 1u);
  return (u16)(u >> 16);
}
__device__ __forceinline__ float bf2f(u16 u) {
  return __uint_as_float(((unsigned)u) << 16);
}

// ---------------- transpose + fp32->bf16 convert: out[c][r] = bf16(in[r][c]) ----
__global__ void k_transpose_cvt(const float* __restrict__ in, u16* __restrict__ out, int R, int C) {
  __shared__ float tile[32][33];
  int c0 = blockIdx.x * 32, r0 = blockIdx.y * 32;
  int tx = threadIdx.x, ty = threadIdx.y;
#pragma unroll
  for (int i = 0; i < 32; i += 8)
    tile[ty + i][tx] = in[(size_t)(r0 + ty + i) * C + (c0 + tx)];
  __syncthreads();
#pragma unroll
  for (int i = 0; i < 32; i += 8)
    out[(size_t)(c0 + ty + i) * R + (r0 + tx)] = f2bf(tile[tx][ty + i]);
}

// ---------------- u16 transpose per head: in [L][64] -> out [64][L] ------------
__global__ void k_transpose_u16(const u16* __restrict__ in, u16* __restrict__ out) {
  __shared__ u16 tile[32][33];
  int hd = blockIdx.z;
  int l0 = blockIdx.y * 32, d0 = blockIdx.x * 32;
  const u16* ip = in + (size_t)hd * LSEQ * DHEAD;
  u16* op = out + (size_t)hd * LSEQ * DHEAD;
  int tx = threadIdx.x, ty = threadIdx.y;
#pragma unroll
  for (int i = 0; i < 32; i += 8)
    tile[ty + i][tx] = ip[(size_t)(l0 + ty + i) * DHEAD + d0 + tx];
  __syncthreads();
#pragma unroll
  for (int i = 0; i < 32; i += 8)
    op[(size_t)(d0 + ty + i) * LSEQ + l0 + tx] = tile[tx][ty + i];
}

// ---------------- RoPE tables + segment bounds (fused) -------------------------
__global__ void k_rope_tables(float* __restrict__ cosb, float* __restrict__ sinb,
                              const int* __restrict__ seq, int* __restrict__ bnd) {
  if (blockIdx.x == 0 && threadIdx.x < BATCH * 5) {
    int b = threadIdx.x / 5, s = threadIdx.x % 5;
    const int* row = seq + b * LSEQ;
    int lo = 0, hi = LSEQ;
    while (lo < hi) { int mid = (lo + hi) >> 1; if (row[mid] < s) lo = mid + 1; else hi = mid; }
    bnd[b * 5 + s] = lo;
  }
  int idx = blockIdx.x * blockDim.x + threadIdx.x;
  if (idx >= LSEQ * 32) return;
  int l = idx >> 5, f = idx & 31;
  double inv = pow(10000.0, -(double)f / 32.0);
  float ang = (float)l * (float)inv;
  cosb[idx] = cosf(ang);
  sinb[idx] = sinf(ang);
}

// ---------------- LN1: h = bf16(layernorm(x, w, b)) ----------------------------
__global__ __launch_bounds__(256) void k_ln1(const float* __restrict__ x, const float* __restrict__ w,
                                             const float* __restrict__ bias, u16* __restrict__ h) {
  int row = blockIdx.x, t = threadIdx.x;
  const float4 xv = ((const float4*)(x + (size_t)row * DMODEL))[t];
  float s = xv.x + xv.y + xv.z + xv.w;
  float s2 = xv.x * xv.x + xv.y * xv.y + xv.z * xv.z + xv.w * xv.w;
#pragma unroll
  for (int m2 = 1; m2 < 64; m2 <<= 1) { s += __shfl_xor(s, m2); s2 += __shfl_xor(s2, m2); }
  __shared__ float rb[2][4];
  int wv = t >> 6;
  if ((t & 63) == 0) { rb[0][wv] = s; rb[1][wv] = s2; }
  __syncthreads();
  s  = rb[0][0] + rb[0][1] + rb[0][2] + rb[0][3];
  s2 = rb[1][0] + rb[1][1] + rb[1][2] + rb[1][3];
  float mu = s * (1.0f / DMODEL);
  float rs = rsqrtf(s2 * (1.0f / DMODEL) - mu * mu + 1e-5f);
  const float4 wv4 = ((const float4*)w)[t];
  const float4 bv4 = ((const float4*)bias)[t];
  ushort4 o;
  o.x = f2bf((xv.x - mu) * rs * wv4.x + bv4.x);
  o.y = f2bf((xv.y - mu) * rs * wv4.y + bv4.y);
  o.z = f2bf((xv.z - mu) * rs * wv4.z + bv4.z);
  o.w = f2bf((xv.w - mu) * rs * wv4.w + bv4.w);
  ((ushort4*)(h + (size_t)row * DMODEL))[t] = o;
}

// ============ 256x192 4-phase GEMM, C = A @ B^T (grid fills 256 CUs) ===========
// 512 thr = 8 waves (2M x 4N); per-wave 128x48 (acc[8][3]). BK=64, 2 K-tiles/iter.
// A staged as 2 halves x 2 chunks; B staged as 3 chunks (192 rows). vmcnt(2) at
// P2/P4 drains exactly the 7 loads of the buffer about to be read.
template<int OUTMODE>
__global__ __launch_bounds__(512, 2) void k_gemm256(const u16* __restrict__ A, const u16* __restrict__ B,
                                                    void* __restrict__ Cv, int M, int N, int K) {
  __shared__ __align__(16) u16 As[2][256 * 64];   // 32 KB per buffer
  __shared__ __align__(16) u16 Bs[2][192 * 64];   // 24 KB per buffer
  const int t = threadIdx.x, lane = t & 63, w = t >> 6;
  const int wr = w >> 2, wc = w & 3;
  const int nbx = N / 192;                        // 16
  const int nwg = nbx * (M >> 8);                 // 256
  const int cpx = nwg >> 3;
  const int bid = blockIdx.x;
  const int sw = (bid & 7) * cpx + (bid >> 3);    // XCD swizzle (nwg % 8 == 0)
  const int m0 = (sw / nbx) * 256, n0 = (sw % nbx) * 192;
  const int NT = K >> 6;                          // 16
  const int cg16 = (lane >> 4) * 16;

  f32x4 acc[8][3] = {};
  const u16* Ap = A + (size_t)m0 * K;
  const u16* Bp = B + (size_t)n0 * K;
  const int rr0 = t >> 3;
  const int sz = ((t & 7) * 8) ^ ((rr0 & 7) << 3);   // u16 units (inverse swizzle)
  const u16* pA[4] = { Ap + (size_t)rr0 * K + sz,
                       Ap + (size_t)(rr0 + 64) * K + sz,
                       Ap + (size_t)(rr0 + 128) * K + sz,
                       Ap + (size_t)(rr0 + 192) * K + sz };
  const u16* pB[3] = { Bp + (size_t)rr0 * K + sz,
                       Bp + (size_t)(rr0 + 64) * K + sz,
                       Bp + (size_t)(rr0 + 128) * K + sz };

// EO = element offset (u16): K-tile delta (64 per tile)
#define SA2(b, h, EO) do { \
    GLD((char*)As + (b)*32768 + (h)*16384 + w*1024,        pA[(h)*2]     + (EO)); \
    GLD((char*)As + (b)*32768 + (h)*16384 + 8192 + w*1024, pA[(h)*2 + 1] + (EO)); \
  } while (0)
#define SB3(b, EO) do { \
    GLD((char*)Bs + (b)*24576 +         w*1024, pB[0] + (EO)); \
    GLD((char*)Bs + (b)*24576 +  8192 + w*1024, pB[1] + (EO)); \
    GLD((char*)Bs + (b)*24576 + 16384 + w*1024, pB[2] + (EO)); \
  } while (0)

#define PHASEM(asb, bsb, mh, STG, WVM) do { \
    bf16x8 af_[4][2], bf_[3][2]; \
    _Pragma("unroll") for (int i2 = 0; i2 < 4; i2++) { \
      const int rowA = (((mh)*4 + i2)*2 + wr)*16 + (lane & 15); \
      const int sA = (rowA & 7) << 4; \
      _Pragma("unroll") for (int kk = 0; kk < 2; kk++) \
        af_[i2][kk] = *(const bf16x8*)((const char*)(asb) + (rowA & 127)*128 + ((kk*64 + cg16) ^ sA)); \
    } \
    _Pragma("unroll") for (int j2 = 0; j2 < 3; j2++) { \
      const int rowB = (j2*4 + wc)*16 + (lane & 15); \
      const int sB = (rowB & 7) << 4; \
      _Pragma("unroll") for (int kk = 0; kk < 2; kk++) \
        bf_[j2][kk] = *(const bf16x8*)((const char*)(bsb) + rowB*128 + ((kk*64 + cg16) ^ sB)); \
    } \
    STG; \
    __builtin_amdgcn_s_barrier(); \
    asm volatile("s_waitcnt lgkmcnt(0)" ::: "memory"); \
    __builtin_amdgcn_s_setprio(1); \
    _Pragma("unroll") for (int i2 = 0; i2 < 4; i2++) \
      _Pragma("unroll") for (int j2 = 0; j2 < 3; j2++) \
        _Pragma("unroll") for (int kk = 0; kk < 2; kk++) \
          acc[(mh)*4+i2][j2] = __builtin_amdgcn_mfma_f32_16x16x32_bf16( \
              af_[i2][kk], bf_[j2][kk], acc[(mh)*4+i2][j2], 0, 0, 0); \
    __builtin_amdgcn_s_setprio(0); \
    WVM; \
    __builtin_amdgcn_s_barrier(); \
  } while (0)

  // prologue: buf0 tile0 full (A 4 + B 3 = 7 loads) + buf1 A h0 of tile1 (2)
  SA2(0, 0, 0); SA2(0, 1, 0); SB3(0, 0);
  SA2(1, 0, 64);
  VM(2);
  __builtin_amdgcn_s_barrier();

  const char* a0  = (const char*)As;
  const char* a0h = a0 + 16384;
  const char* a1  = a0 + 32768;
  const char* a1h = a0 + 49152;
  const char* b0  = (const char*)Bs;
  const char* b1  = b0 + 24576;
  const int NIT = NT >> 1;
  for (int i = 0; i < NIT; i++) {
    const bool lst = (i == NIT - 1);
    PHASEM(a0,  b0, 0, { SA2(1, 1, 64); SB3(1, 64); }, {});
    PHASEM(a0h, b0, 1, { if (!lst) SA2(0, 0, 128); },
                       { if (lst) VM(0); else VM(2); });
    PHASEM(a1,  b1, 0, { if (!lst) { SA2(0, 1, 128); SB3(0, 128); } }, {});
    PHASEM(a1h, b1, 1, { if (!lst) SA2(1, 0, 192); },
                       { if (!lst) VM(2); });
    pA[0] += 128; pA[1] += 128; pA[2] += 128; pA[3] += 128;
    pB[0] += 128; pB[1] += 128; pB[2] += 128;
  }
#undef PHASEM
#undef SA2
#undef SB3

  const int cr = (lane >> 4) * 4, cc = lane & 15;
#pragma unroll
  for (int fi = 0; fi < 8; fi++)
#pragma unroll
    for (int fj = 0; fj < 3; fj++) {
      const size_t roff = (size_t)(m0 + (fi * 2 + wr) * 16 + cr) * N + (n0 + (fj * 4 + wc) * 16 + cc);
      if (OUTMODE == 0) {
        float* Cp = (float*)Cv + roff;
#pragma unroll
        for (int r = 0; r < 4; r++) Cp[(size_t)r * N] = acc[fi][fj][r];
      } else {
        u16* Cp = (u16*)Cv + roff;
#pragma unroll
        for (int r = 0; r < 4; r++) Cp[(size_t)r * N] = f2bf(acc[fi][fj][r]);
      }
    }
}

// ---------------- bf16 GEMM 128^2 2-phase (used for GEMM2) ---------------------
template<int OUTMODE>
__global__ __launch_bounds__(256) void k_gemm_bt(const u16* __restrict__ A, const u16* __restrict__ B,
                                                 void* __restrict__ Cv, int M, int N, int K) {
  __shared__ __align__(16) u16 As[2][128 * 64];
  __shared__ __align__(16) u16 Bs[2][128 * 64];
  const int t = threadIdx.x;
  const int lane = t & 63, w = t >> 6;
  const int m0 = blockIdx.y * 128, n0 = blockIdx.x * 128;
  const int wm = (w >> 1) * 64, wn = (w & 1) * 64;
  const int NT = K >> 6;
  f32x4 acc[4][4] = {};
  const u16* Ap = A + (size_t)m0 * K;
  const u16* Bp = B + (size_t)n0 * K;
  const int cr0 = lane >> 3, cs = lane & 7;

#define GSTAGE(bb, kt_) do { \
    _Pragma("unroll") \
    for (int s2 = 0; s2 < 4; s2++) { \
      int ch = w * 4 + s2; \
      int row = ch * 8 + cr0; \
      int cb = cs ^ (row & 7); \
      GLD((char*)As[bb] + ch * 1024, Ap + (size_t)row * K + (kt_) * 64 + cb * 8); \
      GLD((char*)Bs[bb] + ch * 1024, Bp + (size_t)row * K + (kt_) * 64 + cb * 8); \
    } } while (0)

  GSTAGE(0, 0);
  VM(0);
  __builtin_amdgcn_s_barrier();
  int cur = 0;
  for (int kt = 0; kt < NT; kt++) {
    if (kt + 1 < NT) GSTAGE(cur ^ 1, kt + 1);
    const u16* asb = As[cur];
    const u16* bsb = Bs[cur];
#pragma unroll
    for (int kk = 0; kk < 2; kk++) {
      bf16x8 af[4], bfr[4];
#pragma unroll
      for (int i = 0; i < 4; i++) {
        int rowa = wm + i * 16 + (lane & 15);
        af[i] = *(const bf16x8*)((const char*)asb + rowa * 128 + ((kk * 64 + (lane >> 4) * 16) ^ ((rowa & 7) << 4)));
        int rowb = wn + i * 16 + (lane & 15);
        bfr[i] = *(const bf16x8*)((const char*)bsb + rowb * 128 + ((kk * 64 + (lane >> 4) * 16) ^ ((rowb & 7) << 4)));
      }
#pragma unroll
      for (int mf = 0; mf < 4; mf++)
#pragma unroll
        for (int nf = 0; nf < 4; nf++)
          acc[mf][nf] = __builtin_amdgcn_mfma_f32_16x16x32_bf16(af[mf], bfr[nf], acc[mf][nf], 0, 0, 0);
    }
    VM(0);
    __builtin_amdgcn_s_barrier();
    cur ^= 1;
  }
#undef GSTAGE
  const int cr = (lane >> 4) * 4, cc = lane & 15;
#pragma unroll
  for (int mf = 0; mf < 4; mf++)
#pragma unroll
    for (int nf = 0; nf < 4; nf++) {
      if (OUTMODE == 0) {
        float* Cp = (float*)Cv + (size_t)(m0 + wm + mf * 16 + cr) * N + (n0 + wn + nf * 16 + cc);
#pragma unroll
        for (int r = 0; r < 4; r++) Cp[(size_t)r * N] = acc[mf][nf][r];
      } else {
        u16* Cp = (u16*)Cv + (size_t)(m0 + wm + mf * 16 + cr) * N + (n0 + wn + nf * 16 + cc);
#pragma unroll
        for (int r = 0; r < 4; r++) Cp[(size_t)r * N] = f2bf(acc[mf][nf][r]);
      }
    }
}

// ---------------- q/k layernorm (over full D, bf16 in) + RoPE + head split -----
__global__ __launch_bounds__(256) void k_qk_ln_rope(const u16* __restrict__ qkv,
                                                    const float* __restrict__ qw, const float* __restrict__ kw,
                                                    const float* __restrict__ cosb, const float* __restrict__ sinb,
                                                    u16* __restrict__ Q, u16* __restrict__ K, u16* __restrict__ V) {
  int row = blockIdx.x, t = threadIdx.x;
  int b = row >> 11, l = row & 2047;
  const u16* base = qkv + (size_t)row * 3072;
  ushort4 qu = ((const ushort4*)base)[t];
  ushort4 ku = ((const ushort4*)(base + 1024))[t];
  ushort4 vu = ((const ushort4*)(base + 2048))[t];
  float qx = bf2f(qu.x), qy = bf2f(qu.y), qz = bf2f(qu.z), qw_ = bf2f(qu.w);
  float kx = bf2f(ku.x), ky = bf2f(ku.y), kz = bf2f(ku.z), kw_ = bf2f(ku.w);
  float red[4];
  red[0] = qx + qy + qz + qw_;
  red[1] = qx * qx + qy * qy + qz * qz + qw_ * qw_;
  red[2] = kx + ky + kz + kw_;
  red[3] = kx * kx + ky * ky + kz * kz + kw_ * kw_;
#pragma unroll
  for (int i = 0; i < 4; i++)
#pragma unroll
    for (int m2 = 1; m2 < 64; m2 <<= 1) red[i] += __shfl_xor(red[i], m2);
  __shared__ float rb[4][4];
  int w = t >> 6;
  if ((t & 63) == 0) { rb[w][0] = red[0]; rb[w][1] = red[1]; rb[w][2] = red[2]; rb[w][3] = red[3]; }
  __syncthreads();
  float S1 = rb[0][0] + rb[1][0] + rb[2][0] + rb[3][0];
  float S2 = rb[0][1] + rb[1][1] + rb[2][1] + rb[3][1];
  float S3 = rb[0][2] + rb[1][2] + rb[2][2] + rb[3][2];
  float S4 = rb[0][3] + rb[1][3] + rb[2][3] + rb[3][3];
  float muq = S1 * (1.0f / DMODEL), rsq = rsqrtf(S2 * (1.0f / DMODEL) - muq * muq + 1e-5f);
  float muk = S3 * (1.0f / DMODEL), rsk = rsqrtf(S4 * (1.0f / DMODEL) - muk * muk + 1e-5f);
  __shared__ float qs[1024], ks[1024];
  float4 qwv = ((const float4*)qw)[t];
  float4 kwv = ((const float4*)kw)[t];
  qs[t * 4 + 0] = (qx - muq) * rsq * qwv.x;  ks[t * 4 + 0] = (kx - muk) * rsk * kwv.x;
  qs[t * 4 + 1] = (qy - muq) * rsq * qwv.y;  ks[t * 4 + 1] = (ky - muk) * rsk * kwv.y;
  qs[t * 4 + 2] = (qz - muq) * rsq * qwv.z;  ks[t * 4 + 2] = (kz - muk) * rsk * kwv.z;
  qs[t * 4 + 3] = (qw_ - muq) * rsq * qwv.w; ks[t * 4 + 3] = (kw_ - muk) * rsk * kwv.w;
  __syncthreads();
  int d0 = t * 4;
  int hh = d0 >> 6;
  union { ushort4 v4; u16 e[4]; } qo, ko;
#pragma unroll
  for (int i = 0; i < 4; i++) {
    int d = d0 + i, dd = d & 63, fr = dd & 31;
    float c = cosb[l * 32 + fr], s = sinb[l * 32 + fr];
    float q1 = qs[d], q2 = (dd < 32) ? -qs[d + 32] : qs[d - 32];
    float k1 = ks[d], k2 = (dd < 32) ? -ks[d + 32] : ks[d - 32];
    qo.e[i] = f2bf(q1 * c + q2 * s);
    ko.e[i] = f2bf(k1 * c + k2 * s);
  }
  size_t oidx = ((size_t)(b * NHEAD + hh) * LSEQ + l) * DHEAD + (d0 & 63);
  *(ushort4*)(Q + oidx) = qo.v4;
  *(ushort4*)(K + oidx) = ko.v4;
  *(ushort4*)(V + oidx) = vu;
}

// ---------------- segment-masked flash attention (swapped-QK, fixed-shift SM) --
__global__ __launch_bounds__(256) void k_attn(const u16* __restrict__ Q, const u16* __restrict__ Kb,
                                              const u16* __restrict__ VTb, const int* __restrict__ seq,
                                              const int* __restrict__ bnd, u16* __restrict__ ctx) {
  __shared__ __align__(16) u16 Ks[2][64 * 64];
  __shared__ __align__(16) u16 Vs[2][64 * 64];
  __shared__ __align__(16) u16 Pw[4][16 * 64];

  const int bid = blockIdx.x;
  const int qt = bid & 31, h = (bid >> 5) & 15, b = bid >> 9;
  const int t = threadIdx.x, l = t & 63, w = t >> 6;
  const int c = l & 15, g = l >> 4;
  const int q0 = qt * 64;
  const size_t hoff = (size_t)(b * NHEAD + h) * LSEQ * DHEAD;
  const u16* Qg = Q + hoff;
  const u16* Kg = Kb + hoff;
  const u16* Vg = VTb + hoff;   // [d][l]
  const int* seqb = seq + b * LSEQ;
  const int* bnd5 = bnd + b * 5;

  const int qw0 = q0 + w * 16;
  const int myq = qw0 + c;
  const int sq = seqb[myq];
  const int lo = bnd5[sq], hi = bnd5[sq + 1];
  const int wlo = bnd5[seqb[qw0]];
  const int whi = bnd5[seqb[qw0 + 15] + 1];
  int kbeg = bnd5[seqb[q0]] & ~63;
  int kend = (bnd5[seqb[q0 + 63] + 1] + 63) & ~63;
  if (kend > LSEQ) kend = LSEQ;

  bf16x8 qf[2];
  qf[0] = *(const bf16x8*)(Qg + (size_t)myq * 64 + g * 8);
  qf[1] = *(const bf16x8*)(Qg + (size_t)myq * 64 + 32 + g * 8);

  f32x4 acc[4] = {};
  float lsum = 0.f;

#define STAGE(bb, kt_) do { \
    int r1 = w * 16 + (l >> 3); \
    int r2 = r1 + 8; \
    GLD((char*)Ks[bb] + (w * 2    ) * 1024, Kg + (size_t)((kt_) + r1) * 64 + (((l & 7) ^ (r1 & 7)) * 8)); \
    GLD((char*)Ks[bb] + (w * 2 + 1) * 1024, Kg + (size_t)((kt_) + r2) * 64 + (((l & 7) ^ (r2 & 7)) * 8)); \
    GLD((char*)Vs[bb] + (w * 2    ) * 1024, Vg + (size_t)r1 * LSEQ + (kt_) + (((l & 7) ^ (r1 & 7)) * 8)); \
    GLD((char*)Vs[bb] + (w * 2 + 1) * 1024, Vg + (size_t)r2 * LSEQ + (kt_) + (((l & 7) ^ (r2 & 7)) * 8)); \
  } while (0)

  STAGE(0, kbeg);
  int cur = 0;
  for (int kt = kbeg; kt < kend; kt += 64) {
    const bool more = (kt + 64) < kend;
    if (more) STAGE(cur ^ 1, kt + 64);
    if (more) VM(4);
    else      VM(0);
    __builtin_amdgcn_s_barrier();
    __builtin_amdgcn_sched_barrier(0);
    if (kt < whi && kt + 64 > wlo) {
      const u16* ksb = Ks[cur];
      const u16* vsb = Vs[cur];
      f32x4 st[4] = {};
#pragma unroll
      for (int kk = 0; kk < 2; kk++) {
        bf16x8 kf[4];
#pragma unroll
        for (int i = 0; i < 4; i++) {
          int row = i * 16 + c;
          kf[i] = *(const bf16x8*)((const char*)ksb + row * 128 + ((kk * 64 + g * 16) ^ ((row & 7) << 4)));
        }
#pragma unroll
        for (int i = 0; i < 4; i++)
          st[i] = __builtin_amdgcn_mfma_f32_16x16x32_bf16(kf[i], qf[kk], st[i], 0, 0, 0);
      }
      const int kb0 = kt + g * 4;
#pragma unroll
      for (int i = 0; i < 4; i++) {
        float p[4];
#pragma unroll
        for (int r = 0; r < 4; r++) {
          int kglob = kb0 + i * 16 + r;
          bool ok = ((unsigned)(kglob - lo)) < ((unsigned)(hi - lo));
          float x = ok ? fmaf(st[i][r], 0.125f, -8.0f) : -1e30f;
          p[r] = __expf(x);
          lsum += p[r];
        }
        unsigned w0, w1;
        asm("v_cvt_pk_bf16_f32 %0, %1, %2" : "=v"(w0) : "v"(p[0]), "v"(p[1]));
        asm("v_cvt_pk_bf16_f32 %0, %1, %2" : "=v"(w1) : "v"(p[2]), "v"(p[3]));
        uint2 wp; wp.x = w0; wp.y = w1;
        *(uint2*)((char*)Pw[w] + c * 128 + ((i * 32 + g * 8) ^ ((c & 3) << 4))) = wp;
      }
#pragma unroll
      for (int kk = 0; kk < 2; kk++) {
        bf16x8 pa = *(const bf16x8*)((char*)Pw[w] + c * 128 + ((kk * 64 + g * 16) ^ ((c & 3) << 4)));
        bf16x8 vf[4];
#pragma unroll
        for (int df = 0; df < 4; df++) {
          int row = df * 16 + c;
          vf[df] = *(const bf16x8*)((const char*)vsb + row * 128 + ((kk * 64 + g * 16) ^ ((row & 7) << 4)));
        }
#pragma unroll
        for (int df = 0; df < 4; df++)
          acc[df] = __builtin_amdgcn_mfma_f32_16x16x32_bf16(pa, vf[df], acc[df], 0, 0, 0);
      }
    }
    __builtin_amdgcn_sched_barrier(0);
    __builtin_amdgcn_s_barrier();
    cur ^= 1;
  }
#undef STAGE

  lsum += __shfl_xor(lsum, 16);
  lsum += __shfl_xor(lsum, 32);
#pragma unroll
  for (int r = 0; r < 4; r++) {
    float lr = __shfl(lsum, g * 4 + r, 64);
    float rls = 1.0f / lr;
    int qrow = qw0 + g * 4 + r;
    u16* op = ctx + (size_t)(b * LSEQ + qrow) * DMODEL + h * 64 + c;
#pragma unroll
    for (int df = 0; df < 4; df++)
      op[df * 16] = f2bf(acc[df][r] * rls);
  }
}

// ---------------- launch --------------------------------------------------------
extern "C" void kernel_launch(void* const* d_in, const int* in_sizes, int n_in,
                              void* d_out, int out_size, void* d_ws, size_t ws_size,
                              hipStream_t stream) {
  const float* x    = (const float*)d_in[0];
  const int*   seq  = (const int*)d_in[1];
  const float* ln1w = (const float*)d_in[2];
  const float* ln1b = (const float*)d_in[3];
  const float* wqkv = (const float*)d_in[4];
  const float* qlnw = (const float*)d_in[5];
  const float* klnw = (const float*)d_in[6];
  const float* wout = (const float*)d_in[7];
  float* out = (float*)d_out;

  char* p = (char*)d_ws;
  u16* wqkvT = (u16*)p;  p += (size_t)3072 * 1024 * 2;
  u16* woutT = (u16*)p;  p += (size_t)1024 * 1024 * 2;
  u16* hbuf  = (u16*)p;  p += (size_t)ROWS * DMODEL * 2;
  u16* Qb    = (u16*)p;  p += (size_t)ROWS * DMODEL * 2;
  u16* Kbuf  = (u16*)p;  p += (size_t)ROWS * DMODEL * 2;
  u16* Vbuf  = (u16*)p;  p += (size_t)ROWS * DMODEL * 2;
  u16* VTbuf = (u16*)p;  p += (size_t)ROWS * DMODEL * 2;
  u16* ctxb  = (u16*)p;  p += (size_t)ROWS * DMODEL * 2;
  float* cosb = (float*)p; p += (size_t)LSEQ * 32 * 4;
  float* sinb = (float*)p; p += (size_t)LSEQ * 32 * 4;
  int* bnd   = (int*)p;  p += 256;
  u16* qkv   = (u16*)p;  p += (size_t)ROWS * 3072 * 2;

  k_transpose_cvt<<<dim3(3072 / 32, 1024 / 32), dim3(32, 8), 0, stream>>>(wqkv, wqkvT, 1024, 3072);
  k_transpose_cvt<<<dim3(1024 / 32, 1024 / 32), dim3(32, 8), 0, stream>>>(wout, woutT, 1024, 1024);
  k_rope_tables<<<(LSEQ * 32) / 256, 256, 0, stream>>>(cosb, sinb, seq, bnd);
  k_ln1<<<ROWS, 256, 0, stream>>>(x, ln1w, ln1b, hbuf);
  k_gemm256<1><<<(ROWS / 256) * (3072 / 192), 512, 0, stream>>>(hbuf, wqkvT, (void*)qkv, ROWS, 3072, 1024);
  k_qk_ln_rope<<<ROWS, 256, 0, stream>>>(qkv, qlnw, klnw, cosb, sinb, Qb, Kbuf, Vbuf);
  k_transpose_u16<<<dim3(DHEAD / 32, LSEQ / 32, BATCH * NHEAD), dim3(32, 8), 0, stream>>>(Vbuf, VTbuf);
  k_attn<<<BATCH * NHEAD * (LSEQ / 64), 256, 0, stream>>>(Qb, Kbuf, VTbuf, seq, bnd, ctxb);
  k_gemm_bt<0><<<dim3(1024 / 128, ROWS / 128), 256, 0, stream>>>(ctxb, woutT, (void*)out, ROWS, 1024, 1024);
}

// Round 9
// 123.556 us; speedup vs baseline: 1.1330x; 1.0757x over previous
//
#include <hip/hip_runtime.h>
#include <hip/hip_bf16.h>
#include <cstdint>
#include <math.h>

#define LSEQ 2048
#define BATCH 2
#define NHEAD 16
#define DHEAD 64
#define DMODEL 1024
#define ROWS (BATCH*LSEQ)

typedef __bf16 bf16x8 __attribute__((ext_vector_type(8)));
typedef float f32x4 __attribute__((ext_vector_type(4)));
typedef unsigned short u16;

#define GLD(lds_base, src_g) \
  __builtin_amdgcn_global_load_lds((const __attribute__((address_space(1))) void*)(src_g), \
                                   (__attribute__((address_space(3))) void*)(lds_base), 16, 0, 0)
#define VM(n) asm volatile("s_waitcnt vmcnt(" #n ")" ::: "memory")

__device__ __forceinline__ u16 f2bf(float f) {
  unsigned int u = __float_as_uint(f);
  u += 0x7fffu + ((u >> 16) & 1u);
  return (u16)(u >> 16);
}
__device__ __forceinline__ float bf2f(u16 u) {
  return __uint_as_float(((unsigned)u) << 16);
}

// ---------------- transpose + fp32->bf16 convert: out[c][r] = bf16(in[r][c]) ----
__global__ void k_transpose_cvt(const float* __restrict__ in, u16* __restrict__ out, int R, int C) {
  __shared__ float tile[32][33];
  int c0 = blockIdx.x * 32, r0 = blockIdx.y * 32;
  int tx = threadIdx.x, ty = threadIdx.y;
#pragma unroll
  for (int i = 0; i < 32; i += 8)
    tile[ty + i][tx] = in[(size_t)(r0 + ty + i) * C + (c0 + tx)];
  __syncthreads();
#pragma unroll
  for (int i = 0; i < 32; i += 8)
    out[(size_t)(c0 + ty + i) * R + (r0 + tx)] = f2bf(tile[tx][ty + i]);
}

// ---------------- u16 transpose per head: in [L][64] -> out [64][L] ------------
__global__ void k_transpose_u16(const u16* __restrict__ in, u16* __restrict__ out) {
  __shared__ u16 tile[32][33];
  int hd = blockIdx.z;
  int l0 = blockIdx.y * 32, d0 = blockIdx.x * 32;
  const u16* ip = in + (size_t)hd * LSEQ * DHEAD;
  u16* op = out + (size_t)hd * LSEQ * DHEAD;
  int tx = threadIdx.x, ty = threadIdx.y;
#pragma unroll
  for (int i = 0; i < 32; i += 8)
    tile[ty + i][tx] = ip[(size_t)(l0 + ty + i) * DHEAD + d0 + tx];
  __syncthreads();
#pragma unroll
  for (int i = 0; i < 32; i += 8)
    op[(size_t)(d0 + ty + i) * LSEQ + l0 + tx] = tile[tx][ty + i];
}

// ---------------- RoPE tables + segment bounds (fused) -------------------------
__global__ void k_rope_tables(float* __restrict__ cosb, float* __restrict__ sinb,
                              const int* __restrict__ seq, int* __restrict__ bnd) {
  if (blockIdx.x == 0 && threadIdx.x < BATCH * 5) {
    int b = threadIdx.x / 5, s = threadIdx.x % 5;
    const int* row = seq + b * LSEQ;
    int lo = 0, hi = LSEQ;
    while (lo < hi) { int mid = (lo + hi) >> 1; if (row[mid] < s) lo = mid + 1; else hi = mid; }
    bnd[b * 5 + s] = lo;
  }
  int idx = blockIdx.x * blockDim.x + threadIdx.x;
  if (idx >= LSEQ * 32) return;
  int l = idx >> 5, f = idx & 31;
  double inv = pow(10000.0, -(double)f / 32.0);
  float ang = (float)l * (float)inv;
  cosb[idx] = cosf(ang);
  sinb[idx] = sinf(ang);
}

// ---------------- LN1: h = bf16(layernorm(x, w, b)) ----------------------------
__global__ __launch_bounds__(256) void k_ln1(const float* __restrict__ x, const float* __restrict__ w,
                                             const float* __restrict__ bias, u16* __restrict__ h) {
  int row = blockIdx.x, t = threadIdx.x;
  const float4 xv = ((const float4*)(x + (size_t)row * DMODEL))[t];
  float s = xv.x + xv.y + xv.z + xv.w;
  float s2 = xv.x * xv.x + xv.y * xv.y + xv.z * xv.z + xv.w * xv.w;
#pragma unroll
  for (int m2 = 1; m2 < 64; m2 <<= 1) { s += __shfl_xor(s, m2); s2 += __shfl_xor(s2, m2); }
  __shared__ float rb[2][4];
  int wv = t >> 6;
  if ((t & 63) == 0) { rb[0][wv] = s; rb[1][wv] = s2; }
  __syncthreads();
  s  = rb[0][0] + rb[0][1] + rb[0][2] + rb[0][3];
  s2 = rb[1][0] + rb[1][1] + rb[1][2] + rb[1][3];
  float mu = s * (1.0f / DMODEL);
  float rs = rsqrtf(s2 * (1.0f / DMODEL) - mu * mu + 1e-5f);
  const float4 wv4 = ((const float4*)w)[t];
  const float4 bv4 = ((const float4*)bias)[t];
  ushort4 o;
  o.x = f2bf((xv.x - mu) * rs * wv4.x + bv4.x);
  o.y = f2bf((xv.y - mu) * rs * wv4.y + bv4.y);
  o.z = f2bf((xv.z - mu) * rs * wv4.z + bv4.z);
  o.w = f2bf((xv.w - mu) * rs * wv4.w + bv4.w);
  ((ushort4*)(h + (size_t)row * DMODEL))[t] = o;
}

// ============ 256x192 4-phase GEMM, C = A @ B^T (grid fills 256 CUs) ===========
template<int OUTMODE>
__global__ __launch_bounds__(512, 2) void k_gemm256(const u16* __restrict__ A, const u16* __restrict__ B,
                                                    void* __restrict__ Cv, int M, int N, int K) {
  __shared__ __align__(16) u16 As[2][256 * 64];   // 32 KB per buffer
  __shared__ __align__(16) u16 Bs[2][192 * 64];   // 24 KB per buffer
  const int t = threadIdx.x, lane = t & 63, w = t >> 6;
  const int wr = w >> 2, wc = w & 3;
  const int nbx = N / 192;                        // 16
  const int nwg = nbx * (M >> 8);                 // 256
  const int cpx = nwg >> 3;
  const int bid = blockIdx.x;
  const int sw = (bid & 7) * cpx + (bid >> 3);    // XCD swizzle (nwg % 8 == 0)
  const int m0 = (sw / nbx) * 256, n0 = (sw % nbx) * 192;
  const int NT = K >> 6;                          // 16
  const int cg16 = (lane >> 4) * 16;

  f32x4 acc[8][3] = {};
  const u16* Ap = A + (size_t)m0 * K;
  const u16* Bp = B + (size_t)n0 * K;
  const int rr0 = t >> 3;
  const int sz = ((t & 7) * 8) ^ ((rr0 & 7) << 3);   // u16 units (inverse swizzle)
  const u16* pA[4] = { Ap + (size_t)rr0 * K + sz,
                       Ap + (size_t)(rr0 + 64) * K + sz,
                       Ap + (size_t)(rr0 + 128) * K + sz,
                       Ap + (size_t)(rr0 + 192) * K + sz };
  const u16* pB[3] = { Bp + (size_t)rr0 * K + sz,
                       Bp + (size_t)(rr0 + 64) * K + sz,
                       Bp + (size_t)(rr0 + 128) * K + sz };

#define SA2(b, h, EO) do { \
    GLD((char*)As + (b)*32768 + (h)*16384 + w*1024,        pA[(h)*2]     + (EO)); \
    GLD((char*)As + (b)*32768 + (h)*16384 + 8192 + w*1024, pA[(h)*2 + 1] + (EO)); \
  } while (0)
#define SB3(b, EO) do { \
    GLD((char*)Bs + (b)*24576 +         w*1024, pB[0] + (EO)); \
    GLD((char*)Bs + (b)*24576 +  8192 + w*1024, pB[1] + (EO)); \
    GLD((char*)Bs + (b)*24576 + 16384 + w*1024, pB[2] + (EO)); \
  } while (0)

#define PHASEM(asb, bsb, mh, STG, WVM) do { \
    bf16x8 af_[4][2], bf_[3][2]; \
    _Pragma("unroll") for (int i2 = 0; i2 < 4; i2++) { \
      const int rowA = (((mh)*4 + i2)*2 + wr)*16 + (lane & 15); \
      const int sA = (rowA & 7) << 4; \
      _Pragma("unroll") for (int kk = 0; kk < 2; kk++) \
        af_[i2][kk] = *(const bf16x8*)((const char*)(asb) + (rowA & 127)*128 + ((kk*64 + cg16) ^ sA)); \
    } \
    _Pragma("unroll") for (int j2 = 0; j2 < 3; j2++) { \
      const int rowB = (j2*4 + wc)*16 + (lane & 15); \
      const int sB = (rowB & 7) << 4; \
      _Pragma("unroll") for (int kk = 0; kk < 2; kk++) \
        bf_[j2][kk] = *(const bf16x8*)((const char*)(bsb) + rowB*128 + ((kk*64 + cg16) ^ sB)); \
    } \
    STG; \
    __builtin_amdgcn_s_barrier(); \
    asm volatile("s_waitcnt lgkmcnt(0)" ::: "memory"); \
    __builtin_amdgcn_s_setprio(1); \
    _Pragma("unroll") for (int i2 = 0; i2 < 4; i2++) \
      _Pragma("unroll") for (int j2 = 0; j2 < 3; j2++) \
        _Pragma("unroll") for (int kk = 0; kk < 2; kk++) \
          acc[(mh)*4+i2][j2] = __builtin_amdgcn_mfma_f32_16x16x32_bf16( \
              af_[i2][kk], bf_[j2][kk], acc[(mh)*4+i2][j2], 0, 0, 0); \
    __builtin_amdgcn_s_setprio(0); \
    WVM; \
    __builtin_amdgcn_s_barrier(); \
  } while (0)

  SA2(0, 0, 0); SA2(0, 1, 0); SB3(0, 0);
  SA2(1, 0, 64);
  VM(2);
  __builtin_amdgcn_s_barrier();

  const char* a0  = (const char*)As;
  const char* a0h = a0 + 16384;
  const char* a1  = a0 + 32768;
  const char* a1h = a0 + 49152;
  const char* b0  = (const char*)Bs;
  const char* b1  = b0 + 24576;
  const int NIT = NT >> 1;
  for (int i = 0; i < NIT; i++) {
    const bool lst = (i == NIT - 1);
    PHASEM(a0,  b0, 0, { SA2(1, 1, 64); SB3(1, 64); }, {});
    PHASEM(a0h, b0, 1, { if (!lst) SA2(0, 0, 128); },
                       { if (lst) VM(0); else VM(2); });
    PHASEM(a1,  b1, 0, { if (!lst) { SA2(0, 1, 128); SB3(0, 128); } }, {});
    PHASEM(a1h, b1, 1, { if (!lst) SA2(1, 0, 192); },
                       { if (!lst) VM(2); });
    pA[0] += 128; pA[1] += 128; pA[2] += 128; pA[3] += 128;
    pB[0] += 128; pB[1] += 128; pB[2] += 128;
  }
#undef PHASEM
#undef SA2
#undef SB3

  const int cr = (lane >> 4) * 4, cc = lane & 15;
#pragma unroll
  for (int fi = 0; fi < 8; fi++)
#pragma unroll
    for (int fj = 0; fj < 3; fj++) {
      const size_t roff = (size_t)(m0 + (fi * 2 + wr) * 16 + cr) * N + (n0 + (fj * 4 + wc) * 16 + cc);
      if (OUTMODE == 0) {
        float* Cp = (float*)Cv + roff;
#pragma unroll
        for (int r = 0; r < 4; r++) Cp[(size_t)r * N] = acc[fi][fj][r];
      } else {
        u16* Cp = (u16*)Cv + roff;
#pragma unroll
        for (int r = 0; r < 4; r++) Cp[(size_t)r * N] = f2bf(acc[fi][fj][r]);
      }
    }
}

// ---------------- bf16 GEMM 128^2 2-phase (used for GEMM2) ---------------------
template<int OUTMODE>
__global__ __launch_bounds__(256) void k_gemm_bt(const u16* __restrict__ A, const u16* __restrict__ B,
                                                 void* __restrict__ Cv, int M, int N, int K) {
  __shared__ __align__(16) u16 As[2][128 * 64];
  __shared__ __align__(16) u16 Bs[2][128 * 64];
  const int t = threadIdx.x;
  const int lane = t & 63, w = t >> 6;
  const int m0 = blockIdx.y * 128, n0 = blockIdx.x * 128;
  const int wm = (w >> 1) * 64, wn = (w & 1) * 64;
  const int NT = K >> 6;
  f32x4 acc[4][4] = {};
  const u16* Ap = A + (size_t)m0 * K;
  const u16* Bp = B + (size_t)n0 * K;
  const int cr0 = lane >> 3, cs = lane & 7;

#define GSTAGE(bb, kt_) do { \
    _Pragma("unroll") \
    for (int s2 = 0; s2 < 4; s2++) { \
      int ch = w * 4 + s2; \
      int row = ch * 8 + cr0; \
      int cb = cs ^ (row & 7); \
      GLD((char*)As[bb] + ch * 1024, Ap + (size_t)row * K + (kt_) * 64 + cb * 8); \
      GLD((char*)Bs[bb] + ch * 1024, Bp + (size_t)row * K + (kt_) * 64 + cb * 8); \
    } } while (0)

  GSTAGE(0, 0);
  VM(0);
  __builtin_amdgcn_s_barrier();
  int cur = 0;
  for (int kt = 0; kt < NT; kt++) {
    if (kt + 1 < NT) GSTAGE(cur ^ 1, kt + 1);
    const u16* asb = As[cur];
    const u16* bsb = Bs[cur];
#pragma unroll
    for (int kk = 0; kk < 2; kk++) {
      bf16x8 af[4], bfr[4];
#pragma unroll
      for (int i = 0; i < 4; i++) {
        int rowa = wm + i * 16 + (lane & 15);
        af[i] = *(const bf16x8*)((const char*)asb + rowa * 128 + ((kk * 64 + (lane >> 4) * 16) ^ ((rowa & 7) << 4)));
        int rowb = wn + i * 16 + (lane & 15);
        bfr[i] = *(const bf16x8*)((const char*)bsb + rowb * 128 + ((kk * 64 + (lane >> 4) * 16) ^ ((rowb & 7) << 4)));
      }
#pragma unroll
      for (int mf = 0; mf < 4; mf++)
#pragma unroll
        for (int nf = 0; nf < 4; nf++)
          acc[mf][nf] = __builtin_amdgcn_mfma_f32_16x16x32_bf16(af[mf], bfr[nf], acc[mf][nf], 0, 0, 0);
    }
    VM(0);
    __builtin_amdgcn_s_barrier();
    cur ^= 1;
  }
#undef GSTAGE
  const int cr = (lane >> 4) * 4, cc = lane & 15;
#pragma unroll
  for (int mf = 0; mf < 4; mf++)
#pragma unroll
    for (int nf = 0; nf < 4; nf++) {
      if (OUTMODE == 0) {
        float* Cp = (float*)Cv + (size_t)(m0 + wm + mf * 16 + cr) * N + (n0 + wn + nf * 16 + cc);
#pragma unroll
        for (int r = 0; r < 4; r++) Cp[(size_t)r * N] = acc[mf][nf][r];
      } else {
        u16* Cp = (u16*)Cv + (size_t)(m0 + wm + mf * 16 + cr) * N + (n0 + wn + nf * 16 + cc);
#pragma unroll
        for (int r = 0; r < 4; r++) Cp[(size_t)r * N] = f2bf(acc[mf][nf][r]);
      }
    }
}

// ---------------- q/k layernorm (over full D, bf16 in) + RoPE + head split -----
__global__ __launch_bounds__(256) void k_qk_ln_rope(const u16* __restrict__ qkv,
                                                    const float* __restrict__ qw, const float* __restrict__ kw,
                                                    const float* __restrict__ cosb, const float* __restrict__ sinb,
                                                    u16* __restrict__ Q, u16* __restrict__ K, u16* __restrict__ V) {
  int row = blockIdx.x, t = threadIdx.x;
  int b = row >> 11, l = row & 2047;
  const u16* base = qkv + (size_t)row * 3072;
  ushort4 qu = ((const ushort4*)base)[t];
  ushort4 ku = ((const ushort4*)(base + 1024))[t];
  ushort4 vu = ((const ushort4*)(base + 2048))[t];
  float qx = bf2f(qu.x), qy = bf2f(qu.y), qz = bf2f(qu.z), qw_ = bf2f(qu.w);
  float kx = bf2f(ku.x), ky = bf2f(ku.y), kz = bf2f(ku.z), kw_ = bf2f(ku.w);
  float red[4];
  red[0] = qx + qy + qz + qw_;
  red[1] = qx * qx + qy * qy + qz * qz + qw_ * qw_;
  red[2] = kx + ky + kz + kw_;
  red[3] = kx * kx + ky * ky + kz * kz + kw_ * kw_;
#pragma unroll
  for (int i = 0; i < 4; i++)
#pragma unroll
    for (int m2 = 1; m2 < 64; m2 <<= 1) red[i] += __shfl_xor(red[i], m2);
  __shared__ float rb[4][4];
  int w = t >> 6;
  if ((t & 63) == 0) { rb[w][0] = red[0]; rb[w][1] = red[1]; rb[w][2] = red[2]; rb[w][3] = red[3]; }
  __syncthreads();
  float S1 = rb[0][0] + rb[1][0] + rb[2][0] + rb[3][0];
  float S2 = rb[0][1] + rb[1][1] + rb[2][1] + rb[3][1];
  float S3 = rb[0][2] + rb[1][2] + rb[2][2] + rb[3][2];
  float S4 = rb[0][3] + rb[1][3] + rb[2][3] + rb[3][3];
  float muq = S1 * (1.0f / DMODEL), rsq = rsqrtf(S2 * (1.0f / DMODEL) - muq * muq + 1e-5f);
  float muk = S3 * (1.0f / DMODEL), rsk = rsqrtf(S4 * (1.0f / DMODEL) - muk * muk + 1e-5f);
  __shared__ float qs[1024], ks[1024];
  float4 qwv = ((const float4*)qw)[t];
  float4 kwv = ((const float4*)kw)[t];
  qs[t * 4 + 0] = (qx - muq) * rsq * qwv.x;  ks[t * 4 + 0] = (kx - muk) * rsk * kwv.x;
  qs[t * 4 + 1] = (qy - muq) * rsq * qwv.y;  ks[t * 4 + 1] = (ky - muk) * rsk * kwv.y;
  qs[t * 4 + 2] = (qz - muq) * rsq * qwv.z;  ks[t * 4 + 2] = (kz - muk) * rsk * kwv.z;
  qs[t * 4 + 3] = (qw_ - muq) * rsq * qwv.w; ks[t * 4 + 3] = (kw_ - muk) * rsk * kwv.w;
  __syncthreads();
  int d0 = t * 4;
  int hh = d0 >> 6;
  union { ushort4 v4; u16 e[4]; } qo, ko;
#pragma unroll
  for (int i = 0; i < 4; i++) {
    int d = d0 + i, dd = d & 63, fr = dd & 31;
    float c = cosb[l * 32 + fr], s = sinb[l * 32 + fr];
    float q1 = qs[d], q2 = (dd < 32) ? -qs[d + 32] : qs[d - 32];
    float k1 = ks[d], k2 = (dd < 32) ? -ks[d + 32] : ks[d - 32];
    qo.e[i] = f2bf(q1 * c + q2 * s);
    ko.e[i] = f2bf(k1 * c + k2 * s);
  }
  size_t oidx = ((size_t)(b * NHEAD + hh) * LSEQ + l) * DHEAD + (d0 & 63);
  *(ushort4*)(Q + oidx) = qo.v4;
  *(ushort4*)(K + oidx) = ko.v4;
  *(ushort4*)(V + oidx) = vu;
}

// -------- segment-masked flash attention: QBLK=128, 8 waves, XCD-chunked -------
__global__ __launch_bounds__(512) void k_attn(const u16* __restrict__ Q, const u16* __restrict__ Kb,
                                              const u16* __restrict__ VTb, const int* __restrict__ seq,
                                              const int* __restrict__ bnd, u16* __restrict__ ctx) {
  __shared__ __align__(16) u16 Ks[2][64 * 64];   // 8 KB / buf
  __shared__ __align__(16) u16 Vs[2][64 * 64];   // 8 KB / buf
  __shared__ __align__(16) u16 Pw[8][16 * 64];   // 2 KB / wave

  // XCD-chunked swizzle: nwg = 512, XCD x gets 64 consecutive sw -> 4 whole heads
  const int bid = blockIdx.x;
  const int sw = (bid & 7) * 64 + (bid >> 3);
  const int qt = sw & 15, h = (sw >> 4) & 15, b = sw >> 8;
  const int t = threadIdx.x, l = t & 63, w = t >> 6;
  const int c = l & 15, g = l >> 4;
  const int q0 = qt * 128;
  const size_t hoff = (size_t)(b * NHEAD + h) * LSEQ * DHEAD;
  const u16* Qg = Q + hoff;
  const u16* Kg = Kb + hoff;
  const u16* Vg = VTb + hoff;   // [d][l]
  const int* seqb = seq + b * LSEQ;
  const int* bnd5 = bnd + b * 5;

  const int qw0 = q0 + w * 16;
  const int myq = qw0 + c;
  const int sq = seqb[myq];
  const int lo = bnd5[sq], hi = bnd5[sq + 1];
  const int wlo = bnd5[seqb[qw0]];
  const int whi = bnd5[seqb[qw0 + 15] + 1];
  int kbeg = bnd5[seqb[q0]] & ~63;
  int kend = (bnd5[seqb[q0 + 127] + 1] + 63) & ~63;
  if (kend > LSEQ) kend = LSEQ;

  bf16x8 qf[2];
  qf[0] = *(const bf16x8*)(Qg + (size_t)myq * 64 + g * 8);
  qf[1] = *(const bf16x8*)(Qg + (size_t)myq * 64 + 32 + g * 8);

  f32x4 acc[4] = {};
  float lsum = 0.f;

  // staging: 512 thr x 16B = one full 64x64 tile per buffer; r = t>>3
  const int rr = t >> 3;
  const int szk = ((t & 7) * 8) ^ ((rr & 7) << 3);   // u16 units (inverse swizzle)
  const u16* pK = Kg + (size_t)rr * 64 + szk;        // + kt*64 per tile
  const u16* pV = Vg + (size_t)rr * LSEQ + szk;      // + kt   per tile

#define STAGE(bb, kt_) do { \
    GLD((char*)Ks[bb] + w * 1024, pK + (size_t)(kt_) * 64); \
    GLD((char*)Vs[bb] + w * 1024, pV + (kt_)); \
  } while (0)

  STAGE(0, kbeg);
  int cur = 0;
  for (int kt = kbeg; kt < kend; kt += 64) {
    const bool more = (kt + 64) < kend;
    if (more) STAGE(cur ^ 1, kt + 64);
    if (more) VM(2);
    else      VM(0);
    __builtin_amdgcn_s_barrier();
    __builtin_amdgcn_sched_barrier(0);
    if (kt < whi && kt + 64 > wlo) {
      const u16* ksb = Ks[cur];
      const u16* vsb = Vs[cur];
      f32x4 st[4] = {};
#pragma unroll
      for (int kk = 0; kk < 2; kk++) {
        bf16x8 kf[4];
#pragma unroll
        for (int i = 0; i < 4; i++) {
          int row = i * 16 + c;
          kf[i] = *(const bf16x8*)((const char*)ksb + row * 128 + ((kk * 64 + g * 16) ^ ((row & 7) << 4)));
        }
#pragma unroll
        for (int i = 0; i < 4; i++)
          st[i] = __builtin_amdgcn_mfma_f32_16x16x32_bf16(kf[i], qf[kk], st[i], 0, 0, 0);
      }
      const int kb0 = kt + g * 4;
#pragma unroll
      for (int i = 0; i < 4; i++) {
        float p[4];
#pragma unroll
        for (int r = 0; r < 4; r++) {
          int kglob = kb0 + i * 16 + r;
          bool ok = ((unsigned)(kglob - lo)) < ((unsigned)(hi - lo));
          float x = ok ? fmaf(st[i][r], 0.125f, -8.0f) : -1e30f;
          p[r] = __expf(x);
          lsum += p[r];
        }
        unsigned w0, w1;
        asm("v_cvt_pk_bf16_f32 %0, %1, %2" : "=v"(w0) : "v"(p[0]), "v"(p[1]));
        asm("v_cvt_pk_bf16_f32 %0, %1, %2" : "=v"(w1) : "v"(p[2]), "v"(p[3]));
        uint2 wp; wp.x = w0; wp.y = w1;
        *(uint2*)((char*)Pw[w] + c * 128 + ((i * 32 + g * 8) ^ ((c & 7) << 4))) = wp;
      }
#pragma unroll
      for (int kk = 0; kk < 2; kk++) {
        bf16x8 pa = *(const bf16x8*)((char*)Pw[w] + c * 128 + ((kk * 64 + g * 16) ^ ((c & 7) << 4)));
        bf16x8 vf[4];
#pragma unroll
        for (int df = 0; df < 4; df++) {
          int row = df * 16 + c;
          vf[df] = *(const bf16x8*)((const char*)vsb + row * 128 + ((kk * 64 + g * 16) ^ ((row & 7) << 4)));
        }
#pragma unroll
        for (int df = 0; df < 4; df++)
          acc[df] = __builtin_amdgcn_mfma_f32_16x16x32_bf16(pa, vf[df], acc[df], 0, 0, 0);
      }
    }
    __builtin_amdgcn_sched_barrier(0);
    __builtin_amdgcn_s_barrier();
    cur ^= 1;
  }
#undef STAGE

  lsum += __shfl_xor(lsum, 16);
  lsum += __shfl_xor(lsum, 32);
#pragma unroll
  for (int r = 0; r < 4; r++) {
    float lr = __shfl(lsum, g * 4 + r, 64);
    float rls = 1.0f / lr;
    int qrow = qw0 + g * 4 + r;
    u16* op = ctx + (size_t)(b * LSEQ + qrow) * DMODEL + h * 64 + c;
#pragma unroll
    for (int df = 0; df < 4; df++)
      op[df * 16] = f2bf(acc[df][r] * rls);
  }
}

// ---------------- launch --------------------------------------------------------
extern "C" void kernel_launch(void* const* d_in, const int* in_sizes, int n_in,
                              void* d_out, int out_size, void* d_ws, size_t ws_size,
                              hipStream_t stream) {
  const float* x    = (const float*)d_in[0];
  const int*   seq  = (const int*)d_in[1];
  const float* ln1w = (const float*)d_in[2];
  const float* ln1b = (const float*)d_in[3];
  const float* wqkv = (const float*)d_in[4];
  const float* qlnw = (const float*)d_in[5];
  const float* klnw = (const float*)d_in[6];
  const float* wout = (const float*)d_in[7];
  float* out = (float*)d_out;

  char* p = (char*)d_ws;
  u16* wqkvT = (u16*)p;  p += (size_t)3072 * 1024 * 2;
  u16* woutT = (u16*)p;  p += (size_t)1024 * 1024 * 2;
  u16* hbuf  = (u16*)p;  p += (size_t)ROWS * DMODEL * 2;
  u16* Qb    = (u16*)p;  p += (size_t)ROWS * DMODEL * 2;
  u16* Kbuf  = (u16*)p;  p += (size_t)ROWS * DMODEL * 2;
  u16* Vbuf  = (u16*)p;  p += (size_t)ROWS * DMODEL * 2;
  u16* VTbuf = (u16*)p;  p += (size_t)ROWS * DMODEL * 2;
  u16* ctxb  = (u16*)p;  p += (size_t)ROWS * DMODEL * 2;
  float* cosb = (float*)p; p += (size_t)LSEQ * 32 * 4;
  float* sinb = (float*)p; p += (size_t)LSEQ * 32 * 4;
  int* bnd   = (int*)p;  p += 256;
  u16* qkv   = (u16*)p;  p += (size_t)ROWS * 3072 * 2;

  k_transpose_cvt<<<dim3(3072 / 32, 1024 / 32), dim3(32, 8), 0, stream>>>(wqkv, wqkvT, 1024, 3072);
  k_transpose_cvt<<<dim3(1024 / 32, 1024 / 32), dim3(32, 8), 0, stream>>>(wout, woutT, 1024, 1024);
  k_rope_tables<<<(LSEQ * 32) / 256, 256, 0, stream>>>(cosb, sinb, seq, bnd);
  k_ln1<<<ROWS, 256, 0, stream>>>(x, ln1w, ln1b, hbuf);
  k_gemm256<1><<<(ROWS / 256) * (3072 / 192), 512, 0, stream>>>(hbuf, wqkvT, (void*)qkv, ROWS, 3072, 1024);
  k_qk_ln_rope<<<ROWS, 256, 0, stream>>>(qkv, qlnw, klnw, cosb, sinb, Qb, Kbuf, Vbuf);
  k_transpose_u16<<<dim3(DHEAD / 32, LSEQ / 32, BATCH * NHEAD), dim3(32, 8), 0, stream>>>(Vbuf, VTbuf);
  k_attn<<<BATCH * NHEAD * (LSEQ / 128), 512, 0, stream>>>(Qb, Kbuf, VTbuf, seq, bnd, ctxb);
  k_gemm_bt<0><<<dim3(1024 / 128, ROWS / 128), 256, 0, stream>>>(ctxb, woutT, (void*)out, ROWS, 1024, 1024);
}

// Round 10
// 123.273 us; speedup vs baseline: 1.1356x; 1.0023x over previous
//
#include <hip/hip_runtime.h>
#include <hip/hip_bf16.h>
#include <cstdint>
#include <math.h>

#define LSEQ 2048
#define BATCH 2
#define NHEAD 16
#define DHEAD 64
#define DMODEL 1024
#define ROWS (BATCH*LSEQ)

typedef __bf16 bf16x8 __attribute__((ext_vector_type(8)));
typedef float f32x4 __attribute__((ext_vector_type(4)));
typedef unsigned short u16;

#define GLD(lds_base, src_g) \
  __builtin_amdgcn_global_load_lds((const __attribute__((address_space(1))) void*)(src_g), \
                                   (__attribute__((address_space(3))) void*)(lds_base), 16, 0, 0)
#define VM(n) asm volatile("s_waitcnt vmcnt(" #n ")" ::: "memory")

__device__ __forceinline__ u16 f2bf(float f) {
  unsigned int u = __float_as_uint(f);
  u += 0x7fffu + ((u >> 16) & 1u);
  return (u16)(u >> 16);
}
__device__ __forceinline__ float bf2f(u16 u) {
  return __uint_as_float(((unsigned)u) << 16);
}

// ---------------- transpose + fp32->bf16 convert: out[c][r] = bf16(in[r][c]) ----
__global__ void k_transpose_cvt(const float* __restrict__ in, u16* __restrict__ out, int R, int C) {
  __shared__ float tile[32][33];
  int c0 = blockIdx.x * 32, r0 = blockIdx.y * 32;
  int tx = threadIdx.x, ty = threadIdx.y;
#pragma unroll
  for (int i = 0; i < 32; i += 8)
    tile[ty + i][tx] = in[(size_t)(r0 + ty + i) * C + (c0 + tx)];
  __syncthreads();
#pragma unroll
  for (int i = 0; i < 32; i += 8)
    out[(size_t)(c0 + ty + i) * R + (r0 + tx)] = f2bf(tile[tx][ty + i]);
}

// ---------------- u16 transpose per head: in [L][64] -> out [64][L] ------------
__global__ void k_transpose_u16(const u16* __restrict__ in, u16* __restrict__ out) {
  __shared__ u16 tile[32][33];
  int hd = blockIdx.z;
  int l0 = blockIdx.y * 32, d0 = blockIdx.x * 32;
  const u16* ip = in + (size_t)hd * LSEQ * DHEAD;
  u16* op = out + (size_t)hd * LSEQ * DHEAD;
  int tx = threadIdx.x, ty = threadIdx.y;
#pragma unroll
  for (int i = 0; i < 32; i += 8)
    tile[ty + i][tx] = ip[(size_t)(l0 + ty + i) * DHEAD + d0 + tx];
  __syncthreads();
#pragma unroll
  for (int i = 0; i < 32; i += 8)
    op[(size_t)(d0 + ty + i) * LSEQ + l0 + tx] = tile[tx][ty + i];
}

// ---------------- RoPE tables + segment bounds (fused) -------------------------
__global__ void k_rope_tables(float* __restrict__ cosb, float* __restrict__ sinb,
                              const int* __restrict__ seq, int* __restrict__ bnd) {
  if (blockIdx.x == 0 && threadIdx.x < BATCH * 5) {
    int b = threadIdx.x / 5, s = threadIdx.x % 5;
    const int* row = seq + b * LSEQ;
    int lo = 0, hi = LSEQ;
    while (lo < hi) { int mid = (lo + hi) >> 1; if (row[mid] < s) lo = mid + 1; else hi = mid; }
    bnd[b * 5 + s] = lo;
  }
  int idx = blockIdx.x * blockDim.x + threadIdx.x;
  if (idx >= LSEQ * 32) return;
  int l = idx >> 5, f = idx & 31;
  double inv = pow(10000.0, -(double)f / 32.0);
  float ang = (float)l * (float)inv;
  cosb[idx] = cosf(ang);
  sinb[idx] = sinf(ang);
}

// ---------------- LN1: h = bf16(layernorm(x, w, b)) ----------------------------
__global__ __launch_bounds__(256) void k_ln1(const float* __restrict__ x, const float* __restrict__ w,
                                             const float* __restrict__ bias, u16* __restrict__ h) {
  int row = blockIdx.x, t = threadIdx.x;
  const float4 xv = ((const float4*)(x + (size_t)row * DMODEL))[t];
  float s = xv.x + xv.y + xv.z + xv.w;
  float s2 = xv.x * xv.x + xv.y * xv.y + xv.z * xv.z + xv.w * xv.w;
#pragma unroll
  for (int m2 = 1; m2 < 64; m2 <<= 1) { s += __shfl_xor(s, m2); s2 += __shfl_xor(s2, m2); }
  __shared__ float rb[2][4];
  int wv = t >> 6;
  if ((t & 63) == 0) { rb[0][wv] = s; rb[1][wv] = s2; }
  __syncthreads();
  s  = rb[0][0] + rb[0][1] + rb[0][2] + rb[0][3];
  s2 = rb[1][0] + rb[1][1] + rb[1][2] + rb[1][3];
  float mu = s * (1.0f / DMODEL);
  float rs = rsqrtf(s2 * (1.0f / DMODEL) - mu * mu + 1e-5f);
  const float4 wv4 = ((const float4*)w)[t];
  const float4 bv4 = ((const float4*)bias)[t];
  ushort4 o;
  o.x = f2bf((xv.x - mu) * rs * wv4.x + bv4.x);
  o.y = f2bf((xv.y - mu) * rs * wv4.y + bv4.y);
  o.z = f2bf((xv.z - mu) * rs * wv4.z + bv4.z);
  o.w = f2bf((xv.w - mu) * rs * wv4.w + bv4.w);
  ((ushort4*)(h + (size_t)row * DMODEL))[t] = o;
}

// ============ 256x192 4-phase GEMM, C = A @ B^T (grid fills 256 CUs) ===========
template<int OUTMODE>
__global__ __launch_bounds__(512, 2) void k_gemm256(const u16* __restrict__ A, const u16* __restrict__ B,
                                                    void* __restrict__ Cv, int M, int N, int K) {
  __shared__ __align__(16) u16 As[2][256 * 64];   // 32 KB per buffer
  __shared__ __align__(16) u16 Bs[2][192 * 64];   // 24 KB per buffer
  const int t = threadIdx.x, lane = t & 63, w = t >> 6;
  const int wr = w >> 2, wc = w & 3;
  const int nbx = N / 192;                        // 16
  const int nwg = nbx * (M >> 8);                 // 256
  const int cpx = nwg >> 3;
  const int bid = blockIdx.x;
  const int sw = (bid & 7) * cpx + (bid >> 3);    // XCD swizzle (nwg % 8 == 0)
  const int m0 = (sw / nbx) * 256, n0 = (sw % nbx) * 192;
  const int NT = K >> 6;                          // 16
  const int cg16 = (lane >> 4) * 16;

  f32x4 acc[8][3] = {};
  const u16* Ap = A + (size_t)m0 * K;
  const u16* Bp = B + (size_t)n0 * K;
  const int rr0 = t >> 3;
  const int sz = ((t & 7) * 8) ^ ((rr0 & 7) << 3);   // u16 units (inverse swizzle)
  const u16* pA[4] = { Ap + (size_t)rr0 * K + sz,
                       Ap + (size_t)(rr0 + 64) * K + sz,
                       Ap + (size_t)(rr0 + 128) * K + sz,
                       Ap + (size_t)(rr0 + 192) * K + sz };
  const u16* pB[3] = { Bp + (size_t)rr0 * K + sz,
                       Bp + (size_t)(rr0 + 64) * K + sz,
                       Bp + (size_t)(rr0 + 128) * K + sz };

#define SA2(b, h, EO) do { \
    GLD((char*)As + (b)*32768 + (h)*16384 + w*1024,        pA[(h)*2]     + (EO)); \
    GLD((char*)As + (b)*32768 + (h)*16384 + 8192 + w*1024, pA[(h)*2 + 1] + (EO)); \
  } while (0)
#define SB3(b, EO) do { \
    GLD((char*)Bs + (b)*24576 +         w*1024, pB[0] + (EO)); \
    GLD((char*)Bs + (b)*24576 +  8192 + w*1024, pB[1] + (EO)); \
    GLD((char*)Bs + (b)*24576 + 16384 + w*1024, pB[2] + (EO)); \
  } while (0)

#define PHASEM(asb, bsb, mh, STG, WVM) do { \
    bf16x8 af_[4][2], bf_[3][2]; \
    _Pragma("unroll") for (int i2 = 0; i2 < 4; i2++) { \
      const int rowA = (((mh)*4 + i2)*2 + wr)*16 + (lane & 15); \
      const int sA = (rowA & 7) << 4; \
      _Pragma("unroll") for (int kk = 0; kk < 2; kk++) \
        af_[i2][kk] = *(const bf16x8*)((const char*)(asb) + (rowA & 127)*128 + ((kk*64 + cg16) ^ sA)); \
    } \
    _Pragma("unroll") for (int j2 = 0; j2 < 3; j2++) { \
      const int rowB = (j2*4 + wc)*16 + (lane & 15); \
      const int sB = (rowB & 7) << 4; \
      _Pragma("unroll") for (int kk = 0; kk < 2; kk++) \
        bf_[j2][kk] = *(const bf16x8*)((const char*)(bsb) + rowB*128 + ((kk*64 + cg16) ^ sB)); \
    } \
    STG; \
    __builtin_amdgcn_s_barrier(); \
    asm volatile("s_waitcnt lgkmcnt(0)" ::: "memory"); \
    __builtin_amdgcn_s_setprio(1); \
    _Pragma("unroll") for (int i2 = 0; i2 < 4; i2++) \
      _Pragma("unroll") for (int j2 = 0; j2 < 3; j2++) \
        _Pragma("unroll") for (int kk = 0; kk < 2; kk++) \
          acc[(mh)*4+i2][j2] = __builtin_amdgcn_mfma_f32_16x16x32_bf16( \
              af_[i2][kk], bf_[j2][kk], acc[(mh)*4+i2][j2], 0, 0, 0); \
    __builtin_amdgcn_s_setprio(0); \
    WVM; \
    __builtin_amdgcn_s_barrier(); \
  } while (0)

  SA2(0, 0, 0); SA2(0, 1, 0); SB3(0, 0);
  SA2(1, 0, 64);
  VM(2);
  __builtin_amdgcn_s_barrier();

  const char* a0  = (const char*)As;
  const char* a0h = a0 + 16384;
  const char* a1  = a0 + 32768;
  const char* a1h = a0 + 49152;
  const char* b0  = (const char*)Bs;
  const char* b1  = b0 + 24576;
  const int NIT = NT >> 1;
  for (int i = 0; i < NIT; i++) {
    const bool lst = (i == NIT - 1);
    PHASEM(a0,  b0, 0, { SA2(1, 1, 64); SB3(1, 64); }, {});
    PHASEM(a0h, b0, 1, { if (!lst) SA2(0, 0, 128); },
                       { if (lst) VM(0); else VM(2); });
    PHASEM(a1,  b1, 0, { if (!lst) { SA2(0, 1, 128); SB3(0, 128); } }, {});
    PHASEM(a1h, b1, 1, { if (!lst) SA2(1, 0, 192); },
                       { if (!lst) VM(2); });
    pA[0] += 128; pA[1] += 128; pA[2] += 128; pA[3] += 128;
    pB[0] += 128; pB[1] += 128; pB[2] += 128;
  }
#undef PHASEM
#undef SA2
#undef SB3

  const int cr = (lane >> 4) * 4, cc = lane & 15;
#pragma unroll
  for (int fi = 0; fi < 8; fi++)
#pragma unroll
    for (int fj = 0; fj < 3; fj++) {
      const size_t roff = (size_t)(m0 + (fi * 2 + wr) * 16 + cr) * N + (n0 + (fj * 4 + wc) * 16 + cc);
      if (OUTMODE == 0) {
        float* Cp = (float*)Cv + roff;
#pragma unroll
        for (int r = 0; r < 4; r++) Cp[(size_t)r * N] = acc[fi][fj][r];
      } else {
        u16* Cp = (u16*)Cv + roff;
#pragma unroll
        for (int r = 0; r < 4; r++) Cp[(size_t)r * N] = f2bf(acc[fi][fj][r]);
      }
    }
}

// ---------------- bf16 GEMM 128^2 2-phase (used for GEMM2) ---------------------
template<int OUTMODE>
__global__ __launch_bounds__(256) void k_gemm_bt(const u16* __restrict__ A, const u16* __restrict__ B,
                                                 void* __restrict__ Cv, int M, int N, int K) {
  __shared__ __align__(16) u16 As[2][128 * 64];
  __shared__ __align__(16) u16 Bs[2][128 * 64];
  const int t = threadIdx.x;
  const int lane = t & 63, w = t >> 6;
  const int m0 = blockIdx.y * 128, n0 = blockIdx.x * 128;
  const int wm = (w >> 1) * 64, wn = (w & 1) * 64;
  const int NT = K >> 6;
  f32x4 acc[4][4] = {};
  const u16* Ap = A + (size_t)m0 * K;
  const u16* Bp = B + (size_t)n0 * K;
  const int cr0 = lane >> 3, cs = lane & 7;

#define GSTAGE(bb, kt_) do { \
    _Pragma("unroll") \
    for (int s2 = 0; s2 < 4; s2++) { \
      int ch = w * 4 + s2; \
      int row = ch * 8 + cr0; \
      int cb = cs ^ (row & 7); \
      GLD((char*)As[bb] + ch * 1024, Ap + (size_t)row * K + (kt_) * 64 + cb * 8); \
      GLD((char*)Bs[bb] + ch * 1024, Bp + (size_t)row * K + (kt_) * 64 + cb * 8); \
    } } while (0)

  GSTAGE(0, 0);
  VM(0);
  __builtin_amdgcn_s_barrier();
  int cur = 0;
  for (int kt = 0; kt < NT; kt++) {
    if (kt + 1 < NT) GSTAGE(cur ^ 1, kt + 1);
    const u16* asb = As[cur];
    const u16* bsb = Bs[cur];
#pragma unroll
    for (int kk = 0; kk < 2; kk++) {
      bf16x8 af[4], bfr[4];
#pragma unroll
      for (int i = 0; i < 4; i++) {
        int rowa = wm + i * 16 + (lane & 15);
        af[i] = *(const bf16x8*)((const char*)asb + rowa * 128 + ((kk * 64 + (lane >> 4) * 16) ^ ((rowa & 7) << 4)));
        int rowb = wn + i * 16 + (lane & 15);
        bfr[i] = *(const bf16x8*)((const char*)bsb + rowb * 128 + ((kk * 64 + (lane >> 4) * 16) ^ ((rowb & 7) << 4)));
      }
#pragma unroll
      for (int mf = 0; mf < 4; mf++)
#pragma unroll
        for (int nf = 0; nf < 4; nf++)
          acc[mf][nf] = __builtin_amdgcn_mfma_f32_16x16x32_bf16(af[mf], bfr[nf], acc[mf][nf], 0, 0, 0);
    }
    VM(0);
    __builtin_amdgcn_s_barrier();
    cur ^= 1;
  }
#undef GSTAGE
  const int cr = (lane >> 4) * 4, cc = lane & 15;
#pragma unroll
  for (int mf = 0; mf < 4; mf++)
#pragma unroll
    for (int nf = 0; nf < 4; nf++) {
      if (OUTMODE == 0) {
        float* Cp = (float*)Cv + (size_t)(m0 + wm + mf * 16 + cr) * N + (n0 + wn + nf * 16 + cc);
#pragma unroll
        for (int r = 0; r < 4; r++) Cp[(size_t)r * N] = acc[mf][nf][r];
      } else {
        u16* Cp = (u16*)Cv + (size_t)(m0 + wm + mf * 16 + cr) * N + (n0 + wn + nf * 16 + cc);
#pragma unroll
        for (int r = 0; r < 4; r++) Cp[(size_t)r * N] = f2bf(acc[mf][nf][r]);
      }
    }
}

// ---------------- q/k layernorm (over full D, bf16 in) + RoPE + head split -----
__global__ __launch_bounds__(256) void k_qk_ln_rope(const u16* __restrict__ qkv,
                                                    const float* __restrict__ qw, const float* __restrict__ kw,
                                                    const float* __restrict__ cosb, const float* __restrict__ sinb,
                                                    u16* __restrict__ Q, u16* __restrict__ K, u16* __restrict__ V) {
  int row = blockIdx.x, t = threadIdx.x;
  int b = row >> 11, l = row & 2047;
  const u16* base = qkv + (size_t)row * 3072;
  ushort4 qu = ((const ushort4*)base)[t];
  ushort4 ku = ((const ushort4*)(base + 1024))[t];
  ushort4 vu = ((const ushort4*)(base + 2048))[t];
  float qx = bf2f(qu.x), qy = bf2f(qu.y), qz = bf2f(qu.z), qw_ = bf2f(qu.w);
  float kx = bf2f(ku.x), ky = bf2f(ku.y), kz = bf2f(ku.z), kw_ = bf2f(ku.w);
  float red[4];
  red[0] = qx + qy + qz + qw_;
  red[1] = qx * qx + qy * qy + qz * qz + qw_ * qw_;
  red[2] = kx + ky + kz + kw_;
  red[3] = kx * kx + ky * ky + kz * kz + kw_ * kw_;
#pragma unroll
  for (int i = 0; i < 4; i++)
#pragma unroll
    for (int m2 = 1; m2 < 64; m2 <<= 1) red[i] += __shfl_xor(red[i], m2);
  __shared__ float rb[4][4];
  int w = t >> 6;
  if ((t & 63) == 0) { rb[w][0] = red[0]; rb[w][1] = red[1]; rb[w][2] = red[2]; rb[w][3] = red[3]; }
  __syncthreads();
  float S1 = rb[0][0] + rb[1][0] + rb[2][0] + rb[3][0];
  float S2 = rb[0][1] + rb[1][1] + rb[2][1] + rb[3][1];
  float S3 = rb[0][2] + rb[1][2] + rb[2][2] + rb[3][2];
  float S4 = rb[0][3] + rb[1][3] + rb[2][3] + rb[3][3];
  float muq = S1 * (1.0f / DMODEL), rsq = rsqrtf(S2 * (1.0f / DMODEL) - muq * muq + 1e-5f);
  float muk = S3 * (1.0f / DMODEL), rsk = rsqrtf(S4 * (1.0f / DMODEL) - muk * muk + 1e-5f);
  __shared__ float qs[1024], ks[1024];
  float4 qwv = ((const float4*)qw)[t];
  float4 kwv = ((const float4*)kw)[t];
  qs[t * 4 + 0] = (qx - muq) * rsq * qwv.x;  ks[t * 4 + 0] = (kx - muk) * rsk * kwv.x;
  qs[t * 4 + 1] = (qy - muq) * rsq * qwv.y;  ks[t * 4 + 1] = (ky - muk) * rsk * kwv.y;
  qs[t * 4 + 2] = (qz - muq) * rsq * qwv.z;  ks[t * 4 + 2] = (kz - muk) * rsk * kwv.z;
  qs[t * 4 + 3] = (qw_ - muq) * rsq * qwv.w; ks[t * 4 + 3] = (kw_ - muk) * rsk * kwv.w;
  __syncthreads();
  int d0 = t * 4;
  int hh = d0 >> 6;
  union { ushort4 v4; u16 e[4]; } qo, ko;
#pragma unroll
  for (int i = 0; i < 4; i++) {
    int d = d0 + i, dd = d & 63, fr = dd & 31;
    float c = cosb[l * 32 + fr], s = sinb[l * 32 + fr];
    float q1 = qs[d], q2 = (dd < 32) ? -qs[d + 32] : qs[d - 32];
    float k1 = ks[d], k2 = (dd < 32) ? -ks[d + 32] : ks[d - 32];
    qo.e[i] = f2bf(q1 * c + q2 * s);
    ko.e[i] = f2bf(k1 * c + k2 * s);
  }
  size_t oidx = ((size_t)(b * NHEAD + hh) * LSEQ + l) * DHEAD + (d0 & 63);
  *(ushort4*)(Q + oidx) = qo.v4;
  *(ushort4*)(K + oidx) = ko.v4;
  *(ushort4*)(V + oidx) = vu;
}

// -- segment-masked flash attention: QBLK=128, 8 waves, XCD-chunked, 4-deep pipe -
__global__ __launch_bounds__(512) void k_attn(const u16* __restrict__ Q, const u16* __restrict__ Kb,
                                              const u16* __restrict__ VTb, const int* __restrict__ seq,
                                              const int* __restrict__ bnd, u16* __restrict__ ctx) {
  __shared__ __align__(16) u16 Ks[4][64 * 64];   // 8 KB / buf
  __shared__ __align__(16) u16 Vs[4][64 * 64];   // 8 KB / buf
  __shared__ __align__(16) u16 Pw[8][16 * 64];   // 2 KB / wave

  // XCD-chunked swizzle: nwg = 512, XCD x gets 64 consecutive sw -> 4 whole heads
  const int bid = blockIdx.x;
  const int sw = (bid & 7) * 64 + (bid >> 3);
  const int qt = sw & 15, h = (sw >> 4) & 15, b = sw >> 8;
  const int t = threadIdx.x, l = t & 63, w = t >> 6;
  const int c = l & 15, g = l >> 4;
  const int q0 = qt * 128;
  const size_t hoff = (size_t)(b * NHEAD + h) * LSEQ * DHEAD;
  const u16* Qg = Q + hoff;
  const u16* Kg = Kb + hoff;
  const u16* Vg = VTb + hoff;   // [d][l]
  const int* seqb = seq + b * LSEQ;
  const int* bnd5 = bnd + b * 5;

  const int qw0 = q0 + w * 16;
  const int myq = qw0 + c;
  const int sq = seqb[myq];
  const int lo = bnd5[sq], hi = bnd5[sq + 1];
  const int wlo = bnd5[seqb[qw0]];
  const int whi = bnd5[seqb[qw0 + 15] + 1];
  int kbeg = bnd5[seqb[q0]] & ~63;
  int kend = (bnd5[seqb[q0 + 127] + 1] + 63) & ~63;
  if (kend > LSEQ) kend = LSEQ;

  bf16x8 qf[2];
  qf[0] = *(const bf16x8*)(Qg + (size_t)myq * 64 + g * 8);
  qf[1] = *(const bf16x8*)(Qg + (size_t)myq * 64 + 32 + g * 8);

  f32x4 acc[4] = {};
  float lsum = 0.f;

  // staging: 512 thr x 16B = one full 64x64 tile per buffer; each wave owns rows w*8..w*8+7
  const int rr = t >> 3;
  const int szk = ((t & 7) * 8) ^ ((rr & 7) << 3);   // u16 units (inverse swizzle)
  const u16* pK = Kg + (size_t)rr * 64 + szk;        // + kt*64 per tile
  const u16* pV = Vg + (size_t)rr * LSEQ + szk;      // + kt   per tile

#define STAGE(bb, kt_) do { \
    GLD((char*)Ks[bb] + w * 1024, pK + (size_t)(kt_) * 64); \
    GLD((char*)Vs[bb] + w * 1024, pV + (kt_)); \
  } while (0)

  const int nt = (kend - kbeg) >> 6;
  if (nt > 0) STAGE(0, kbeg);
  if (nt > 1) STAGE(1, kbeg + 64);
  if (nt > 2) STAGE(2, kbeg + 128);
  int idx = 0;
  for (int kt = kbeg; kt < kend; kt += 64, idx++) {
    if (idx + 3 < nt) STAGE((idx + 3) & 3, kt + 192);
    const int rem = nt - idx - 1;                 // tiles in flight beyond current
    if (rem >= 3)      VM(6);
    else if (rem == 2) VM(4);
    else if (rem == 1) VM(2);
    else               VM(0);
    __builtin_amdgcn_s_barrier();
    __builtin_amdgcn_sched_barrier(0);
    if (kt < whi && kt + 64 > wlo) {
      const u16* ksb = Ks[idx & 3];
      const u16* vsb = Vs[idx & 3];
      f32x4 st[4] = {};
#pragma unroll
      for (int kk = 0; kk < 2; kk++) {
        bf16x8 kf[4];
#pragma unroll
        for (int i = 0; i < 4; i++) {
          int row = i * 16 + c;
          kf[i] = *(const bf16x8*)((const char*)ksb + row * 128 + ((kk * 64 + g * 16) ^ ((row & 7) << 4)));
        }
#pragma unroll
        for (int i = 0; i < 4; i++)
          st[i] = __builtin_amdgcn_mfma_f32_16x16x32_bf16(kf[i], qf[kk], st[i], 0, 0, 0);
      }
      const int kb0 = kt + g * 4;
#pragma unroll
      for (int i = 0; i < 4; i++) {
        float p[4];
#pragma unroll
        for (int r = 0; r < 4; r++) {
          int kglob = kb0 + i * 16 + r;
          bool ok = ((unsigned)(kglob - lo)) < ((unsigned)(hi - lo));
          float x = ok ? fmaf(st[i][r], 0.125f, -8.0f) : -1e30f;
          p[r] = __expf(x);
          lsum += p[r];
        }
        unsigned w0, w1;
        asm("v_cvt_pk_bf16_f32 %0, %1, %2" : "=v"(w0) : "v"(p[0]), "v"(p[1]));
        asm("v_cvt_pk_bf16_f32 %0, %1, %2" : "=v"(w1) : "v"(p[2]), "v"(p[3]));
        uint2 wp; wp.x = w0; wp.y = w1;
        *(uint2*)((char*)Pw[w] + c * 128 + ((i * 32 + g * 8) ^ ((c & 7) << 4))) = wp;
      }
#pragma unroll
      for (int kk = 0; kk < 2; kk++) {
        bf16x8 pa = *(const bf16x8*)((char*)Pw[w] + c * 128 + ((kk * 64 + g * 16) ^ ((c & 7) << 4)));
        bf16x8 vf[4];
#pragma unroll
        for (int df = 0; df < 4; df++) {
          int row = df * 16 + c;
          vf[df] = *(const bf16x8*)((const char*)vsb + row * 128 + ((kk * 64 + g * 16) ^ ((row & 7) << 4)));
        }
#pragma unroll
        for (int df = 0; df < 4; df++)
          acc[df] = __builtin_amdgcn_mfma_f32_16x16x32_bf16(pa, vf[df], acc[df], 0, 0, 0);
      }
    }
    __builtin_amdgcn_sched_barrier(0);
    __builtin_amdgcn_s_barrier();
  }
#undef STAGE

  lsum += __shfl_xor(lsum, 16);
  lsum += __shfl_xor(lsum, 32);
#pragma unroll
  for (int r = 0; r < 4; r++) {
    float lr = __shfl(lsum, g * 4 + r, 64);
    float rls = 1.0f / lr;
    int qrow = qw0 + g * 4 + r;
    u16* op = ctx + (size_t)(b * LSEQ + qrow) * DMODEL + h * 64 + c;
#pragma unroll
    for (int df = 0; df < 4; df++)
      op[df * 16] = f2bf(acc[df][r] * rls);
  }
}

// ---------------- launch --------------------------------------------------------
extern "C" void kernel_launch(void* const* d_in, const int* in_sizes, int n_in,
                              void* d_out, int out_size, void* d_ws, size_t ws_size,
                              hipStream_t stream) {
  const float* x    = (const float*)d_in[0];
  const int*   seq  = (const int*)d_in[1];
  const float* ln1w = (const float*)d_in[2];
  const float* ln1b = (const float*)d_in[3];
  const float* wqkv = (const float*)d_in[4];
  const float* qlnw = (const float*)d_in[5];
  const float* klnw = (const float*)d_in[6];
  const float* wout = (const float*)d_in[7];
  float* out = (float*)d_out;

  char* p = (char*)d_ws;
  u16* wqkvT = (u16*)p;  p += (size_t)3072 * 1024 * 2;
  u16* woutT = (u16*)p;  p += (size_t)1024 * 1024 * 2;
  u16* hbuf  = (u16*)p;  p += (size_t)ROWS * DMODEL * 2;
  u16* Qb    = (u16*)p;  p += (size_t)ROWS * DMODEL * 2;
  u16* Kbuf  = (u16*)p;  p += (size_t)ROWS * DMODEL * 2;
  u16* Vbuf  = (u16*)p;  p += (size_t)ROWS * DMODEL * 2;
  u16* VTbuf = (u16*)p;  p += (size_t)ROWS * DMODEL * 2;
  u16* ctxb  = (u16*)p;  p += (size_t)ROWS * DMODEL * 2;
  float* cosb = (float*)p; p += (size_t)LSEQ * 32 * 4;
  float* sinb = (float*)p; p += (size_t)LSEQ * 32 * 4;
  int* bnd   = (int*)p;  p += 256;
  u16* qkv   = (u16*)p;  p += (size_t)ROWS * 3072 * 2;

  k_transpose_cvt<<<dim3(3072 / 32, 1024 / 32), dim3(32, 8), 0, stream>>>(wqkv, wqkvT, 1024, 3072);
  k_transpose_cvt<<<dim3(1024 / 32, 1024 / 32), dim3(32, 8), 0, stream>>>(wout, woutT, 1024, 1024);
  k_rope_tables<<<(LSEQ * 32) / 256, 256, 0, stream>>>(cosb, sinb, seq, bnd);
  k_ln1<<<ROWS, 256, 0, stream>>>(x, ln1w, ln1b, hbuf);
  k_gemm256<1><<<(ROWS / 256) * (3072 / 192), 512, 0, stream>>>(hbuf, wqkvT, (void*)qkv, ROWS, 3072, 1024);
  k_qk_ln_rope<<<ROWS, 256, 0, stream>>>(qkv, qlnw, klnw, cosb, sinb, Qb, Kbuf, Vbuf);
  k_transpose_u16<<<dim3(DHEAD / 32, LSEQ / 32, BATCH * NHEAD), dim3(32, 8), 0, stream>>>(Vbuf, VTbuf);
  k_attn<<<BATCH * NHEAD * (LSEQ / 128), 512, 0, stream>>>(Qb, Kbuf, VTbuf, seq, bnd, ctxb);
  k_gemm_bt<0><<<dim3(1024 / 128, ROWS / 128), 256, 0, stream>>>(ctxb, woutT, (void*)out, ROWS, 1024, 1024);
}

// Round 11
// 123.270 us; speedup vs baseline: 1.1356x; 1.0000x over previous
//
#include <hip/hip_runtime.h>
#include <hip/hip_bf16.h>
#include <cstdint>
#include <math.h>

#define LSEQ 2048
#define BATCH 2
#define NHEAD 16
#define DHEAD 64
#define DMODEL 1024
#define ROWS (BATCH*LSEQ)

typedef __bf16 bf16x8 __attribute__((ext_vector_type(8)));
typedef float f32x4 __attribute__((ext_vector_type(4)));
typedef unsigned short u16;

#define GLD(lds_base, src_g) \
  __builtin_amdgcn_global_load_lds((const __attribute__((address_space(1))) void*)(src_g), \
                                   (__attribute__((address_space(3))) void*)(lds_base), 16, 0, 0)
#define VM(n) asm volatile("s_waitcnt vmcnt(" #n ")" ::: "memory")

__device__ __forceinline__ u16 f2bf(float f) {
  unsigned int u = __float_as_uint(f);
  u += 0x7fffu + ((u >> 16) & 1u);
  return (u16)(u >> 16);
}
__device__ __forceinline__ float bf2f(u16 u) {
  return __uint_as_float(((unsigned)u) << 16);
}

// ---------------- transpose + fp32->bf16 convert: out[c][r] = bf16(in[r][c]) ----
__global__ void k_transpose_cvt(const float* __restrict__ in, u16* __restrict__ out, int R, int C) {
  __shared__ float tile[32][33];
  int c0 = blockIdx.x * 32, r0 = blockIdx.y * 32;
  int tx = threadIdx.x, ty = threadIdx.y;
#pragma unroll
  for (int i = 0; i < 32; i += 8)
    tile[ty + i][tx] = in[(size_t)(r0 + ty + i) * C + (c0 + tx)];
  __syncthreads();
#pragma unroll
  for (int i = 0; i < 32; i += 8)
    out[(size_t)(c0 + ty + i) * R + (r0 + tx)] = f2bf(tile[tx][ty + i]);
}

// ---------------- u16 transpose per head: in [L][64] -> out [64][L] ------------
__global__ void k_transpose_u16(const u16* __restrict__ in, u16* __restrict__ out) {
  __shared__ u16 tile[32][33];
  int hd = blockIdx.z;
  int l0 = blockIdx.y * 32, d0 = blockIdx.x * 32;
  const u16* ip = in + (size_t)hd * LSEQ * DHEAD;
  u16* op = out + (size_t)hd * LSEQ * DHEAD;
  int tx = threadIdx.x, ty = threadIdx.y;
#pragma unroll
  for (int i = 0; i < 32; i += 8)
    tile[ty + i][tx] = ip[(size_t)(l0 + ty + i) * DHEAD + d0 + tx];
  __syncthreads();
#pragma unroll
  for (int i = 0; i < 32; i += 8)
    op[(size_t)(d0 + ty + i) * LSEQ + l0 + tx] = tile[tx][ty + i];
}

// ---------------- RoPE tables + segment bounds (fused) -------------------------
__global__ void k_rope_tables(float* __restrict__ cosb, float* __restrict__ sinb,
                              const int* __restrict__ seq, int* __restrict__ bnd) {
  if (blockIdx.x == 0 && threadIdx.x < BATCH * 5) {
    int b = threadIdx.x / 5, s = threadIdx.x % 5;
    const int* row = seq + b * LSEQ;
    int lo = 0, hi = LSEQ;
    while (lo < hi) { int mid = (lo + hi) >> 1; if (row[mid] < s) lo = mid + 1; else hi = mid; }
    bnd[b * 5 + s] = lo;
  }
  int idx = blockIdx.x * blockDim.x + threadIdx.x;
  if (idx >= LSEQ * 32) return;
  int l = idx >> 5, f = idx & 31;
  double inv = pow(10000.0, -(double)f / 32.0);
  float ang = (float)l * (float)inv;
  cosb[idx] = cosf(ang);
  sinb[idx] = sinf(ang);
}

// ---------------- LN1: h = bf16(layernorm(x, w, b)) ----------------------------
__global__ __launch_bounds__(256) void k_ln1(const float* __restrict__ x, const float* __restrict__ w,
                                             const float* __restrict__ bias, u16* __restrict__ h) {
  int row = blockIdx.x, t = threadIdx.x;
  const float4 xv = ((const float4*)(x + (size_t)row * DMODEL))[t];
  float s = xv.x + xv.y + xv.z + xv.w;
  float s2 = xv.x * xv.x + xv.y * xv.y + xv.z * xv.z + xv.w * xv.w;
#pragma unroll
  for (int m2 = 1; m2 < 64; m2 <<= 1) { s += __shfl_xor(s, m2); s2 += __shfl_xor(s2, m2); }
  __shared__ float rb[2][4];
  int wv = t >> 6;
  if ((t & 63) == 0) { rb[0][wv] = s; rb[1][wv] = s2; }
  __syncthreads();
  s  = rb[0][0] + rb[0][1] + rb[0][2] + rb[0][3];
  s2 = rb[1][0] + rb[1][1] + rb[1][2] + rb[1][3];
  float mu = s * (1.0f / DMODEL);
  float rs = rsqrtf(s2 * (1.0f / DMODEL) - mu * mu + 1e-5f);
  const float4 wv4 = ((const float4*)w)[t];
  const float4 bv4 = ((const float4*)bias)[t];
  ushort4 o;
  o.x = f2bf((xv.x - mu) * rs * wv4.x + bv4.x);
  o.y = f2bf((xv.y - mu) * rs * wv4.y + bv4.y);
  o.z = f2bf((xv.z - mu) * rs * wv4.z + bv4.z);
  o.w = f2bf((xv.w - mu) * rs * wv4.w + bv4.w);
  ((ushort4*)(h + (size_t)row * DMODEL))[t] = o;
}

// ============ 256x192 4-phase GEMM, C = A @ B^T (grid fills 256 CUs) ===========
// 512 thr = 8 waves (2M x 4N); per-wave 128x48 (acc[8][3]). BK=64, 2 K-tiles/iter.
// B fragments read ONCE per K-tile (kept in regs across the mh phase pair).
// MFMA cluster kk-outer: 12 independent acc chains per kk step.
template<int OUTMODE>
__global__ __launch_bounds__(512, 2) void k_gemm256(const u16* __restrict__ A, const u16* __restrict__ B,
                                                    void* __restrict__ Cv, int M, int N, int K) {
  __shared__ __align__(16) u16 As[2][256 * 64];   // 32 KB per buffer
  __shared__ __align__(16) u16 Bs[2][192 * 64];   // 24 KB per buffer
  const int t = threadIdx.x, lane = t & 63, w = t >> 6;
  const int wr = w >> 2, wc = w & 3;
  const int nbx = N / 192;                        // 16
  const int nwg = nbx * (M >> 8);                 // 256
  const int cpx = nwg >> 3;
  const int bid = blockIdx.x;
  const int sw = (bid & 7) * cpx + (bid >> 3);    // XCD swizzle (nwg % 8 == 0)
  const int m0 = (sw / nbx) * 256, n0 = (sw % nbx) * 192;
  const int NT = K >> 6;                          // 16
  const int cg16 = (lane >> 4) * 16;

  f32x4 acc[8][3] = {};
  bf16x8 af_[4][2], bf_[3][2];
  const u16* Ap = A + (size_t)m0 * K;
  const u16* Bp = B + (size_t)n0 * K;
  const int rr0 = t >> 3;
  const int sz = ((t & 7) * 8) ^ ((rr0 & 7) << 3);   // u16 units (inverse swizzle)
  const u16* pA[4] = { Ap + (size_t)rr0 * K + sz,
                       Ap + (size_t)(rr0 + 64) * K + sz,
                       Ap + (size_t)(rr0 + 128) * K + sz,
                       Ap + (size_t)(rr0 + 192) * K + sz };
  const u16* pB[3] = { Bp + (size_t)rr0 * K + sz,
                       Bp + (size_t)(rr0 + 64) * K + sz,
                       Bp + (size_t)(rr0 + 128) * K + sz };

#define SA2(b, h, EO) do { \
    GLD((char*)As + (b)*32768 + (h)*16384 + w*1024,        pA[(h)*2]     + (EO)); \
    GLD((char*)As + (b)*32768 + (h)*16384 + 8192 + w*1024, pA[(h)*2 + 1] + (EO)); \
  } while (0)
#define SB3(b, EO) do { \
    GLD((char*)Bs + (b)*24576 +         w*1024, pB[0] + (EO)); \
    GLD((char*)Bs + (b)*24576 +  8192 + w*1024, pB[1] + (EO)); \
    GLD((char*)Bs + (b)*24576 + 16384 + w*1024, pB[2] + (EO)); \
  } while (0)

#define READ_AF(asb, mh) do { \
    _Pragma("unroll") for (int i2 = 0; i2 < 4; i2++) { \
      const int rowA = (((mh)*4 + i2)*2 + wr)*16 + (lane & 15); \
      const int sA = (rowA & 7) << 4; \
      _Pragma("unroll") for (int kk = 0; kk < 2; kk++) \
        af_[i2][kk] = *(const bf16x8*)((const char*)(asb) + (rowA & 127)*128 + ((kk*64 + cg16) ^ sA)); \
    } } while (0)
#define READ_BF(bsb) do { \
    _Pragma("unroll") for (int j2 = 0; j2 < 3; j2++) { \
      const int rowB = (j2*4 + wc)*16 + (lane & 15); \
      const int sB = (rowB & 7) << 4; \
      _Pragma("unroll") for (int kk = 0; kk < 2; kk++) \
        bf_[j2][kk] = *(const bf16x8*)((const char*)(bsb) + rowB*128 + ((kk*64 + cg16) ^ sB)); \
    } } while (0)
#define MFMA24(mh) do { \
    _Pragma("unroll") for (int kk = 0; kk < 2; kk++) \
      _Pragma("unroll") for (int i2 = 0; i2 < 4; i2++) \
        _Pragma("unroll") for (int j2 = 0; j2 < 3; j2++) \
          acc[(mh)*4+i2][j2] = __builtin_amdgcn_mfma_f32_16x16x32_bf16( \
              af_[i2][kk], bf_[j2][kk], acc[(mh)*4+i2][j2], 0, 0, 0); \
  } while (0)

  SA2(0, 0, 0); SA2(0, 1, 0); SB3(0, 0);
  SA2(1, 0, 64);
  VM(2);
  __builtin_amdgcn_s_barrier();

  const char* a0  = (const char*)As;
  const char* a0h = a0 + 16384;
  const char* a1  = a0 + 32768;
  const char* a1h = a0 + 49152;
  const char* b0  = (const char*)Bs;
  const char* b1  = b0 + 24576;
  const int NIT = NT >> 1;
  for (int i = 0; i < NIT; i++) {
    const bool lst = (i == NIT - 1);
    // P1: mh0 of buf0 (reads A h0 + all B frags of tile t0)
    READ_AF(a0, 0); READ_BF(b0);
    SA2(1, 1, 64); SB3(1, 64);
    __builtin_amdgcn_s_barrier();
    asm volatile("s_waitcnt lgkmcnt(0)" ::: "memory");
    __builtin_amdgcn_s_setprio(1); MFMA24(0); __builtin_amdgcn_s_setprio(0);
    __builtin_amdgcn_s_barrier();
    // P2: mh1 of buf0 (reuse bf_ registers)
    READ_AF(a0h, 1);
    if (!lst) SA2(0, 0, 128);
    __builtin_amdgcn_s_barrier();
    asm volatile("s_waitcnt lgkmcnt(0)" ::: "memory");
    __builtin_amdgcn_s_setprio(1); MFMA24(1); __builtin_amdgcn_s_setprio(0);
    if (lst) VM(0); else VM(2);
    __builtin_amdgcn_s_barrier();
    // P3: mh0 of buf1
    READ_AF(a1, 0); READ_BF(b1);
    if (!lst) { SA2(0, 1, 128); SB3(0, 128); }
    __builtin_amdgcn_s_barrier();
    asm volatile("s_waitcnt lgkmcnt(0)" ::: "memory");
    __builtin_amdgcn_s_setprio(1); MFMA24(0); __builtin_amdgcn_s_setprio(0);
    __builtin_amdgcn_s_barrier();
    // P4: mh1 of buf1 (reuse bf_)
    READ_AF(a1h, 1);
    if (!lst) SA2(1, 0, 192);
    __builtin_amdgcn_s_barrier();
    asm volatile("s_waitcnt lgkmcnt(0)" ::: "memory");
    __builtin_amdgcn_s_setprio(1); MFMA24(1); __builtin_amdgcn_s_setprio(0);
    if (!lst) VM(2);
    __builtin_amdgcn_s_barrier();
    pA[0] += 128; pA[1] += 128; pA[2] += 128; pA[3] += 128;
    pB[0] += 128; pB[1] += 128; pB[2] += 128;
  }
#undef MFMA24
#undef READ_BF
#undef READ_AF
#undef SA2
#undef SB3

  const int cr = (lane >> 4) * 4, cc = lane & 15;
#pragma unroll
  for (int fi = 0; fi < 8; fi++)
#pragma unroll
    for (int fj = 0; fj < 3; fj++) {
      const size_t roff = (size_t)(m0 + (fi * 2 + wr) * 16 + cr) * N + (n0 + (fj * 4 + wc) * 16 + cc);
      if (OUTMODE == 0) {
        float* Cp = (float*)Cv + roff;
#pragma unroll
        for (int r = 0; r < 4; r++) Cp[(size_t)r * N] = acc[fi][fj][r];
      } else {
        u16* Cp = (u16*)Cv + roff;
#pragma unroll
        for (int r = 0; r < 4; r++) Cp[(size_t)r * N] = f2bf(acc[fi][fj][r]);
      }
    }
}

// ------- bf16 GEMM 128^2 2-phase with chunked XCD swizzle (used for GEMM2) -----
template<int OUTMODE>
__global__ __launch_bounds__(256) void k_gemm_bt(const u16* __restrict__ A, const u16* __restrict__ B,
                                                 void* __restrict__ Cv, int M, int N, int K) {
  __shared__ __align__(16) u16 As[2][128 * 64];
  __shared__ __align__(16) u16 Bs[2][128 * 64];
  const int t = threadIdx.x;
  const int lane = t & 63, w = t >> 6;
  const int nbx = N >> 7;
  const int nwg = nbx * (M >> 7);
  const int cpx = nwg >> 3;
  const int bid = blockIdx.x;
  const int sw = (bid & 7) * cpx + (bid >> 3);    // chunked XCD swizzle (nwg%8==0)
  const int m0 = (sw / nbx) * 128, n0 = (sw % nbx) * 128;
  const int wm = (w >> 1) * 64, wn = (w & 1) * 64;
  const int NT = K >> 6;
  f32x4 acc[4][4] = {};
  const u16* Ap = A + (size_t)m0 * K;
  const u16* Bp = B + (size_t)n0 * K;
  const int cr0 = lane >> 3, cs = lane & 7;

#define GSTAGE(bb, kt_) do { \
    _Pragma("unroll") \
    for (int s2 = 0; s2 < 4; s2++) { \
      int ch = w * 4 + s2; \
      int row = ch * 8 + cr0; \
      int cb = cs ^ (row & 7); \
      GLD((char*)As[bb] + ch * 1024, Ap + (size_t)row * K + (kt_) * 64 + cb * 8); \
      GLD((char*)Bs[bb] + ch * 1024, Bp + (size_t)row * K + (kt_) * 64 + cb * 8); \
    } } while (0)

  GSTAGE(0, 0);
  VM(0);
  __builtin_amdgcn_s_barrier();
  int cur = 0;
  for (int kt = 0; kt < NT; kt++) {
    if (kt + 1 < NT) GSTAGE(cur ^ 1, kt + 1);
    const u16* asb = As[cur];
    const u16* bsb = Bs[cur];
#pragma unroll
    for (int kk = 0; kk < 2; kk++) {
      bf16x8 af[4], bfr[4];
#pragma unroll
      for (int i = 0; i < 4; i++) {
        int rowa = wm + i * 16 + (lane & 15);
        af[i] = *(const bf16x8*)((const char*)asb + rowa * 128 + ((kk * 64 + (lane >> 4) * 16) ^ ((rowa & 7) << 4)));
        int rowb = wn + i * 16 + (lane & 15);
        bfr[i] = *(const bf16x8*)((const char*)bsb + rowb * 128 + ((kk * 64 + (lane >> 4) * 16) ^ ((rowb & 7) << 4)));
      }
#pragma unroll
      for (int mf = 0; mf < 4; mf++)
#pragma unroll
        for (int nf = 0; nf < 4; nf++)
          acc[mf][nf] = __builtin_amdgcn_mfma_f32_16x16x32_bf16(af[mf], bfr[nf], acc[mf][nf], 0, 0, 0);
    }
    VM(0);
    __builtin_amdgcn_s_barrier();
    cur ^= 1;
  }
#undef GSTAGE
  const int cr = (lane >> 4) * 4, cc = lane & 15;
#pragma unroll
  for (int mf = 0; mf < 4; mf++)
#pragma unroll
    for (int nf = 0; nf < 4; nf++) {
      if (OUTMODE == 0) {
        float* Cp = (float*)Cv + (size_t)(m0 + wm + mf * 16 + cr) * N + (n0 + wn + nf * 16 + cc);
#pragma unroll
        for (int r = 0; r < 4; r++) Cp[(size_t)r * N] = acc[mf][nf][r];
      } else {
        u16* Cp = (u16*)Cv + (size_t)(m0 + wm + mf * 16 + cr) * N + (n0 + wn + nf * 16 + cc);
#pragma unroll
        for (int r = 0; r < 4; r++) Cp[(size_t)r * N] = f2bf(acc[mf][nf][r]);
      }
    }
}

// ---------------- q/k layernorm (over full D, bf16 in) + RoPE + head split -----
__global__ __launch_bounds__(256) void k_qk_ln_rope(const u16* __restrict__ qkv,
                                                    const float* __restrict__ qw, const float* __restrict__ kw,
                                                    const float* __restrict__ cosb, const float* __restrict__ sinb,
                                                    u16* __restrict__ Q, u16* __restrict__ K, u16* __restrict__ V) {
  int row = blockIdx.x, t = threadIdx.x;
  int b = row >> 11, l = row & 2047;
  const u16* base = qkv + (size_t)row * 3072;
  ushort4 qu = ((const ushort4*)base)[t];
  ushort4 ku = ((const ushort4*)(base + 1024))[t];
  ushort4 vu = ((const ushort4*)(base + 2048))[t];
  float qx = bf2f(qu.x), qy = bf2f(qu.y), qz = bf2f(qu.z), qw_ = bf2f(qu.w);
  float kx = bf2f(ku.x), ky = bf2f(ku.y), kz = bf2f(ku.z), kw_ = bf2f(ku.w);
  float red[4];
  red[0] = qx + qy + qz + qw_;
  red[1] = qx * qx + qy * qy + qz * qz + qw_ * qw_;
  red[2] = kx + ky + kz + kw_;
  red[3] = kx * kx + ky * ky + kz * kz + kw_ * kw_;
#pragma unroll
  for (int i = 0; i < 4; i++)
#pragma unroll
    for (int m2 = 1; m2 < 64; m2 <<= 1) red[i] += __shfl_xor(red[i], m2);
  __shared__ float rb[4][4];
  int w = t >> 6;
  if ((t & 63) == 0) { rb[w][0] = red[0]; rb[w][1] = red[1]; rb[w][2] = red[2]; rb[w][3] = red[3]; }
  __syncthreads();
  float S1 = rb[0][0] + rb[1][0] + rb[2][0] + rb[3][0];
  float S2 = rb[0][1] + rb[1][1] + rb[2][1] + rb[3][1];
  float S3 = rb[0][2] + rb[1][2] + rb[2][2] + rb[3][2];
  float S4 = rb[0][3] + rb[1][3] + rb[2][3] + rb[3][3];
  float muq = S1 * (1.0f / DMODEL), rsq = rsqrtf(S2 * (1.0f / DMODEL) - muq * muq + 1e-5f);
  float muk = S3 * (1.0f / DMODEL), rsk = rsqrtf(S4 * (1.0f / DMODEL) - muk * muk + 1e-5f);
  __shared__ float qs[1024], ks[1024];
  float4 qwv = ((const float4*)qw)[t];
  float4 kwv = ((const float4*)kw)[t];
  qs[t * 4 + 0] = (qx - muq) * rsq * qwv.x;  ks[t * 4 + 0] = (kx - muk) * rsk * kwv.x;
  qs[t * 4 + 1] = (qy - muq) * rsq * qwv.y;  ks[t * 4 + 1] = (ky - muk) * rsk * kwv.y;
  qs[t * 4 + 2] = (qz - muq) * rsq * qwv.z;  ks[t * 4 + 2] = (kz - muk) * rsk * kwv.z;
  qs[t * 4 + 3] = (qw_ - muq) * rsq * qwv.w; ks[t * 4 + 3] = (kw_ - muk) * rsk * kwv.w;
  __syncthreads();
  int d0 = t * 4;
  int hh = d0 >> 6;
  union { ushort4 v4; u16 e[4]; } qo, ko;
#pragma unroll
  for (int i = 0; i < 4; i++) {
    int d = d0 + i, dd = d & 63, fr = dd & 31;
    float c = cosb[l * 32 + fr], s = sinb[l * 32 + fr];
    float q1 = qs[d], q2 = (dd < 32) ? -qs[d + 32] : qs[d - 32];
    float k1 = ks[d], k2 = (dd < 32) ? -ks[d + 32] : ks[d - 32];
    qo.e[i] = f2bf(q1 * c + q2 * s);
    ko.e[i] = f2bf(k1 * c + k2 * s);
  }
  size_t oidx = ((size_t)(b * NHEAD + hh) * LSEQ + l) * DHEAD + (d0 & 63);
  *(ushort4*)(Q + oidx) = qo.v4;
  *(ushort4*)(K + oidx) = ko.v4;
  *(ushort4*)(V + oidx) = vu;
}

// -- segment-masked flash attention: QBLK=128, 8 waves, XCD-chunked, 2-deep pipe -
__global__ __launch_bounds__(512) void k_attn(const u16* __restrict__ Q, const u16* __restrict__ Kb,
                                              const u16* __restrict__ VTb, const int* __restrict__ seq,
                                              const int* __restrict__ bnd, u16* __restrict__ ctx) {
  __shared__ __align__(16) u16 Ks[2][64 * 64];   // 8 KB / buf
  __shared__ __align__(16) u16 Vs[2][64 * 64];   // 8 KB / buf
  __shared__ __align__(16) u16 Pw[8][16 * 64];   // 2 KB / wave  (48 KB total -> 3 blocks/CU)

  // XCD-chunked swizzle: nwg = 512, XCD x gets 64 consecutive sw -> 4 whole heads
  const int bid = blockIdx.x;
  const int sw = (bid & 7) * 64 + (bid >> 3);
  const int qt = sw & 15, h = (sw >> 4) & 15, b = sw >> 8;
  const int t = threadIdx.x, l = t & 63, w = t >> 6;
  const int c = l & 15, g = l >> 4;
  const int q0 = qt * 128;
  const size_t hoff = (size_t)(b * NHEAD + h) * LSEQ * DHEAD;
  const u16* Qg = Q + hoff;
  const u16* Kg = Kb + hoff;
  const u16* Vg = VTb + hoff;   // [d][l]
  const int* seqb = seq + b * LSEQ;
  const int* bnd5 = bnd + b * 5;

  const int qw0 = q0 + w * 16;
  const int myq = qw0 + c;
  const int sq = seqb[myq];
  const int lo = bnd5[sq], hi = bnd5[sq + 1];
  const int wlo = bnd5[seqb[qw0]];
  const int whi = bnd5[seqb[qw0 + 15] + 1];
  int kbeg = bnd5[seqb[q0]] & ~63;
  int kend = (bnd5[seqb[q0 + 127] + 1] + 63) & ~63;
  if (kend > LSEQ) kend = LSEQ;

  bf16x8 qf[2];
  qf[0] = *(const bf16x8*)(Qg + (size_t)myq * 64 + g * 8);
  qf[1] = *(const bf16x8*)(Qg + (size_t)myq * 64 + 32 + g * 8);

  f32x4 acc[4] = {};
  float lsum = 0.f;

  // staging: 512 thr x 16B = one full 64x64 tile per buffer
  const int rr = t >> 3;
  const int szk = ((t & 7) * 8) ^ ((rr & 7) << 3);   // u16 units (inverse swizzle)
  const u16* pK = Kg + (size_t)rr * 64 + szk;        // + kt*64 per tile
  const u16* pV = Vg + (size_t)rr * LSEQ + szk;      // + kt   per tile

#define STAGE(bb, kt_) do { \
    GLD((char*)Ks[bb] + w * 1024, pK + (size_t)(kt_) * 64); \
    GLD((char*)Vs[bb] + w * 1024, pV + (kt_)); \
  } while (0)

  STAGE(0, kbeg);
  int cur = 0;
  for (int kt = kbeg; kt < kend; kt += 64) {
    const bool more = (kt + 64) < kend;
    if (more) STAGE(cur ^ 1, kt + 64);
    if (more) VM(2);
    else      VM(0);
    __builtin_amdgcn_s_barrier();
    __builtin_amdgcn_sched_barrier(0);
    if (kt < whi && kt + 64 > wlo) {
      const u16* ksb = Ks[cur];
      const u16* vsb = Vs[cur];
      f32x4 st[4] = {};
#pragma unroll
      for (int kk = 0; kk < 2; kk++) {
        bf16x8 kf[4];
#pragma unroll
        for (int i = 0; i < 4; i++) {
          int row = i * 16 + c;
          kf[i] = *(const bf16x8*)((const char*)ksb + row * 128 + ((kk * 64 + g * 16) ^ ((row & 7) << 4)));
        }
#pragma unroll
        for (int i = 0; i < 4; i++)
          st[i] = __builtin_amdgcn_mfma_f32_16x16x32_bf16(kf[i], qf[kk], st[i], 0, 0, 0);
      }
      const int kb0 = kt + g * 4;
#pragma unroll
      for (int i = 0; i < 4; i++) {
        float p[4];
#pragma unroll
        for (int r = 0; r < 4; r++) {
          int kglob = kb0 + i * 16 + r;
          bool ok = ((unsigned)(kglob - lo)) < ((unsigned)(hi - lo));
          float x = ok ? fmaf(st[i][r], 0.125f, -8.0f) : -1e30f;
          p[r] = __expf(x);
          lsum += p[r];
        }
        unsigned w0, w1;
        asm("v_cvt_pk_bf16_f32 %0, %1, %2" : "=v"(w0) : "v"(p[0]), "v"(p[1]));
        asm("v_cvt_pk_bf16_f32 %0, %1, %2" : "=v"(w1) : "v"(p[2]), "v"(p[3]));
        uint2 wp; wp.x = w0; wp.y = w1;
        *(uint2*)((char*)Pw[w] + c * 128 + ((i * 32 + g * 8) ^ ((c & 7) << 4))) = wp;
      }
#pragma unroll
      for (int kk = 0; kk < 2; kk++) {
        bf16x8 pa = *(const bf16x8*)((char*)Pw[w] + c * 128 + ((kk * 64 + g * 16) ^ ((c & 7) << 4)));
        bf16x8 vf[4];
#pragma unroll
        for (int df = 0; df < 4; df++) {
          int row = df * 16 + c;
          vf[df] = *(const bf16x8*)((const char*)vsb + row * 128 + ((kk * 64 + g * 16) ^ ((row & 7) << 4)));
        }
#pragma unroll
        for (int df = 0; df < 4; df++)
          acc[df] = __builtin_amdgcn_mfma_f32_16x16x32_bf16(pa, vf[df], acc[df], 0, 0, 0);
      }
    }
    __builtin_amdgcn_sched_barrier(0);
    __builtin_amdgcn_s_barrier();
    cur ^= 1;
  }
#undef STAGE

  lsum += __shfl_xor(lsum, 16);
  lsum += __shfl_xor(lsum, 32);
#pragma unroll
  for (int r = 0; r < 4; r++) {
    float lr = __shfl(lsum, g * 4 + r, 64);
    float rls = 1.0f / lr;
    int qrow = qw0 + g * 4 + r;
    u16* op = ctx + (size_t)(b * LSEQ + qrow) * DMODEL + h * 64 + c;
#pragma unroll
    for (int df = 0; df < 4; df++)
      op[df * 16] = f2bf(acc[df][r] * rls);
  }
}

// ---------------- launch --------------------------------------------------------
extern "C" void kernel_launch(void* const* d_in, const int* in_sizes, int n_in,
                              void* d_out, int out_size, void* d_ws, size_t ws_size,
                              hipStream_t stream) {
  const float* x    = (const float*)d_in[0];
  const int*   seq  = (const int*)d_in[1];
  const float* ln1w = (const float*)d_in[2];
  const float* ln1b = (const float*)d_in[3];
  const float* wqkv = (const float*)d_in[4];
  const float* qlnw = (const float*)d_in[5];
  const float* klnw = (const float*)d_in[6];
  const float* wout = (const float*)d_in[7];
  float* out = (float*)d_out;

  char* p = (char*)d_ws;
  u16* wqkvT = (u16*)p;  p += (size_t)3072 * 1024 * 2;
  u16* woutT = (u16*)p;  p += (size_t)1024 * 1024 * 2;
  u16* hbuf  = (u16*)p;  p += (size_t)ROWS * DMODEL * 2;
  u16* Qb    = (u16*)p;  p += (size_t)ROWS * DMODEL * 2;
  u16* Kbuf  = (u16*)p;  p += (size_t)ROWS * DMODEL * 2;
  u16* Vbuf  = (u16*)p;  p += (size_t)ROWS * DMODEL * 2;
  u16* VTbuf = (u16*)p;  p += (size_t)ROWS * DMODEL * 2;
  u16* ctxb  = (u16*)p;  p += (size_t)ROWS * DMODEL * 2;
  float* cosb = (float*)p; p += (size_t)LSEQ * 32 * 4;
  float* sinb = (float*)p; p += (size_t)LSEQ * 32 * 4;
  int* bnd   = (int*)p;  p += 256;
  u16* qkv   = (u16*)p;  p += (size_t)ROWS * 3072 * 2;

  k_transpose_cvt<<<dim3(3072 / 32, 1024 / 32), dim3(32, 8), 0, stream>>>(wqkv, wqkvT, 1024, 3072);
  k_transpose_cvt<<<dim3(1024 / 32, 1024 / 32), dim3(32, 8), 0, stream>>>(wout, woutT, 1024, 1024);
  k_rope_tables<<<(LSEQ * 32) / 256, 256, 0, stream>>>(cosb, sinb, seq, bnd);
  k_ln1<<<ROWS, 256, 0, stream>>>(x, ln1w, ln1b, hbuf);
  k_gemm256<1><<<(ROWS / 256) * (3072 / 192), 512, 0, stream>>>(hbuf, wqkvT, (void*)qkv, ROWS, 3072, 1024);
  k_qk_ln_rope<<<ROWS, 256, 0, stream>>>(qkv, qlnw, klnw, cosb, sinb, Qb, Kbuf, Vbuf);
  k_transpose_u16<<<dim3(DHEAD / 32, LSEQ / 32, BATCH * NHEAD), dim3(32, 8), 0, stream>>>(Vbuf, VTbuf);
  k_attn<<<BATCH * NHEAD * (LSEQ / 128), 512, 0, stream>>>(Qb, Kbuf, VTbuf, seq, bnd, ctxb);
  k_gemm_bt<0><<<(ROWS / 128) * (1024 / 128), 256, 0, stream>>>(ctxb, woutT, (void*)out, ROWS, 1024, 1024);
}

// Round 12
// 112.289 us; speedup vs baseline: 1.2467x; 1.0978x over previous
//
#include <hip/hip_runtime.h>
#include <hip/hip_bf16.h>
#include <cstdint>
#include <math.h>

#define LSEQ 2048
#define BATCH 2
#define NHEAD 16
#define DHEAD 64
#define DMODEL 1024
#define ROWS (BATCH*LSEQ)

typedef __bf16 bf16x8 __attribute__((ext_vector_type(8)));
typedef float f32x4 __attribute__((ext_vector_type(4)));
typedef unsigned short u16;

#define GLD(lds_base, src_g) \
  __builtin_amdgcn_global_load_lds((const __attribute__((address_space(1))) void*)(src_g), \
                                   (__attribute__((address_space(3))) void*)(lds_base), 16, 0, 0)
#define VM(n) asm volatile("s_waitcnt vmcnt(" #n ")" ::: "memory")

__device__ __forceinline__ u16 f2bf(float f) {
  unsigned int u = __float_as_uint(f);
  u += 0x7fffu + ((u >> 16) & 1u);
  return (u16)(u >> 16);
}
__device__ __forceinline__ float bf2f(u16 u) {
  return __uint_as_float(((unsigned)u) << 16);
}

// ---------------- u16 transpose per head: in [L][64] -> out [64][L] ------------
__global__ void k_transpose_u16(const u16* __restrict__ in, u16* __restrict__ out) {
  __shared__ u16 tile[32][33];
  int hd = blockIdx.z;
  int l0 = blockIdx.y * 32, d0 = blockIdx.x * 32;
  const u16* ip = in + (size_t)hd * LSEQ * DHEAD;
  u16* op = out + (size_t)hd * LSEQ * DHEAD;
  int tx = threadIdx.x, ty = threadIdx.y;
#pragma unroll
  for (int i = 0; i < 32; i += 8)
    tile[ty + i][tx] = ip[(size_t)(l0 + ty + i) * DHEAD + d0 + tx];
  __syncthreads();
#pragma unroll
  for (int i = 0; i < 32; i += 8)
    op[(size_t)(d0 + ty + i) * LSEQ + l0 + tx] = tile[tx][ty + i];
}

// ---- fused prep: ln1 (4096) | wqkv^T (3072) | wout^T (1024) | rope+bnd (256) --
__global__ __launch_bounds__(256) void k_prep(const float* __restrict__ x, const float* __restrict__ ln1w,
                                              const float* __restrict__ ln1b, u16* __restrict__ hbuf,
                                              const float* __restrict__ wqkv, u16* __restrict__ wqkvT,
                                              const float* __restrict__ wout, u16* __restrict__ woutT,
                                              const int* __restrict__ seq, int* __restrict__ bnd,
                                              float* __restrict__ cosb, float* __restrict__ sinb) {
  __shared__ float tile[32][33];
  __shared__ float rb[2][4];
  const int bid = blockIdx.x, t = threadIdx.x;
  if (bid < 4096) {
    // ---- LN1 row ----
    const int row = bid;
    const float4 xv = ((const float4*)(x + (size_t)row * DMODEL))[t];
    float s = xv.x + xv.y + xv.z + xv.w;
    float s2 = xv.x * xv.x + xv.y * xv.y + xv.z * xv.z + xv.w * xv.w;
#pragma unroll
    for (int m2 = 1; m2 < 64; m2 <<= 1) { s += __shfl_xor(s, m2); s2 += __shfl_xor(s2, m2); }
    int wv = t >> 6;
    if ((t & 63) == 0) { rb[0][wv] = s; rb[1][wv] = s2; }
    __syncthreads();
    s  = rb[0][0] + rb[0][1] + rb[0][2] + rb[0][3];
    s2 = rb[1][0] + rb[1][1] + rb[1][2] + rb[1][3];
    float mu = s * (1.0f / DMODEL);
    float rs = rsqrtf(s2 * (1.0f / DMODEL) - mu * mu + 1e-5f);
    const float4 wv4 = ((const float4*)ln1w)[t];
    const float4 bv4 = ((const float4*)ln1b)[t];
    ushort4 o;
    o.x = f2bf((xv.x - mu) * rs * wv4.x + bv4.x);
    o.y = f2bf((xv.y - mu) * rs * wv4.y + bv4.y);
    o.z = f2bf((xv.z - mu) * rs * wv4.z + bv4.z);
    o.w = f2bf((xv.w - mu) * rs * wv4.w + bv4.w);
    ((ushort4*)(hbuf + (size_t)row * DMODEL))[t] = o;
  } else if (bid < 4096 + 3072 + 1024) {
    // ---- weight transpose+cvt: out[c][r] = bf16(in[r][c]) ----
    const float* in; u16* out; int R, C, bx, by;
    if (bid < 4096 + 3072) { int rel = bid - 4096; in = wqkv; out = wqkvT; R = 1024; C = 3072; bx = rel % 96; by = rel / 96; }
    else                   { int rel = bid - 7168; in = wout; out = woutT; R = 1024; C = 1024; bx = rel % 32; by = rel / 32; }
    int c0 = bx * 32, r0 = by * 32;
    int tx = t & 31, ty = t >> 5;
#pragma unroll
    for (int i = 0; i < 32; i += 8)
      tile[ty + i][tx] = in[(size_t)(r0 + ty + i) * C + (c0 + tx)];
    __syncthreads();
#pragma unroll
    for (int i = 0; i < 32; i += 8)
      out[(size_t)(c0 + ty + i) * R + (r0 + tx)] = f2bf(tile[tx][ty + i]);
  } else {
    // ---- rope tables + segment bounds ----
    const int rel = bid - 8192;
    if (rel == 0 && t < BATCH * 5) {
      int b = t / 5, s = t % 5;
      const int* row = seq + b * LSEQ;
      int lo = 0, hi = LSEQ;
      while (lo < hi) { int mid = (lo + hi) >> 1; if (row[mid] < s) lo = mid + 1; else hi = mid; }
      bnd[b * 5 + s] = lo;
    }
    int idx = rel * 256 + t;
    if (idx < LSEQ * 32) {
      int l = idx >> 5, f = idx & 31;
      double inv = pow(10000.0, -(double)f / 32.0);
      float ang = (float)l * (float)inv;
      cosb[idx] = cosf(ang);
      sinb[idx] = sinf(ang);
    }
  }
}

// ============ 128x192 4-phase GEMM, C = A @ B^T (80 KB LDS -> 2 blocks/CU) =====
// 512 thr = 8 waves (2M x 4N); per-wave 64x48 (acc[4][3]). BK=64, 2 K-tiles/iter.
// 5 GLD/K-tile; VM(1) at P2/P4 completes exactly the buffer about to be read.
template<int OUTMODE>
__global__ __launch_bounds__(512, 4) void k_gemm256(const u16* __restrict__ A, const u16* __restrict__ B,
                                                    void* __restrict__ Cv, int M, int N, int K) {
  __shared__ __align__(16) u16 As[2][128 * 64];   // 16 KB per buffer
  __shared__ __align__(16) u16 Bs[2][192 * 64];   // 24 KB per buffer
  const int t = threadIdx.x, lane = t & 63, w = t >> 6;
  const int wr = w >> 2, wc = w & 3;
  const int nbx = N / 192;                        // 16
  const int nwg = nbx * (M >> 7);                 // 512
  const int cpx = nwg >> 3;                       // 64
  const int bid = blockIdx.x;
  const int sw = (bid & 7) * cpx + (bid >> 3);    // XCD swizzle (nwg % 8 == 0)
  const int m0 = (sw / nbx) * 128, n0 = (sw % nbx) * 192;
  const int NT = K >> 6;                          // 16
  const int cg16 = (lane >> 4) * 16;

  f32x4 acc[4][3] = {};
  bf16x8 af_[2][2], bf_[3][2];
  const u16* Ap = A + (size_t)m0 * K;
  const u16* Bp = B + (size_t)n0 * K;
  const int rr0 = t >> 3;                         // 0..63
  const int sz = ((t & 7) * 8) ^ ((rr0 & 7) << 3);   // u16 units (inverse swizzle)
  const u16* pA[2] = { Ap + (size_t)rr0 * K + sz,
                       Ap + (size_t)(rr0 + 64) * K + sz };
  const u16* pB[3] = { Bp + (size_t)rr0 * K + sz,
                       Bp + (size_t)(rr0 + 64) * K + sz,
                       Bp + (size_t)(rr0 + 128) * K + sz };

#define SA1(b, h, EO) GLD((char*)As + (b)*16384 + (h)*8192 + w*1024, pA[h] + (EO))
#define SB3(b, EO) do { \
    GLD((char*)Bs + (b)*24576 +         w*1024, pB[0] + (EO)); \
    GLD((char*)Bs + (b)*24576 +  8192 + w*1024, pB[1] + (EO)); \
    GLD((char*)Bs + (b)*24576 + 16384 + w*1024, pB[2] + (EO)); \
  } while (0)

#define READ_AF(asb, mh) do { \
    _Pragma("unroll") for (int i2 = 0; i2 < 2; i2++) { \
      const int rowA = (((mh)*2 + i2)*2 + wr)*16 + (lane & 15); \
      const int sA = (rowA & 7) << 4; \
      _Pragma("unroll") for (int kk = 0; kk < 2; kk++) \
        af_[i2][kk] = *(const bf16x8*)((const char*)(asb) + (rowA & 63)*128 + ((kk*64 + cg16) ^ sA)); \
    } } while (0)
#define READ_BF(bsb) do { \
    _Pragma("unroll") for (int j2 = 0; j2 < 3; j2++) { \
      const int rowB = (j2*4 + wc)*16 + (lane & 15); \
      const int sB = (rowB & 7) << 4; \
      _Pragma("unroll") for (int kk = 0; kk < 2; kk++) \
        bf_[j2][kk] = *(const bf16x8*)((const char*)(bsb) + rowB*128 + ((kk*64 + cg16) ^ sB)); \
    } } while (0)
#define MFMA12(mh) do { \
    _Pragma("unroll") for (int kk = 0; kk < 2; kk++) \
      _Pragma("unroll") for (int i2 = 0; i2 < 2; i2++) \
        _Pragma("unroll") for (int j2 = 0; j2 < 3; j2++) \
          acc[(mh)*2+i2][j2] = __builtin_amdgcn_mfma_f32_16x16x32_bf16( \
              af_[i2][kk], bf_[j2][kk], acc[(mh)*2+i2][j2], 0, 0, 0); \
  } while (0)

  // prologue: buf0 tile0 full (A h0+h1 + B = 5 loads) + buf1 A h0 of tile1 (1)
  SA1(0, 0, 0); SA1(0, 1, 0); SB3(0, 0);
  SA1(1, 0, 64);
  VM(1);
  __builtin_amdgcn_s_barrier();

  const char* a0  = (const char*)As;
  const char* a0h = a0 + 8192;
  const char* a1  = a0 + 16384;
  const char* a1h = a0 + 24576;
  const char* b0  = (const char*)Bs;
  const char* b1  = b0 + 24576;
  const int NIT = NT >> 1;
  for (int i = 0; i < NIT; i++) {
    const bool lst = (i == NIT - 1);
    // P1: mh0 of buf0
    READ_AF(a0, 0); READ_BF(b0);
    SA1(1, 1, 64); SB3(1, 64);
    __builtin_amdgcn_s_barrier();
    asm volatile("s_waitcnt lgkmcnt(0)" ::: "memory");
    __builtin_amdgcn_s_setprio(1); MFMA12(0); __builtin_amdgcn_s_setprio(0);
    __builtin_amdgcn_s_barrier();
    // P2: mh1 of buf0 (reuse bf_)
    READ_AF(a0h, 1);
    if (!lst) SA1(0, 0, 128);
    __builtin_amdgcn_s_barrier();
    asm volatile("s_waitcnt lgkmcnt(0)" ::: "memory");
    __builtin_amdgcn_s_setprio(1); MFMA12(1); __builtin_amdgcn_s_setprio(0);
    if (lst) VM(0); else VM(1);
    __builtin_amdgcn_s_barrier();
    // P3: mh0 of buf1
    READ_AF(a1, 0); READ_BF(b1);
    if (!lst) { SA1(0, 1, 128); SB3(0, 128); }
    __builtin_amdgcn_s_barrier();
    asm volatile("s_waitcnt lgkmcnt(0)" ::: "memory");
    __builtin_amdgcn_s_setprio(1); MFMA12(0); __builtin_amdgcn_s_setprio(0);
    __builtin_amdgcn_s_barrier();
    // P4: mh1 of buf1 (reuse bf_)
    READ_AF(a1h, 1);
    if (!lst) SA1(1, 0, 192);
    __builtin_amdgcn_s_barrier();
    asm volatile("s_waitcnt lgkmcnt(0)" ::: "memory");
    __builtin_amdgcn_s_setprio(1); MFMA12(1); __builtin_amdgcn_s_setprio(0);
    if (!lst) VM(1);
    __builtin_amdgcn_s_barrier();
    pA[0] += 128; pA[1] += 128;
    pB[0] += 128; pB[1] += 128; pB[2] += 128;
  }
#undef MFMA12
#undef READ_BF
#undef READ_AF
#undef SA1
#undef SB3

  const int cr = (lane >> 4) * 4, cc = lane & 15;
#pragma unroll
  for (int fi = 0; fi < 4; fi++)
#pragma unroll
    for (int fj = 0; fj < 3; fj++) {
      const size_t roff = (size_t)(m0 + (fi * 2 + wr) * 16 + cr) * N + (n0 + (fj * 4 + wc) * 16 + cc);
      if (OUTMODE == 0) {
        float* Cp = (float*)Cv + roff;
#pragma unroll
        for (int r = 0; r < 4; r++) Cp[(size_t)r * N] = acc[fi][fj][r];
      } else {
        u16* Cp = (u16*)Cv + roff;
#pragma unroll
        for (int r = 0; r < 4; r++) Cp[(size_t)r * N] = f2bf(acc[fi][fj][r]);
      }
    }
}

// ------- bf16 GEMM 128^2 2-phase with chunked XCD swizzle (used for GEMM2) -----
template<int OUTMODE>
__global__ __launch_bounds__(256) void k_gemm_bt(const u16* __restrict__ A, const u16* __restrict__ B,
                                                 void* __restrict__ Cv, int M, int N, int K) {
  __shared__ __align__(16) u16 As[2][128 * 64];
  __shared__ __align__(16) u16 Bs[2][128 * 64];
  const int t = threadIdx.x;
  const int lane = t & 63, w = t >> 6;
  const int nbx = N >> 7;
  const int nwg = nbx * (M >> 7);
  const int cpx = nwg >> 3;
  const int bid = blockIdx.x;
  const int sw = (bid & 7) * cpx + (bid >> 3);    // chunked XCD swizzle (nwg%8==0)
  const int m0 = (sw / nbx) * 128, n0 = (sw % nbx) * 128;
  const int wm = (w >> 1) * 64, wn = (w & 1) * 64;
  const int NT = K >> 6;
  f32x4 acc[4][4] = {};
  const u16* Ap = A + (size_t)m0 * K;
  const u16* Bp = B + (size_t)n0 * K;
  const int cr0 = lane >> 3, cs = lane & 7;

#define GSTAGE(bb, kt_) do { \
    _Pragma("unroll") \
    for (int s2 = 0; s2 < 4; s2++) { \
      int ch = w * 4 + s2; \
      int row = ch * 8 + cr0; \
      int cb = cs ^ (row & 7); \
      GLD((char*)As[bb] + ch * 1024, Ap + (size_t)row * K + (kt_) * 64 + cb * 8); \
      GLD((char*)Bs[bb] + ch * 1024, Bp + (size_t)row * K + (kt_) * 64 + cb * 8); \
    } } while (0)

  GSTAGE(0, 0);
  VM(0);
  __builtin_amdgcn_s_barrier();
  int cur = 0;
  for (int kt = 0; kt < NT; kt++) {
    if (kt + 1 < NT) GSTAGE(cur ^ 1, kt + 1);
    const u16* asb = As[cur];
    const u16* bsb = Bs[cur];
#pragma unroll
    for (int kk = 0; kk < 2; kk++) {
      bf16x8 af[4], bfr[4];
#pragma unroll
      for (int i = 0; i < 4; i++) {
        int rowa = wm + i * 16 + (lane & 15);
        af[i] = *(const bf16x8*)((const char*)asb + rowa * 128 + ((kk * 64 + (lane >> 4) * 16) ^ ((rowa & 7) << 4)));
        int rowb = wn + i * 16 + (lane & 15);
        bfr[i] = *(const bf16x8*)((const char*)bsb + rowb * 128 + ((kk * 64 + (lane >> 4) * 16) ^ ((rowb & 7) << 4)));
      }
#pragma unroll
      for (int mf = 0; mf < 4; mf++)
#pragma unroll
        for (int nf = 0; nf < 4; nf++)
          acc[mf][nf] = __builtin_amdgcn_mfma_f32_16x16x32_bf16(af[mf], bfr[nf], acc[mf][nf], 0, 0, 0);
    }
    VM(0);
    __builtin_amdgcn_s_barrier();
    cur ^= 1;
  }
#undef GSTAGE
  const int cr = (lane >> 4) * 4, cc = lane & 15;
#pragma unroll
  for (int mf = 0; mf < 4; mf++)
#pragma unroll
    for (int nf = 0; nf < 4; nf++) {
      if (OUTMODE == 0) {
        float* Cp = (float*)Cv + (size_t)(m0 + wm + mf * 16 + cr) * N + (n0 + wn + nf * 16 + cc);
#pragma unroll
        for (int r = 0; r < 4; r++) Cp[(size_t)r * N] = acc[mf][nf][r];
      } else {
        u16* Cp = (u16*)Cv + (size_t)(m0 + wm + mf * 16 + cr) * N + (n0 + wn + nf * 16 + cc);
#pragma unroll
        for (int r = 0; r < 4; r++) Cp[(size_t)r * N] = f2bf(acc[mf][nf][r]);
      }
    }
}

// ---------------- q/k layernorm (over full D, bf16 in) + RoPE + head split -----
__global__ __launch_bounds__(256) void k_qk_ln_rope(const u16* __restrict__ qkv,
                                                    const float* __restrict__ qw, const float* __restrict__ kw,
                                                    const float* __restrict__ cosb, const float* __restrict__ sinb,
                                                    u16* __restrict__ Q, u16* __restrict__ K, u16* __restrict__ V) {
  int row = blockIdx.x, t = threadIdx.x;
  int b = row >> 11, l = row & 2047;
  const u16* base = qkv + (size_t)row * 3072;
  ushort4 qu = ((const ushort4*)base)[t];
  ushort4 ku = ((const ushort4*)(base + 1024))[t];
  ushort4 vu = ((const ushort4*)(base + 2048))[t];
  float qx = bf2f(qu.x), qy = bf2f(qu.y), qz = bf2f(qu.z), qw_ = bf2f(qu.w);
  float kx = bf2f(ku.x), ky = bf2f(ku.y), kz = bf2f(ku.z), kw_ = bf2f(ku.w);
  float red[4];
  red[0] = qx + qy + qz + qw_;
  red[1] = qx * qx + qy * qy + qz * qz + qw_ * qw_;
  red[2] = kx + ky + kz + kw_;
  red[3] = kx * kx + ky * ky + kz * kz + kw_ * kw_;
#pragma unroll
  for (int i = 0; i < 4; i++)
#pragma unroll
    for (int m2 = 1; m2 < 64; m2 <<= 1) red[i] += __shfl_xor(red[i], m2);
  __shared__ float rb[4][4];
  int w = t >> 6;
  if ((t & 63) == 0) { rb[w][0] = red[0]; rb[w][1] = red[1]; rb[w][2] = red[2]; rb[w][3] = red[3]; }
  __syncthreads();
  float S1 = rb[0][0] + rb[1][0] + rb[2][0] + rb[3][0];
  float S2 = rb[0][1] + rb[1][1] + rb[2][1] + rb[3][1];
  float S3 = rb[0][2] + rb[1][2] + rb[2][2] + rb[3][2];
  float S4 = rb[0][3] + rb[1][3] + rb[2][3] + rb[3][3];
  float muq = S1 * (1.0f / DMODEL), rsq = rsqrtf(S2 * (1.0f / DMODEL) - muq * muq + 1e-5f);
  float muk = S3 * (1.0f / DMODEL), rsk = rsqrtf(S4 * (1.0f / DMODEL) - muk * muk + 1e-5f);
  __shared__ float qs[1024], ks[1024];
  float4 qwv = ((const float4*)qw)[t];
  float4 kwv = ((const float4*)kw)[t];
  qs[t * 4 + 0] = (qx - muq) * rsq * qwv.x;  ks[t * 4 + 0] = (kx - muk) * rsk * kwv.x;
  qs[t * 4 + 1] = (qy - muq) * rsq * qwv.y;  ks[t * 4 + 1] = (ky - muk) * rsk * kwv.y;
  qs[t * 4 + 2] = (qz - muq) * rsq * qwv.z;  ks[t * 4 + 2] = (kz - muk) * rsk * kwv.z;
  qs[t * 4 + 3] = (qw_ - muq) * rsq * qwv.w; ks[t * 4 + 3] = (kw_ - muk) * rsk * kwv.w;
  __syncthreads();
  int d0 = t * 4;
  int hh = d0 >> 6;
  union { ushort4 v4; u16 e[4]; } qo, ko;
#pragma unroll
  for (int i = 0; i < 4; i++) {
    int d = d0 + i, dd = d & 63, fr = dd & 31;
    float c = cosb[l * 32 + fr], s = sinb[l * 32 + fr];
    float q1 = qs[d], q2 = (dd < 32) ? -qs[d + 32] : qs[d - 32];
    float k1 = ks[d], k2 = (dd < 32) ? -ks[d + 32] : ks[d - 32];
    qo.e[i] = f2bf(q1 * c + q2 * s);
    ko.e[i] = f2bf(k1 * c + k2 * s);
  }
  size_t oidx = ((size_t)(b * NHEAD + hh) * LSEQ + l) * DHEAD + (d0 & 63);
  *(ushort4*)(Q + oidx) = qo.v4;
  *(ushort4*)(K + oidx) = ko.v4;
  *(ushort4*)(V + oidx) = vu;
}

// -- segment-masked flash attention: QBLK=128, 8 waves, XCD-chunked, 2-deep pipe -
__global__ __launch_bounds__(512) void k_attn(const u16* __restrict__ Q, const u16* __restrict__ Kb,
                                              const u16* __restrict__ VTb, const int* __restrict__ seq,
                                              const int* __restrict__ bnd, u16* __restrict__ ctx) {
  __shared__ __align__(16) u16 Ks[2][64 * 64];
  __shared__ __align__(16) u16 Vs[2][64 * 64];
  __shared__ __align__(16) u16 Pw[8][16 * 64];

  const int bid = blockIdx.x;
  const int sw = (bid & 7) * 64 + (bid >> 3);
  const int qt = sw & 15, h = (sw >> 4) & 15, b = sw >> 8;
  const int t = threadIdx.x, l = t & 63, w = t >> 6;
  const int c = l & 15, g = l >> 4;
  const int q0 = qt * 128;
  const size_t hoff = (size_t)(b * NHEAD + h) * LSEQ * DHEAD;
  const u16* Qg = Q + hoff;
  const u16* Kg = Kb + hoff;
  const u16* Vg = VTb + hoff;   // [d][l]
  const int* seqb = seq + b * LSEQ;
  const int* bnd5 = bnd + b * 5;

  const int qw0 = q0 + w * 16;
  const int myq = qw0 + c;
  const int sq = seqb[myq];
  const int lo = bnd5[sq], hi = bnd5[sq + 1];
  const int wlo = bnd5[seqb[qw0]];
  const int whi = bnd5[seqb[qw0 + 15] + 1];
  int kbeg = bnd5[seqb[q0]] & ~63;
  int kend = (bnd5[seqb[q0 + 127] + 1] + 63) & ~63;
  if (kend > LSEQ) kend = LSEQ;

  bf16x8 qf[2];
  qf[0] = *(const bf16x8*)(Qg + (size_t)myq * 64 + g * 8);
  qf[1] = *(const bf16x8*)(Qg + (size_t)myq * 64 + 32 + g * 8);

  f32x4 acc[4] = {};
  float lsum = 0.f;

  const int rr = t >> 3;
  const int szk = ((t & 7) * 8) ^ ((rr & 7) << 3);
  const u16* pK = Kg + (size_t)rr * 64 + szk;
  const u16* pV = Vg + (size_t)rr * LSEQ + szk;

#define STAGE(bb, kt_) do { \
    GLD((char*)Ks[bb] + w * 1024, pK + (size_t)(kt_) * 64); \
    GLD((char*)Vs[bb] + w * 1024, pV + (kt_)); \
  } while (0)

  STAGE(0, kbeg);
  int cur = 0;
  for (int kt = kbeg; kt < kend; kt += 64) {
    const bool more = (kt + 64) < kend;
    if (more) STAGE(cur ^ 1, kt + 64);
    if (more) VM(2);
    else      VM(0);
    __builtin_amdgcn_s_barrier();
    __builtin_amdgcn_sched_barrier(0);
    if (kt < whi && kt + 64 > wlo) {
      const u16* ksb = Ks[cur];
      const u16* vsb = Vs[cur];
      f32x4 st[4] = {};
#pragma unroll
      for (int kk = 0; kk < 2; kk++) {
        bf16x8 kf[4];
#pragma unroll
        for (int i = 0; i < 4; i++) {
          int row = i * 16 + c;
          kf[i] = *(const bf16x8*)((const char*)ksb + row * 128 + ((kk * 64 + g * 16) ^ ((row & 7) << 4)));
        }
#pragma unroll
        for (int i = 0; i < 4; i++)
          st[i] = __builtin_amdgcn_mfma_f32_16x16x32_bf16(kf[i], qf[kk], st[i], 0, 0, 0);
      }
      const int kb0 = kt + g * 4;
#pragma unroll
      for (int i = 0; i < 4; i++) {
        float p[4];
#pragma unroll
        for (int r = 0; r < 4; r++) {
          int kglob = kb0 + i * 16 + r;
          bool ok = ((unsigned)(kglob - lo)) < ((unsigned)(hi - lo));
          float x = ok ? fmaf(st[i][r], 0.125f, -8.0f) : -1e30f;
          p[r] = __expf(x);
          lsum += p[r];
        }
        unsigned w0, w1;
        asm("v_cvt_pk_bf16_f32 %0, %1, %2" : "=v"(w0) : "v"(p[0]), "v"(p[1]));
        asm("v_cvt_pk_bf16_f32 %0, %1, %2" : "=v"(w1) : "v"(p[2]), "v"(p[3]));
        uint2 wp; wp.x = w0; wp.y = w1;
        *(uint2*)((char*)Pw[w] + c * 128 + ((i * 32 + g * 8) ^ ((c & 7) << 4))) = wp;
      }
#pragma unroll
      for (int kk = 0; kk < 2; kk++) {
        bf16x8 pa = *(const bf16x8*)((char*)Pw[w] + c * 128 + ((kk * 64 + g * 16) ^ ((c & 7) << 4)));
        bf16x8 vf[4];
#pragma unroll
        for (int df = 0; df < 4; df++) {
          int row = df * 16 + c;
          vf[df] = *(const bf16x8*)((const char*)vsb + row * 128 + ((kk * 64 + g * 16) ^ ((row & 7) << 4)));
        }
#pragma unroll
        for (int df = 0; df < 4; df++)
          acc[df] = __builtin_amdgcn_mfma_f32_16x16x32_bf16(pa, vf[df], acc[df], 0, 0, 0);
      }
    }
    __builtin_amdgcn_sched_barrier(0);
    __builtin_amdgcn_s_barrier();
    cur ^= 1;
  }
#undef STAGE

  lsum += __shfl_xor(lsum, 16);
  lsum += __shfl_xor(lsum, 32);
#pragma unroll
  for (int r = 0; r < 4; r++) {
    float lr = __shfl(lsum, g * 4 + r, 64);
    float rls = 1.0f / lr;
    int qrow = qw0 + g * 4 + r;
    u16* op = ctx + (size_t)(b * LSEQ + qrow) * DMODEL + h * 64 + c;
#pragma unroll
    for (int df = 0; df < 4; df++)
      op[df * 16] = f2bf(acc[df][r] * rls);
  }
}

// ---------------- launch --------------------------------------------------------
extern "C" void kernel_launch(void* const* d_in, const int* in_sizes, int n_in,
                              void* d_out, int out_size, void* d_ws, size_t ws_size,
                              hipStream_t stream) {
  const float* x    = (const float*)d_in[0];
  const int*   seq  = (const int*)d_in[1];
  const float* ln1w = (const float*)d_in[2];
  const float* ln1b = (const float*)d_in[3];
  const float* wqkv = (const float*)d_in[4];
  const float* qlnw = (const float*)d_in[5];
  const float* klnw = (const float*)d_in[6];
  const float* wout = (const float*)d_in[7];
  float* out = (float*)d_out;

  char* p = (char*)d_ws;
  u16* wqkvT = (u16*)p;  p += (size_t)3072 * 1024 * 2;
  u16* woutT = (u16*)p;  p += (size_t)1024 * 1024 * 2;
  u16* hbuf  = (u16*)p;  p += (size_t)ROWS * DMODEL * 2;
  u16* Qb    = (u16*)p;  p += (size_t)ROWS * DMODEL * 2;
  u16* Kbuf  = (u16*)p;  p += (size_t)ROWS * DMODEL * 2;
  u16* Vbuf  = (u16*)p;  p += (size_t)ROWS * DMODEL * 2;
  u16* VTbuf = (u16*)p;  p += (size_t)ROWS * DMODEL * 2;
  u16* ctxb  = (u16*)p;  p += (size_t)ROWS * DMODEL * 2;
  float* cosb = (float*)p; p += (size_t)LSEQ * 32 * 4;
  float* sinb = (float*)p; p += (size_t)LSEQ * 32 * 4;
  int* bnd   = (int*)p;  p += 256;
  u16* qkv   = (u16*)p;  p += (size_t)ROWS * 3072 * 2;

  k_prep<<<8448, 256, 0, stream>>>(x, ln1w, ln1b, hbuf, wqkv, wqkvT, wout, woutT, seq, bnd, cosb, sinb);
  k_gemm256<1><<<(ROWS / 128) * (3072 / 192), 512, 0, stream>>>(hbuf, wqkvT, (void*)qkv, ROWS, 3072, 1024);
  k_qk_ln_rope<<<ROWS, 256, 0, stream>>>(qkv, qlnw, klnw, cosb, sinb, Qb, Kbuf, Vbuf);
  k_transpose_u16<<<dim3(DHEAD / 32, LSEQ / 32, BATCH * NHEAD), dim3(32, 8), 0, stream>>>(Vbuf, VTbuf);
  k_attn<<<BATCH * NHEAD * (LSEQ / 128), 512, 0, stream>>>(Qb, Kbuf, VTbuf, seq, bnd, ctxb);
  k_gemm_bt<0><<<(ROWS / 128) * (1024 / 128), 256, 0, stream>>>(ctxb, woutT, (void*)out, ROWS, 1024, 1024);
}

// Round 13
// 107.522 us; speedup vs baseline: 1.3019x; 1.0443x over previous
//
#include <hip/hip_runtime.h>
#include <hip/hip_bf16.h>
#include <cstdint>
#include <math.h>

#define LSEQ 2048
#define BATCH 2
#define NHEAD 16
#define DHEAD 64
#define DMODEL 1024
#define ROWS (BATCH*LSEQ)

typedef __bf16 bf16x8 __attribute__((ext_vector_type(8)));
typedef float f32x4 __attribute__((ext_vector_type(4)));
typedef unsigned short u16;

#define GLD(lds_base, src_g) \
  __builtin_amdgcn_global_load_lds((const __attribute__((address_space(1))) void*)(src_g), \
                                   (__attribute__((address_space(3))) void*)(lds_base), 16, 0, 0)
#define VM(n) asm volatile("s_waitcnt vmcnt(" #n ")" ::: "memory")

__device__ __forceinline__ u16 f2bf(float f) {
  unsigned int u = __float_as_uint(f);
  u += 0x7fffu + ((u >> 16) & 1u);
  return (u16)(u >> 16);
}
__device__ __forceinline__ float bf2f(u16 u) {
  return __uint_as_float(((unsigned)u) << 16);
}

// ---- fused prep: ln1 (4096) | wqkv^T (3072) | wout^T (1024) | rope+bnd (256) --
__global__ __launch_bounds__(256) void k_prep(const float* __restrict__ x, const float* __restrict__ ln1w,
                                              const float* __restrict__ ln1b, u16* __restrict__ hbuf,
                                              const float* __restrict__ wqkv, u16* __restrict__ wqkvT,
                                              const float* __restrict__ wout, u16* __restrict__ woutT,
                                              const int* __restrict__ seq, int* __restrict__ bnd,
                                              float* __restrict__ cosb, float* __restrict__ sinb) {
  __shared__ float tile[32][33];
  __shared__ float rb[2][4];
  const int bid = blockIdx.x, t = threadIdx.x;
  if (bid < 4096) {
    const int row = bid;
    const float4 xv = ((const float4*)(x + (size_t)row * DMODEL))[t];
    float s = xv.x + xv.y + xv.z + xv.w;
    float s2 = xv.x * xv.x + xv.y * xv.y + xv.z * xv.z + xv.w * xv.w;
#pragma unroll
    for (int m2 = 1; m2 < 64; m2 <<= 1) { s += __shfl_xor(s, m2); s2 += __shfl_xor(s2, m2); }
    int wv = t >> 6;
    if ((t & 63) == 0) { rb[0][wv] = s; rb[1][wv] = s2; }
    __syncthreads();
    s  = rb[0][0] + rb[0][1] + rb[0][2] + rb[0][3];
    s2 = rb[1][0] + rb[1][1] + rb[1][2] + rb[1][3];
    float mu = s * (1.0f / DMODEL);
    float rs = rsqrtf(s2 * (1.0f / DMODEL) - mu * mu + 1e-5f);
    const float4 wv4 = ((const float4*)ln1w)[t];
    const float4 bv4 = ((const float4*)ln1b)[t];
    ushort4 o;
    o.x = f2bf((xv.x - mu) * rs * wv4.x + bv4.x);
    o.y = f2bf((xv.y - mu) * rs * wv4.y + bv4.y);
    o.z = f2bf((xv.z - mu) * rs * wv4.z + bv4.z);
    o.w = f2bf((xv.w - mu) * rs * wv4.w + bv4.w);
    ((ushort4*)(hbuf + (size_t)row * DMODEL))[t] = o;
  } else if (bid < 4096 + 3072 + 1024) {
    const float* in; u16* out; int R, C, bx, by;
    if (bid < 4096 + 3072) { int rel = bid - 4096; in = wqkv; out = wqkvT; R = 1024; C = 3072; bx = rel % 96; by = rel / 96; }
    else                   { int rel = bid - 7168; in = wout; out = woutT; R = 1024; C = 1024; bx = rel % 32; by = rel / 32; }
    int c0 = bx * 32, r0 = by * 32;
    int tx = t & 31, ty = t >> 5;
#pragma unroll
    for (int i = 0; i < 32; i += 8)
      tile[ty + i][tx] = in[(size_t)(r0 + ty + i) * C + (c0 + tx)];
    __syncthreads();
#pragma unroll
    for (int i = 0; i < 32; i += 8)
      out[(size_t)(c0 + ty + i) * R + (r0 + tx)] = f2bf(tile[tx][ty + i]);
  } else {
    const int rel = bid - 8192;
    if (rel == 0 && t < BATCH * 5) {
      int b = t / 5, s = t % 5;
      const int* row = seq + b * LSEQ;
      int lo = 0, hi = LSEQ;
      while (lo < hi) { int mid = (lo + hi) >> 1; if (row[mid] < s) lo = mid + 1; else hi = mid; }
      bnd[b * 5 + s] = lo;
    }
    int idx = rel * 256 + t;
    if (idx < LSEQ * 32) {
      int l = idx >> 5, f = idx & 31;
      double inv = pow(10000.0, -(double)f / 32.0);
      float ang = (float)l * (float)inv;
      cosb[idx] = cosf(ang);
      sinb[idx] = sinf(ang);
    }
  }
}

// ============ 128x192 4-phase GEMM, C = A @ B^T (80 KB LDS -> 2 blocks/CU) =====
template<int OUTMODE>
__global__ __launch_bounds__(512, 4) void k_gemm256(const u16* __restrict__ A, const u16* __restrict__ B,
                                                    void* __restrict__ Cv, int M, int N, int K) {
  __shared__ __align__(16) u16 As[2][128 * 64];   // 16 KB per buffer
  __shared__ __align__(16) u16 Bs[2][192 * 64];   // 24 KB per buffer
  const int t = threadIdx.x, lane = t & 63, w = t >> 6;
  const int wr = w >> 2, wc = w & 3;
  const int nbx = N / 192;
  const int nwg = nbx * (M >> 7);
  const int cpx = nwg >> 3;
  const int bid = blockIdx.x;
  const int sw = (bid & 7) * cpx + (bid >> 3);
  const int m0 = (sw / nbx) * 128, n0 = (sw % nbx) * 192;
  const int NT = K >> 6;
  const int cg16 = (lane >> 4) * 16;

  f32x4 acc[4][3] = {};
  bf16x8 af_[2][2], bf_[3][2];
  const u16* Ap = A + (size_t)m0 * K;
  const u16* Bp = B + (size_t)n0 * K;
  const int rr0 = t >> 3;
  const int sz = ((t & 7) * 8) ^ ((rr0 & 7) << 3);
  const u16* pA[2] = { Ap + (size_t)rr0 * K + sz,
                       Ap + (size_t)(rr0 + 64) * K + sz };
  const u16* pB[3] = { Bp + (size_t)rr0 * K + sz,
                       Bp + (size_t)(rr0 + 64) * K + sz,
                       Bp + (size_t)(rr0 + 128) * K + sz };

#define SA1(b, h, EO) GLD((char*)As + (b)*16384 + (h)*8192 + w*1024, pA[h] + (EO))
#define SB3(b, EO) do { \
    GLD((char*)Bs + (b)*24576 +         w*1024, pB[0] + (EO)); \
    GLD((char*)Bs + (b)*24576 +  8192 + w*1024, pB[1] + (EO)); \
    GLD((char*)Bs + (b)*24576 + 16384 + w*1024, pB[2] + (EO)); \
  } while (0)

#define READ_AF(asb, mh) do { \
    _Pragma("unroll") for (int i2 = 0; i2 < 2; i2++) { \
      const int rowA = (((mh)*2 + i2)*2 + wr)*16 + (lane & 15); \
      const int sA = (rowA & 7) << 4; \
      _Pragma("unroll") for (int kk = 0; kk < 2; kk++) \
        af_[i2][kk] = *(const bf16x8*)((const char*)(asb) + (rowA & 63)*128 + ((kk*64 + cg16) ^ sA)); \
    } } while (0)
#define READ_BF(bsb) do { \
    _Pragma("unroll") for (int j2 = 0; j2 < 3; j2++) { \
      const int rowB = (j2*4 + wc)*16 + (lane & 15); \
      const int sB = (rowB & 7) << 4; \
      _Pragma("unroll") for (int kk = 0; kk < 2; kk++) \
        bf_[j2][kk] = *(const bf16x8*)((const char*)(bsb) + rowB*128 + ((kk*64 + cg16) ^ sB)); \
    } } while (0)
#define MFMA12(mh) do { \
    _Pragma("unroll") for (int kk = 0; kk < 2; kk++) \
      _Pragma("unroll") for (int i2 = 0; i2 < 2; i2++) \
        _Pragma("unroll") for (int j2 = 0; j2 < 3; j2++) \
          acc[(mh)*2+i2][j2] = __builtin_amdgcn_mfma_f32_16x16x32_bf16( \
              af_[i2][kk], bf_[j2][kk], acc[(mh)*2+i2][j2], 0, 0, 0); \
  } while (0)

  SA1(0, 0, 0); SA1(0, 1, 0); SB3(0, 0);
  SA1(1, 0, 64);
  VM(1);
  __builtin_amdgcn_s_barrier();

  const char* a0  = (const char*)As;
  const char* a0h = a0 + 8192;
  const char* a1  = a0 + 16384;
  const char* a1h = a0 + 24576;
  const char* b0  = (const char*)Bs;
  const char* b1  = b0 + 24576;
  const int NIT = NT >> 1;
  for (int i = 0; i < NIT; i++) {
    const bool lst = (i == NIT - 1);
    READ_AF(a0, 0); READ_BF(b0);
    SA1(1, 1, 64); SB3(1, 64);
    __builtin_amdgcn_s_barrier();
    asm volatile("s_waitcnt lgkmcnt(0)" ::: "memory");
    __builtin_amdgcn_s_setprio(1); MFMA12(0); __builtin_amdgcn_s_setprio(0);
    __builtin_amdgcn_s_barrier();
    READ_AF(a0h, 1);
    if (!lst) SA1(0, 0, 128);
    __builtin_amdgcn_s_barrier();
    asm volatile("s_waitcnt lgkmcnt(0)" ::: "memory");
    __builtin_amdgcn_s_setprio(1); MFMA12(1); __builtin_amdgcn_s_setprio(0);
    if (lst) VM(0); else VM(1);
    __builtin_amdgcn_s_barrier();
    READ_AF(a1, 0); READ_BF(b1);
    if (!lst) { SA1(0, 1, 128); SB3(0, 128); }
    __builtin_amdgcn_s_barrier();
    asm volatile("s_waitcnt lgkmcnt(0)" ::: "memory");
    __builtin_amdgcn_s_setprio(1); MFMA12(0); __builtin_amdgcn_s_setprio(0);
    __builtin_amdgcn_s_barrier();
    READ_AF(a1h, 1);
    if (!lst) SA1(1, 0, 192);
    __builtin_amdgcn_s_barrier();
    asm volatile("s_waitcnt lgkmcnt(0)" ::: "memory");
    __builtin_amdgcn_s_setprio(1); MFMA12(1); __builtin_amdgcn_s_setprio(0);
    if (!lst) VM(1);
    __builtin_amdgcn_s_barrier();
    pA[0] += 128; pA[1] += 128;
    pB[0] += 128; pB[1] += 128; pB[2] += 128;
  }
#undef MFMA12
#undef READ_BF
#undef READ_AF
#undef SA1
#undef SB3

  const int cr = (lane >> 4) * 4, cc = lane & 15;
#pragma unroll
  for (int fi = 0; fi < 4; fi++)
#pragma unroll
    for (int fj = 0; fj < 3; fj++) {
      const size_t roff = (size_t)(m0 + (fi * 2 + wr) * 16 + cr) * N + (n0 + (fj * 4 + wc) * 16 + cc);
      if (OUTMODE == 0) {
        float* Cp = (float*)Cv + roff;
#pragma unroll
        for (int r = 0; r < 4; r++) Cp[(size_t)r * N] = acc[fi][fj][r];
      } else {
        u16* Cp = (u16*)Cv + roff;
#pragma unroll
        for (int r = 0; r < 4; r++) Cp[(size_t)r * N] = f2bf(acc[fi][fj][r]);
      }
    }
}

// ------- bf16 GEMM 128^2, chunked XCD swizzle, TOP-counted vmcnt (GEMM2) -------
template<int OUTMODE>
__global__ __launch_bounds__(256) void k_gemm_bt(const u16* __restrict__ A, const u16* __restrict__ B,
                                                 void* __restrict__ Cv, int M, int N, int K) {
  __shared__ __align__(16) u16 As[2][128 * 64];
  __shared__ __align__(16) u16 Bs[2][128 * 64];
  const int t = threadIdx.x;
  const int lane = t & 63, w = t >> 6;
  const int nbx = N >> 7;
  const int nwg = nbx * (M >> 7);
  const int cpx = nwg >> 3;
  const int bid = blockIdx.x;
  const int sw = (bid & 7) * cpx + (bid >> 3);
  const int m0 = (sw / nbx) * 128, n0 = (sw % nbx) * 128;
  const int wm = (w >> 1) * 64, wn = (w & 1) * 64;
  const int NT = K >> 6;
  f32x4 acc[4][4] = {};
  const u16* Ap = A + (size_t)m0 * K;
  const u16* Bp = B + (size_t)n0 * K;
  const int cr0 = lane >> 3, cs = lane & 7;

#define GSTAGE(bb, kt_) do { \
    _Pragma("unroll") \
    for (int s2 = 0; s2 < 4; s2++) { \
      int ch = w * 4 + s2; \
      int row = ch * 8 + cr0; \
      int cb = cs ^ (row & 7); \
      GLD((char*)As[bb] + ch * 1024, Ap + (size_t)row * K + (kt_) * 64 + cb * 8); \
      GLD((char*)Bs[bb] + ch * 1024, Bp + (size_t)row * K + (kt_) * 64 + cb * 8); \
    } } while (0)

  GSTAGE(0, 0);                       // 8 loads in flight for buf0
  int cur = 0;
  for (int kt = 0; kt < NT; kt++) {
    if (kt + 1 < NT) { GSTAGE(cur ^ 1, kt + 1); VM(8); }   // drain cur's 8, keep next's 8 in flight
    else             { VM(0); }
    __builtin_amdgcn_s_barrier();
    const u16* asb = As[cur];
    const u16* bsb = Bs[cur];
#pragma unroll
    for (int kk = 0; kk < 2; kk++) {
      bf16x8 af[4], bfr[4];
#pragma unroll
      for (int i = 0; i < 4; i++) {
        int rowa = wm + i * 16 + (lane & 15);
        af[i] = *(const bf16x8*)((const char*)asb + rowa * 128 + ((kk * 64 + (lane >> 4) * 16) ^ ((rowa & 7) << 4)));
        int rowb = wn + i * 16 + (lane & 15);
        bfr[i] = *(const bf16x8*)((const char*)bsb + rowb * 128 + ((kk * 64 + (lane >> 4) * 16) ^ ((rowb & 7) << 4)));
      }
#pragma unroll
      for (int mf = 0; mf < 4; mf++)
#pragma unroll
        for (int nf = 0; nf < 4; nf++)
          acc[mf][nf] = __builtin_amdgcn_mfma_f32_16x16x32_bf16(af[mf], bfr[nf], acc[mf][nf], 0, 0, 0);
    }
    __builtin_amdgcn_s_barrier();     // WAR: next iter's stage of this buffer waits here
    cur ^= 1;
  }
#undef GSTAGE
  const int cr = (lane >> 4) * 4, cc = lane & 15;
#pragma unroll
  for (int mf = 0; mf < 4; mf++)
#pragma unroll
    for (int nf = 0; nf < 4; nf++) {
      if (OUTMODE == 0) {
        float* Cp = (float*)Cv + (size_t)(m0 + wm + mf * 16 + cr) * N + (n0 + wn + nf * 16 + cc);
#pragma unroll
        for (int r = 0; r < 4; r++) Cp[(size_t)r * N] = acc[mf][nf][r];
      } else {
        u16* Cp = (u16*)Cv + (size_t)(m0 + wm + mf * 16 + cr) * N + (n0 + wn + nf * 16 + cc);
#pragma unroll
        for (int r = 0; r < 4; r++) Cp[(size_t)r * N] = f2bf(acc[mf][nf][r]);
      }
    }
}

// ---- fused: q/k LN+RoPE+split (4096 blocks) | V^T from qkv (4096 blocks) ------
__global__ __launch_bounds__(256) void k_qkv_post(const u16* __restrict__ qkv,
                                                  const float* __restrict__ qw, const float* __restrict__ kw,
                                                  const float* __restrict__ cosb, const float* __restrict__ sinb,
                                                  u16* __restrict__ Q, u16* __restrict__ K, u16* __restrict__ VT) {
  const int bid = blockIdx.x, t = threadIdx.x;
  if (bid < 4096) {
    __shared__ float qs[1024], ks[1024];
    __shared__ float rb[4][4];
    int row = bid;
    int b = row >> 11, l = row & 2047;
    const u16* base = qkv + (size_t)row * 3072;
    ushort4 qu = ((const ushort4*)base)[t];
    ushort4 ku = ((const ushort4*)(base + 1024))[t];
    float qx = bf2f(qu.x), qy = bf2f(qu.y), qz = bf2f(qu.z), qw_ = bf2f(qu.w);
    float kx = bf2f(ku.x), ky = bf2f(ku.y), kz = bf2f(ku.z), kw_ = bf2f(ku.w);
    float red[4];
    red[0] = qx + qy + qz + qw_;
    red[1] = qx * qx + qy * qy + qz * qz + qw_ * qw_;
    red[2] = kx + ky + kz + kw_;
    red[3] = kx * kx + ky * ky + kz * kz + kw_ * kw_;
#pragma unroll
    for (int i = 0; i < 4; i++)
#pragma unroll
      for (int m2 = 1; m2 < 64; m2 <<= 1) red[i] += __shfl_xor(red[i], m2);
    int w = t >> 6;
    if ((t & 63) == 0) { rb[w][0] = red[0]; rb[w][1] = red[1]; rb[w][2] = red[2]; rb[w][3] = red[3]; }
    __syncthreads();
    float S1 = rb[0][0] + rb[1][0] + rb[2][0] + rb[3][0];
    float S2 = rb[0][1] + rb[1][1] + rb[2][1] + rb[3][1];
    float S3 = rb[0][2] + rb[1][2] + rb[2][2] + rb[3][2];
    float S4 = rb[0][3] + rb[1][3] + rb[2][3] + rb[3][3];
    float muq = S1 * (1.0f / DMODEL), rsq = rsqrtf(S2 * (1.0f / DMODEL) - muq * muq + 1e-5f);
    float muk = S3 * (1.0f / DMODEL), rsk = rsqrtf(S4 * (1.0f / DMODEL) - muk * muk + 1e-5f);
    float4 qwv = ((const float4*)qw)[t];
    float4 kwv = ((const float4*)kw)[t];
    qs[t * 4 + 0] = (qx - muq) * rsq * qwv.x;  ks[t * 4 + 0] = (kx - muk) * rsk * kwv.x;
    qs[t * 4 + 1] = (qy - muq) * rsq * qwv.y;  ks[t * 4 + 1] = (ky - muk) * rsk * kwv.y;
    qs[t * 4 + 2] = (qz - muq) * rsq * qwv.z;  ks[t * 4 + 2] = (kz - muk) * rsk * kwv.z;
    qs[t * 4 + 3] = (qw_ - muq) * rsq * qwv.w; ks[t * 4 + 3] = (kw_ - muk) * rsk * kwv.w;
    __syncthreads();
    int d0 = t * 4;
    int hh = d0 >> 6;
    union { ushort4 v4; u16 e[4]; } qo, ko;
#pragma unroll
    for (int i = 0; i < 4; i++) {
      int d = d0 + i, dd = d & 63, fr = dd & 31;
      float c = cosb[l * 32 + fr], s = sinb[l * 32 + fr];
      float q1 = qs[d], q2 = (dd < 32) ? -qs[d + 32] : qs[d - 32];
      float k1 = ks[d], k2 = (dd < 32) ? -ks[d + 32] : ks[d - 32];
      qo.e[i] = f2bf(q1 * c + q2 * s);
      ko.e[i] = f2bf(k1 * c + k2 * s);
    }
    size_t oidx = ((size_t)(b * NHEAD + hh) * LSEQ + l) * DHEAD + (d0 & 63);
    *(ushort4*)(Q + oidx) = qo.v4;
    *(ushort4*)(K + oidx) = ko.v4;
  } else {
    // ---- V^T tile: read V straight from qkv (cols 2048..3071), write [d][l] ----
    __shared__ u16 vtile[32][33];
    const int rel = bid - 4096;
    const int hd = rel >> 7;            // 0..31 (b*16+h)
    const int tl = rel & 127;
    const int d0 = (tl & 1) * 32, l0 = (tl >> 1) * 32;
    const int gl = (hd >> 4) * LSEQ;    // batch row offset in qkv
    const u16* ip = qkv + (size_t)(gl + l0) * 3072 + 2048 + (hd & 15) * 64 + d0;
    u16* op = VT + (size_t)hd * LSEQ * DHEAD + (size_t)d0 * LSEQ + l0;
    int tx = t & 31, ty = t >> 5;
#pragma unroll
    for (int i = 0; i < 32; i += 8)
      vtile[ty + i][tx] = ip[(size_t)(ty + i) * 3072 + tx];
    __syncthreads();
#pragma unroll
    for (int i = 0; i < 32; i += 8)
      op[(size_t)(ty + i) * LSEQ + tx] = vtile[tx][ty + i];
  }
}

// -- segment-masked flash attention: QBLK=128, 8 waves, XCD-chunked, 2-deep pipe -
__global__ __launch_bounds__(512) void k_attn(const u16* __restrict__ Q, const u16* __restrict__ Kb,
                                              const u16* __restrict__ VTb, const int* __restrict__ seq,
                                              const int* __restrict__ bnd, u16* __restrict__ ctx) {
  __shared__ __align__(16) u16 Ks[2][64 * 64];
  __shared__ __align__(16) u16 Vs[2][64 * 64];
  __shared__ __align__(16) u16 Pw[8][16 * 64];

  const int bid = blockIdx.x;
  const int sw = (bid & 7) * 64 + (bid >> 3);
  const int qt = sw & 15, h = (sw >> 4) & 15, b = sw >> 8;
  const int t = threadIdx.x, l = t & 63, w = t >> 6;
  const int c = l & 15, g = l >> 4;
  const int q0 = qt * 128;
  const size_t hoff = (size_t)(b * NHEAD + h) * LSEQ * DHEAD;
  const u16* Qg = Q + hoff;
  const u16* Kg = Kb + hoff;
  const u16* Vg = VTb + hoff;   // [d][l]
  const int* seqb = seq + b * LSEQ;
  const int* bnd5 = bnd + b * 5;

  const int qw0 = q0 + w * 16;
  const int myq = qw0 + c;
  const int sq = seqb[myq];
  const int lo = bnd5[sq], hi = bnd5[sq + 1];
  const int wlo = bnd5[seqb[qw0]];
  const int whi = bnd5[seqb[qw0 + 15] + 1];
  int kbeg = bnd5[seqb[q0]] & ~63;
  int kend = (bnd5[seqb[q0 + 127] + 1] + 63) & ~63;
  if (kend > LSEQ) kend = LSEQ;

  bf16x8 qf[2];
  qf[0] = *(const bf16x8*)(Qg + (size_t)myq * 64 + g * 8);
  qf[1] = *(const bf16x8*)(Qg + (size_t)myq * 64 + 32 + g * 8);

  f32x4 acc[4] = {};
  float lsum = 0.f;

  const int rr = t >> 3;
  const int szk = ((t & 7) * 8) ^ ((rr & 7) << 3);
  const u16* pK = Kg + (size_t)rr * 64 + szk;
  const u16* pV = Vg + (size_t)rr * LSEQ + szk;

#define STAGE(bb, kt_) do { \
    GLD((char*)Ks[bb] + w * 1024, pK + (size_t)(kt_) * 64); \
    GLD((char*)Vs[bb] + w * 1024, pV + (kt_)); \
  } while (0)

  STAGE(0, kbeg);
  int cur = 0;
  for (int kt = kbeg; kt < kend; kt += 64) {
    const bool more = (kt + 64) < kend;
    if (more) STAGE(cur ^ 1, kt + 64);
    if (more) VM(2);
    else      VM(0);
    __builtin_amdgcn_s_barrier();
    __builtin_amdgcn_sched_barrier(0);
    if (kt < whi && kt + 64 > wlo) {
      const u16* ksb = Ks[cur];
      const u16* vsb = Vs[cur];
      f32x4 st[4] = {};
#pragma unroll
      for (int kk = 0; kk < 2; kk++) {
        bf16x8 kf[4];
#pragma unroll
        for (int i = 0; i < 4; i++) {
          int row = i * 16 + c;
          kf[i] = *(const bf16x8*)((const char*)ksb + row * 128 + ((kk * 64 + g * 16) ^ ((row & 7) << 4)));
        }
#pragma unroll
        for (int i = 0; i < 4; i++)
          st[i] = __builtin_amdgcn_mfma_f32_16x16x32_bf16(kf[i], qf[kk], st[i], 0, 0, 0);
      }
      const int kb0 = kt + g * 4;
#pragma unroll
      for (int i = 0; i < 4; i++) {
        float p[4];
#pragma unroll
        for (int r = 0; r < 4; r++) {
          int kglob = kb0 + i * 16 + r;
          bool ok = ((unsigned)(kglob - lo)) < ((unsigned)(hi - lo));
          float x = ok ? fmaf(st[i][r], 0.125f, -8.0f) : -1e30f;
          p[r] = __expf(x);
          lsum += p[r];
        }
        unsigned w0, w1;
        asm("v_cvt_pk_bf16_f32 %0, %1, %2" : "=v"(w0) : "v"(p[0]), "v"(p[1]));
        asm("v_cvt_pk_bf16_f32 %0, %1, %2" : "=v"(w1) : "v"(p[2]), "v"(p[3]));
        uint2 wp; wp.x = w0; wp.y = w1;
        *(uint2*)((char*)Pw[w] + c * 128 + ((i * 32 + g * 8) ^ ((c & 7) << 4))) = wp;
      }
#pragma unroll
      for (int kk = 0; kk < 2; kk++) {
        bf16x8 pa = *(const bf16x8*)((char*)Pw[w] + c * 128 + ((kk * 64 + g * 16) ^ ((c & 7) << 4)));
        bf16x8 vf[4];
#pragma unroll
        for (int df = 0; df < 4; df++) {
          int row = df * 16 + c;
          vf[df] = *(const bf16x8*)((const char*)vsb + row * 128 + ((kk * 64 + g * 16) ^ ((row & 7) << 4)));
        }
#pragma unroll
        for (int df = 0; df < 4; df++)
          acc[df] = __builtin_amdgcn_mfma_f32_16x16x32_bf16(pa, vf[df], acc[df], 0, 0, 0);
      }
    }
    __builtin_amdgcn_sched_barrier(0);
    __builtin_amdgcn_s_barrier();
    cur ^= 1;
  }
#undef STAGE

  lsum += __shfl_xor(lsum, 16);
  lsum += __shfl_xor(lsum, 32);
#pragma unroll
  for (int r = 0; r < 4; r++) {
    float lr = __shfl(lsum, g * 4 + r, 64);
    float rls = 1.0f / lr;
    int qrow = qw0 + g * 4 + r;
    u16* op = ctx + (size_t)(b * LSEQ + qrow) * DMODEL + h * 64 + c;
#pragma unroll
    for (int df = 0; df < 4; df++)
      op[df * 16] = f2bf(acc[df][r] * rls);
  }
}

// ---------------- launch --------------------------------------------------------
extern "C" void kernel_launch(void* const* d_in, const int* in_sizes, int n_in,
                              void* d_out, int out_size, void* d_ws, size_t ws_size,
                              hipStream_t stream) {
  const float* x    = (const float*)d_in[0];
  const int*   seq  = (const int*)d_in[1];
  const float* ln1w = (const float*)d_in[2];
  const float* ln1b = (const float*)d_in[3];
  const float* wqkv = (const float*)d_in[4];
  const float* qlnw = (const float*)d_in[5];
  const float* klnw = (const float*)d_in[6];
  const float* wout = (const float*)d_in[7];
  float* out = (float*)d_out;

  char* p = (char*)d_ws;
  u16* wqkvT = (u16*)p;  p += (size_t)3072 * 1024 * 2;
  u16* woutT = (u16*)p;  p += (size_t)1024 * 1024 * 2;
  u16* hbuf  = (u16*)p;  p += (size_t)ROWS * DMODEL * 2;
  u16* Qb    = (u16*)p;  p += (size_t)ROWS * DMODEL * 2;
  u16* Kbuf  = (u16*)p;  p += (size_t)ROWS * DMODEL * 2;
  u16* VTbuf = (u16*)p;  p += (size_t)ROWS * DMODEL * 2;
  u16* ctxb  = (u16*)p;  p += (size_t)ROWS * DMODEL * 2;
  float* cosb = (float*)p; p += (size_t)LSEQ * 32 * 4;
  float* sinb = (float*)p; p += (size_t)LSEQ * 32 * 4;
  int* bnd   = (int*)p;  p += 256;
  u16* qkv   = (u16*)p;  p += (size_t)ROWS * 3072 * 2;

  k_prep<<<8448, 256, 0, stream>>>(x, ln1w, ln1b, hbuf, wqkv, wqkvT, wout, woutT, seq, bnd, cosb, sinb);
  k_gemm256<1><<<(ROWS / 128) * (3072 / 192), 512, 0, stream>>>(hbuf, wqkvT, (void*)qkv, ROWS, 3072, 1024);
  k_qkv_post<<<8192, 256, 0, stream>>>(qkv, qlnw, klnw, cosb, sinb, Qb, Kbuf, VTbuf);
  k_attn<<<BATCH * NHEAD * (LSEQ / 128), 512, 0, stream>>>(Qb, Kbuf, VTbuf, seq, bnd, ctxb);
  k_gemm_bt<0><<<(ROWS / 128) * (1024 / 128), 256, 0, stream>>>(ctxb, woutT, (void*)out, ROWS, 1024, 1024);
}

// Round 14
// 106.401 us; speedup vs baseline: 1.3157x; 1.0105x over previous
//
#include <hip/hip_runtime.h>
#include <hip/hip_bf16.h>
#include <cstdint>
#include <math.h>

#define LSEQ 2048
#define BATCH 2
#define NHEAD 16
#define DHEAD 64
#define DMODEL 1024
#define ROWS (BATCH*LSEQ)

typedef __bf16 bf16x8 __attribute__((ext_vector_type(8)));
typedef float f32x4 __attribute__((ext_vector_type(4)));
typedef unsigned short u16;

#define GLD(lds_base, src_g) \
  __builtin_amdgcn_global_load_lds((const __attribute__((address_space(1))) void*)(src_g), \
                                   (__attribute__((address_space(3))) void*)(lds_base), 16, 0, 0)
#define VM(n) asm volatile("s_waitcnt vmcnt(" #n ")" ::: "memory")

__device__ __forceinline__ u16 f2bf(float f) {
  unsigned int u = __float_as_uint(f);
  u += 0x7fffu + ((u >> 16) & 1u);
  return (u16)(u >> 16);
}
__device__ __forceinline__ float bf2f(u16 u) {
  return __uint_as_float(((unsigned)u) << 16);
}

// ---- fused prep: ln1 (4096) | wqkv^T (3072) | wout^T (1024) | rope+bnd (256) --
__global__ __launch_bounds__(256) void k_prep(const float* __restrict__ x, const float* __restrict__ ln1w,
                                              const float* __restrict__ ln1b, u16* __restrict__ hbuf,
                                              const float* __restrict__ wqkv, u16* __restrict__ wqkvT,
                                              const float* __restrict__ wout, u16* __restrict__ woutT,
                                              const int* __restrict__ seq, int* __restrict__ bnd,
                                              float* __restrict__ cosb, float* __restrict__ sinb) {
  __shared__ float tile[32][33];
  __shared__ float rb[2][4];
  const int bid = blockIdx.x, t = threadIdx.x;
  if (bid < 4096) {
    const int row = bid;
    const float4 xv = ((const float4*)(x + (size_t)row * DMODEL))[t];
    float s = xv.x + xv.y + xv.z + xv.w;
    float s2 = xv.x * xv.x + xv.y * xv.y + xv.z * xv.z + xv.w * xv.w;
#pragma unroll
    for (int m2 = 1; m2 < 64; m2 <<= 1) { s += __shfl_xor(s, m2); s2 += __shfl_xor(s2, m2); }
    int wv = t >> 6;
    if ((t & 63) == 0) { rb[0][wv] = s; rb[1][wv] = s2; }
    __syncthreads();
    s  = rb[0][0] + rb[0][1] + rb[0][2] + rb[0][3];
    s2 = rb[1][0] + rb[1][1] + rb[1][2] + rb[1][3];
    float mu = s * (1.0f / DMODEL);
    float rs = rsqrtf(s2 * (1.0f / DMODEL) - mu * mu + 1e-5f);
    const float4 wv4 = ((const float4*)ln1w)[t];
    const float4 bv4 = ((const float4*)ln1b)[t];
    ushort4 o;
    o.x = f2bf((xv.x - mu) * rs * wv4.x + bv4.x);
    o.y = f2bf((xv.y - mu) * rs * wv4.y + bv4.y);
    o.z = f2bf((xv.z - mu) * rs * wv4.z + bv4.z);
    o.w = f2bf((xv.w - mu) * rs * wv4.w + bv4.w);
    ((ushort4*)(hbuf + (size_t)row * DMODEL))[t] = o;
  } else if (bid < 4096 + 3072 + 1024) {
    const float* in; u16* out; int R, C, bx, by;
    if (bid < 4096 + 3072) { int rel = bid - 4096; in = wqkv; out = wqkvT; R = 1024; C = 3072; bx = rel % 96; by = rel / 96; }
    else                   { int rel = bid - 7168; in = wout; out = woutT; R = 1024; C = 1024; bx = rel % 32; by = rel / 32; }
    int c0 = bx * 32, r0 = by * 32;
    int tx = t & 31, ty = t >> 5;
#pragma unroll
    for (int i = 0; i < 32; i += 8)
      tile[ty + i][tx] = in[(size_t)(r0 + ty + i) * C + (c0 + tx)];
    __syncthreads();
#pragma unroll
    for (int i = 0; i < 32; i += 8)
      out[(size_t)(c0 + ty + i) * R + (r0 + tx)] = f2bf(tile[tx][ty + i]);
  } else {
    const int rel = bid - 8192;
    if (rel == 0 && t < BATCH * 5) {
      int b = t / 5, s = t % 5;
      const int* row = seq + b * LSEQ;
      int lo = 0, hi = LSEQ;
      while (lo < hi) { int mid = (lo + hi) >> 1; if (row[mid] < s) lo = mid + 1; else hi = mid; }
      bnd[b * 5 + s] = lo;
    }
    int idx = rel * 256 + t;
    if (idx < LSEQ * 32) {
      int l = idx >> 5, f = idx & 31;
      double inv = pow(10000.0, -(double)f / 32.0);
      float ang = (float)l * (float)inv;
      cosb[idx] = cosf(ang);
      sinb[idx] = sinf(ang);
    }
  }
}

// ============ 128x192 4-phase GEMM, C = A @ B^T (80 KB LDS -> 2 blocks/CU) =====
template<int OUTMODE>
__global__ __launch_bounds__(512, 4) void k_gemm256(const u16* __restrict__ A, const u16* __restrict__ B,
                                                    void* __restrict__ Cv, int M, int N, int K) {
  __shared__ __align__(16) u16 As[2][128 * 64];   // 16 KB per buffer
  __shared__ __align__(16) u16 Bs[2][192 * 64];   // 24 KB per buffer
  const int t = threadIdx.x, lane = t & 63, w = t >> 6;
  const int wr = w >> 2, wc = w & 3;
  const int nbx = N / 192;
  const int nwg = nbx * (M >> 7);
  const int cpx = nwg >> 3;
  const int bid = blockIdx.x;
  const int sw = (bid & 7) * cpx + (bid >> 3);
  const int m0 = (sw / nbx) * 128, n0 = (sw % nbx) * 192;
  const int NT = K >> 6;
  const int cg16 = (lane >> 4) * 16;

  f32x4 acc[4][3] = {};
  bf16x8 af_[2][2], bf_[3][2];
  const u16* Ap = A + (size_t)m0 * K;
  const u16* Bp = B + (size_t)n0 * K;
  const int rr0 = t >> 3;
  const int sz = ((t & 7) * 8) ^ ((rr0 & 7) << 3);
  const u16* pA[2] = { Ap + (size_t)rr0 * K + sz,
                       Ap + (size_t)(rr0 + 64) * K + sz };
  const u16* pB[3] = { Bp + (size_t)rr0 * K + sz,
                       Bp + (size_t)(rr0 + 64) * K + sz,
                       Bp + (size_t)(rr0 + 128) * K + sz };

#define SA1(b, h, EO) GLD((char*)As + (b)*16384 + (h)*8192 + w*1024, pA[h] + (EO))
#define SB3(b, EO) do { \
    GLD((char*)Bs + (b)*24576 +         w*1024, pB[0] + (EO)); \
    GLD((char*)Bs + (b)*24576 +  8192 + w*1024, pB[1] + (EO)); \
    GLD((char*)Bs + (b)*24576 + 16384 + w*1024, pB[2] + (EO)); \
  } while (0)

#define READ_AF(asb, mh) do { \
    _Pragma("unroll") for (int i2 = 0; i2 < 2; i2++) { \
      const int rowA = (((mh)*2 + i2)*2 + wr)*16 + (lane & 15); \
      const int sA = (rowA & 7) << 4; \
      _Pragma("unroll") for (int kk = 0; kk < 2; kk++) \
        af_[i2][kk] = *(const bf16x8*)((const char*)(asb) + (rowA & 63)*128 + ((kk*64 + cg16) ^ sA)); \
    } } while (0)
#define READ_BF(bsb) do { \
    _Pragma("unroll") for (int j2 = 0; j2 < 3; j2++) { \
      const int rowB = (j2*4 + wc)*16 + (lane & 15); \
      const int sB = (rowB & 7) << 4; \
      _Pragma("unroll") for (int kk = 0; kk < 2; kk++) \
        bf_[j2][kk] = *(const bf16x8*)((const char*)(bsb) + rowB*128 + ((kk*64 + cg16) ^ sB)); \
    } } while (0)
#define MFMA12(mh) do { \
    _Pragma("unroll") for (int kk = 0; kk < 2; kk++) \
      _Pragma("unroll") for (int i2 = 0; i2 < 2; i2++) \
        _Pragma("unroll") for (int j2 = 0; j2 < 3; j2++) \
          acc[(mh)*2+i2][j2] = __builtin_amdgcn_mfma_f32_16x16x32_bf16( \
              af_[i2][kk], bf_[j2][kk], acc[(mh)*2+i2][j2], 0, 0, 0); \
  } while (0)

  SA1(0, 0, 0); SA1(0, 1, 0); SB3(0, 0);
  SA1(1, 0, 64);
  VM(1);
  __builtin_amdgcn_s_barrier();

  const char* a0  = (const char*)As;
  const char* a0h = a0 + 8192;
  const char* a1  = a0 + 16384;
  const char* a1h = a0 + 24576;
  const char* b0  = (const char*)Bs;
  const char* b1  = b0 + 24576;
  const int NIT = NT >> 1;
  for (int i = 0; i < NIT; i++) {
    const bool lst = (i == NIT - 1);
    READ_AF(a0, 0); READ_BF(b0);
    SA1(1, 1, 64); SB3(1, 64);
    __builtin_amdgcn_s_barrier();
    asm volatile("s_waitcnt lgkmcnt(0)" ::: "memory");
    __builtin_amdgcn_s_setprio(1); MFMA12(0); __builtin_amdgcn_s_setprio(0);
    __builtin_amdgcn_s_barrier();
    READ_AF(a0h, 1);
    if (!lst) SA1(0, 0, 128);
    __builtin_amdgcn_s_barrier();
    asm volatile("s_waitcnt lgkmcnt(0)" ::: "memory");
    __builtin_amdgcn_s_setprio(1); MFMA12(1); __builtin_amdgcn_s_setprio(0);
    if (lst) VM(0); else VM(1);
    __builtin_amdgcn_s_barrier();
    READ_AF(a1, 0); READ_BF(b1);
    if (!lst) { SA1(0, 1, 128); SB3(0, 128); }
    __builtin_amdgcn_s_barrier();
    asm volatile("s_waitcnt lgkmcnt(0)" ::: "memory");
    __builtin_amdgcn_s_setprio(1); MFMA12(0); __builtin_amdgcn_s_setprio(0);
    __builtin_amdgcn_s_barrier();
    READ_AF(a1h, 1);
    if (!lst) SA1(1, 0, 192);
    __builtin_amdgcn_s_barrier();
    asm volatile("s_waitcnt lgkmcnt(0)" ::: "memory");
    __builtin_amdgcn_s_setprio(1); MFMA12(1); __builtin_amdgcn_s_setprio(0);
    if (!lst) VM(1);
    __builtin_amdgcn_s_barrier();
    pA[0] += 128; pA[1] += 128;
    pB[0] += 128; pB[1] += 128; pB[2] += 128;
  }
#undef MFMA12
#undef READ_BF
#undef READ_AF
#undef SA1
#undef SB3

  const int cr = (lane >> 4) * 4, cc = lane & 15;
#pragma unroll
  for (int fi = 0; fi < 4; fi++)
#pragma unroll
    for (int fj = 0; fj < 3; fj++) {
      const size_t roff = (size_t)(m0 + (fi * 2 + wr) * 16 + cr) * N + (n0 + (fj * 4 + wc) * 16 + cc);
      if (OUTMODE == 0) {
        float* Cp = (float*)Cv + roff;
#pragma unroll
        for (int r = 0; r < 4; r++) Cp[(size_t)r * N] = acc[fi][fj][r];
      } else {
        u16* Cp = (u16*)Cv + roff;
#pragma unroll
        for (int r = 0; r < 4; r++) Cp[(size_t)r * N] = f2bf(acc[fi][fj][r]);
      }
    }
}

// ------- bf16 GEMM 128^2, chunked XCD swizzle, single-barrier loop (GEMM2) -----
template<int OUTMODE>
__global__ __launch_bounds__(256) void k_gemm_bt(const u16* __restrict__ A, const u16* __restrict__ B,
                                                 void* __restrict__ Cv, int M, int N, int K) {
  __shared__ __align__(16) u16 As[2][128 * 64];
  __shared__ __align__(16) u16 Bs[2][128 * 64];
  const int t = threadIdx.x;
  const int lane = t & 63, w = t >> 6;
  const int nbx = N >> 7;
  const int nwg = nbx * (M >> 7);
  const int cpx = nwg >> 3;
  const int bid = blockIdx.x;
  const int sw = (bid & 7) * cpx + (bid >> 3);
  const int m0 = (sw / nbx) * 128, n0 = (sw % nbx) * 128;
  const int wm = (w >> 1) * 64, wn = (w & 1) * 64;
  const int NT = K >> 6;
  f32x4 acc[4][4] = {};
  const u16* Ap = A + (size_t)m0 * K;
  const u16* Bp = B + (size_t)n0 * K;
  const int cr0 = lane >> 3, cs = lane & 7;

#define GSTAGE(bb, kt_) do { \
    _Pragma("unroll") \
    for (int s2 = 0; s2 < 4; s2++) { \
      int ch = w * 4 + s2; \
      int row = ch * 8 + cr0; \
      int cb = cs ^ (row & 7); \
      GLD((char*)As[bb] + ch * 1024, Ap + (size_t)row * K + (kt_) * 64 + cb * 8); \
      GLD((char*)Bs[bb] + ch * 1024, Bp + (size_t)row * K + (kt_) * 64 + cb * 8); \
    } } while (0)

  GSTAGE(0, 0);
  int cur = 0;
  // single-barrier loop: VM(0) drains exactly stage(i); stage(i+1) after barrier
  // cannot race compute(i-1) readers (they completed before this barrier).
  for (int kt = 0; kt < NT; kt++) {
    VM(0);
    __builtin_amdgcn_s_barrier();
    __builtin_amdgcn_sched_barrier(0);
    if (kt + 1 < NT) GSTAGE(cur ^ 1, kt + 1);
    const u16* asb = As[cur];
    const u16* bsb = Bs[cur];
#pragma unroll
    for (int kk = 0; kk < 2; kk++) {
      bf16x8 af[4], bfr[4];
#pragma unroll
      for (int i = 0; i < 4; i++) {
        int rowa = wm + i * 16 + (lane & 15);
        af[i] = *(const bf16x8*)((const char*)asb + rowa * 128 + ((kk * 64 + (lane >> 4) * 16) ^ ((rowa & 7) << 4)));
        int rowb = wn + i * 16 + (lane & 15);
        bfr[i] = *(const bf16x8*)((const char*)bsb + rowb * 128 + ((kk * 64 + (lane >> 4) * 16) ^ ((rowb & 7) << 4)));
      }
#pragma unroll
      for (int mf = 0; mf < 4; mf++)
#pragma unroll
        for (int nf = 0; nf < 4; nf++)
          acc[mf][nf] = __builtin_amdgcn_mfma_f32_16x16x32_bf16(af[mf], bfr[nf], acc[mf][nf], 0, 0, 0);
    }
    __builtin_amdgcn_sched_barrier(0);
    cur ^= 1;
  }
#undef GSTAGE
  const int cr = (lane >> 4) * 4, cc = lane & 15;
#pragma unroll
  for (int mf = 0; mf < 4; mf++)
#pragma unroll
    for (int nf = 0; nf < 4; nf++) {
      if (OUTMODE == 0) {
        float* Cp = (float*)Cv + (size_t)(m0 + wm + mf * 16 + cr) * N + (n0 + wn + nf * 16 + cc);
#pragma unroll
        for (int r = 0; r < 4; r++) Cp[(size_t)r * N] = acc[mf][nf][r];
      } else {
        u16* Cp = (u16*)Cv + (size_t)(m0 + wm + mf * 16 + cr) * N + (n0 + wn + nf * 16 + cc);
#pragma unroll
        for (int r = 0; r < 4; r++) Cp[(size_t)r * N] = f2bf(acc[mf][nf][r]);
      }
    }
}

// ---- fused: q/k LN+RoPE+split (4096 blocks) | V^T from qkv (4096 blocks) ------
__global__ __launch_bounds__(256) void k_qkv_post(const u16* __restrict__ qkv,
                                                  const float* __restrict__ qw, const float* __restrict__ kw,
                                                  const float* __restrict__ cosb, const float* __restrict__ sinb,
                                                  u16* __restrict__ Q, u16* __restrict__ K, u16* __restrict__ VT) {
  const int bid = blockIdx.x, t = threadIdx.x;
  if (bid < 4096) {
    __shared__ float qs[1024], ks[1024];
    __shared__ float rb[4][4];
    int row = bid;
    int b = row >> 11, l = row & 2047;
    const u16* base = qkv + (size_t)row * 3072;
    ushort4 qu = ((const ushort4*)base)[t];
    ushort4 ku = ((const ushort4*)(base + 1024))[t];
    float qx = bf2f(qu.x), qy = bf2f(qu.y), qz = bf2f(qu.z), qw_ = bf2f(qu.w);
    float kx = bf2f(ku.x), ky = bf2f(ku.y), kz = bf2f(ku.z), kw_ = bf2f(ku.w);
    float red[4];
    red[0] = qx + qy + qz + qw_;
    red[1] = qx * qx + qy * qy + qz * qz + qw_ * qw_;
    red[2] = kx + ky + kz + kw_;
    red[3] = kx * kx + ky * ky + kz * kz + kw_ * kw_;
#pragma unroll
    for (int i = 0; i < 4; i++)
#pragma unroll
      for (int m2 = 1; m2 < 64; m2 <<= 1) red[i] += __shfl_xor(red[i], m2);
    int w = t >> 6;
    if ((t & 63) == 0) { rb[w][0] = red[0]; rb[w][1] = red[1]; rb[w][2] = red[2]; rb[w][3] = red[3]; }
    __syncthreads();
    float S1 = rb[0][0] + rb[1][0] + rb[2][0] + rb[3][0];
    float S2 = rb[0][1] + rb[1][1] + rb[2][1] + rb[3][1];
    float S3 = rb[0][2] + rb[1][2] + rb[2][2] + rb[3][2];
    float S4 = rb[0][3] + rb[1][3] + rb[2][3] + rb[3][3];
    float muq = S1 * (1.0f / DMODEL), rsq = rsqrtf(S2 * (1.0f / DMODEL) - muq * muq + 1e-5f);
    float muk = S3 * (1.0f / DMODEL), rsk = rsqrtf(S4 * (1.0f / DMODEL) - muk * muk + 1e-5f);
    float4 qwv = ((const float4*)qw)[t];
    float4 kwv = ((const float4*)kw)[t];
    qs[t * 4 + 0] = (qx - muq) * rsq * qwv.x;  ks[t * 4 + 0] = (kx - muk) * rsk * kwv.x;
    qs[t * 4 + 1] = (qy - muq) * rsq * qwv.y;  ks[t * 4 + 1] = (ky - muk) * rsk * kwv.y;
    qs[t * 4 + 2] = (qz - muq) * rsq * qwv.z;  ks[t * 4 + 2] = (kz - muk) * rsk * kwv.z;
    qs[t * 4 + 3] = (qw_ - muq) * rsq * qwv.w; ks[t * 4 + 3] = (kw_ - muk) * rsk * kwv.w;
    __syncthreads();
    int d0 = t * 4;
    int hh = d0 >> 6;
    union { ushort4 v4; u16 e[4]; } qo, ko;
#pragma unroll
    for (int i = 0; i < 4; i++) {
      int d = d0 + i, dd = d & 63, fr = dd & 31;
      float c = cosb[l * 32 + fr], s = sinb[l * 32 + fr];
      float q1 = qs[d], q2 = (dd < 32) ? -qs[d + 32] : qs[d - 32];
      float k1 = ks[d], k2 = (dd < 32) ? -ks[d + 32] : ks[d - 32];
      qo.e[i] = f2bf(q1 * c + q2 * s);
      ko.e[i] = f2bf(k1 * c + k2 * s);
    }
    size_t oidx = ((size_t)(b * NHEAD + hh) * LSEQ + l) * DHEAD + (d0 & 63);
    *(ushort4*)(Q + oidx) = qo.v4;
    *(ushort4*)(K + oidx) = ko.v4;
  } else {
    __shared__ u16 vtile[32][33];
    const int rel = bid - 4096;
    const int hd = rel >> 7;
    const int tl = rel & 127;
    const int d0 = (tl & 1) * 32, l0 = (tl >> 1) * 32;
    const int gl = (hd >> 4) * LSEQ;
    const u16* ip = qkv + (size_t)(gl + l0) * 3072 + 2048 + (hd & 15) * 64 + d0;
    u16* op = VT + (size_t)hd * LSEQ * DHEAD + (size_t)d0 * LSEQ + l0;
    int tx = t & 31, ty = t >> 5;
#pragma unroll
    for (int i = 0; i < 32; i += 8)
      vtile[ty + i][tx] = ip[(size_t)(ty + i) * 3072 + tx];
    __syncthreads();
#pragma unroll
    for (int i = 0; i < 32; i += 8)
      op[(size_t)(ty + i) * LSEQ + tx] = vtile[tx][ty + i];
  }
}

// -- segment-masked flash attention: QBLK=128, 8 waves, single-barrier 2-deep ---
__global__ __launch_bounds__(512) void k_attn(const u16* __restrict__ Q, const u16* __restrict__ Kb,
                                              const u16* __restrict__ VTb, const int* __restrict__ seq,
                                              const int* __restrict__ bnd, u16* __restrict__ ctx) {
  __shared__ __align__(16) u16 Ks[2][64 * 64];
  __shared__ __align__(16) u16 Vs[2][64 * 64];
  __shared__ __align__(16) u16 Pw[8][16 * 64];

  const int bid = blockIdx.x;
  const int sw = (bid & 7) * 64 + (bid >> 3);
  const int qt = sw & 15, h = (sw >> 4) & 15, b = sw >> 8;
  const int t = threadIdx.x, l = t & 63, w = t >> 6;
  const int c = l & 15, g = l >> 4;
  const int q0 = qt * 128;
  const size_t hoff = (size_t)(b * NHEAD + h) * LSEQ * DHEAD;
  const u16* Qg = Q + hoff;
  const u16* Kg = Kb + hoff;
  const u16* Vg = VTb + hoff;   // [d][l]
  const int* seqb = seq + b * LSEQ;
  const int* bnd5 = bnd + b * 5;

  const int qw0 = q0 + w * 16;
  const int myq = qw0 + c;
  const int sq = seqb[myq];
  const int lo = bnd5[sq], hi = bnd5[sq + 1];
  const int wlo = bnd5[seqb[qw0]];
  const int whi = bnd5[seqb[qw0 + 15] + 1];
  int kbeg = bnd5[seqb[q0]] & ~63;
  int kend = (bnd5[seqb[q0 + 127] + 1] + 63) & ~63;
  if (kend > LSEQ) kend = LSEQ;

  bf16x8 qf[2];
  qf[0] = *(const bf16x8*)(Qg + (size_t)myq * 64 + g * 8);
  qf[1] = *(const bf16x8*)(Qg + (size_t)myq * 64 + 32 + g * 8);

  f32x4 acc[4] = {};
  float lsum = 0.f;

  const int rr = t >> 3;
  const int szk = ((t & 7) * 8) ^ ((rr & 7) << 3);
  const u16* pK = Kg + (size_t)rr * 64 + szk;
  const u16* pV = Vg + (size_t)rr * LSEQ + szk;

#define STAGE(bb, kt_) do { \
    GLD((char*)Ks[bb] + w * 1024, pK + (size_t)(kt_) * 64); \
    GLD((char*)Vs[bb] + w * 1024, pV + (kt_)); \
  } while (0)

  STAGE(0, kbeg);
  int cur = 0;
  // single-barrier loop: VM(0) drains exactly this tile's 2 loads (next stage
  // not yet issued); stage(next) after the barrier cannot race the previous
  // iteration's readers (they completed before this barrier).
  for (int kt = kbeg; kt < kend; kt += 64) {
    VM(0);
    __builtin_amdgcn_s_barrier();
    __builtin_amdgcn_sched_barrier(0);
    if (kt + 64 < kend) STAGE(cur ^ 1, kt + 64);
    if (kt < whi && kt + 64 > wlo) {
      const u16* ksb = Ks[cur];
      const u16* vsb = Vs[cur];
      f32x4 st[4] = {};
#pragma unroll
      for (int kk = 0; kk < 2; kk++) {
        bf16x8 kf[4];
#pragma unroll
        for (int i = 0; i < 4; i++) {
          int row = i * 16 + c;
          kf[i] = *(const bf16x8*)((const char*)ksb + row * 128 + ((kk * 64 + g * 16) ^ ((row & 7) << 4)));
        }
        __builtin_amdgcn_s_setprio(1);
#pragma unroll
        for (int i = 0; i < 4; i++)
          st[i] = __builtin_amdgcn_mfma_f32_16x16x32_bf16(kf[i], qf[kk], st[i], 0, 0, 0);
        __builtin_amdgcn_s_setprio(0);
      }
      const int kb0 = kt + g * 4;
#pragma unroll
      for (int i = 0; i < 4; i++) {
        float p[4];
#pragma unroll
        for (int r = 0; r < 4; r++) {
          int kglob = kb0 + i * 16 + r;
          bool ok = ((unsigned)(kglob - lo)) < ((unsigned)(hi - lo));
          float x = ok ? fmaf(st[i][r], 0.125f, -8.0f) : -1e30f;
          p[r] = __expf(x);
          lsum += p[r];
        }
        unsigned w0, w1;
        asm("v_cvt_pk_bf16_f32 %0, %1, %2" : "=v"(w0) : "v"(p[0]), "v"(p[1]));
        asm("v_cvt_pk_bf16_f32 %0, %1, %2" : "=v"(w1) : "v"(p[2]), "v"(p[3]));
        uint2 wp; wp.x = w0; wp.y = w1;
        *(uint2*)((char*)Pw[w] + c * 128 + ((i * 32 + g * 8) ^ ((c & 7) << 4))) = wp;
      }
#pragma unroll
      for (int kk = 0; kk < 2; kk++) {
        bf16x8 pa = *(const bf16x8*)((char*)Pw[w] + c * 128 + ((kk * 64 + g * 16) ^ ((c & 7) << 4)));
        bf16x8 vf[4];
#pragma unroll
        for (int df = 0; df < 4; df++) {
          int row = df * 16 + c;
          vf[df] = *(const bf16x8*)((const char*)vsb + row * 128 + ((kk * 64 + g * 16) ^ ((row & 7) << 4)));
        }
        __builtin_amdgcn_s_setprio(1);
#pragma unroll
        for (int df = 0; df < 4; df++)
          acc[df] = __builtin_amdgcn_mfma_f32_16x16x32_bf16(pa, vf[df], acc[df], 0, 0, 0);
        __builtin_amdgcn_s_setprio(0);
      }
    }
    __builtin_amdgcn_sched_barrier(0);
    cur ^= 1;
  }
#undef STAGE

  lsum += __shfl_xor(lsum, 16);
  lsum += __shfl_xor(lsum, 32);
#pragma unroll
  for (int r = 0; r < 4; r++) {
    float lr = __shfl(lsum, g * 4 + r, 64);
    float rls = 1.0f / lr;
    int qrow = qw0 + g * 4 + r;
    u16* op = ctx + (size_t)(b * LSEQ + qrow) * DMODEL + h * 64 + c;
#pragma unroll
    for (int df = 0; df < 4; df++)
      op[df * 16] = f2bf(acc[df][r] * rls);
  }
}

// ---------------- launch --------------------------------------------------------
extern "C" void kernel_launch(void* const* d_in, const int* in_sizes, int n_in,
                              void* d_out, int out_size, void* d_ws, size_t ws_size,
                              hipStream_t stream) {
  const float* x    = (const float*)d_in[0];
  const int*   seq  = (const int*)d_in[1];
  const float* ln1w = (const float*)d_in[2];
  const float* ln1b = (const float*)d_in[3];
  const float* wqkv = (const float*)d_in[4];
  const float* qlnw = (const float*)d_in[5];
  const float* klnw = (const float*)d_in[6];
  const float* wout = (const float*)d_in[7];
  float* out = (float*)d_out;

  char* p = (char*)d_ws;
  u16* wqkvT = (u16*)p;  p += (size_t)3072 * 1024 * 2;
  u16* woutT = (u16*)p;  p += (size_t)1024 * 1024 * 2;
  u16* hbuf  = (u16*)p;  p += (size_t)ROWS * DMODEL * 2;
  u16* Qb    = (u16*)p;  p += (size_t)ROWS * DMODEL * 2;
  u16* Kbuf  = (u16*)p;  p += (size_t)ROWS * DMODEL * 2;
  u16* VTbuf = (u16*)p;  p += (size_t)ROWS * DMODEL * 2;
  u16* ctxb  = (u16*)p;  p += (size_t)ROWS * DMODEL * 2;
  float* cosb = (float*)p; p += (size_t)LSEQ * 32 * 4;
  float* sinb = (float*)p; p += (size_t)LSEQ * 32 * 4;
  int* bnd   = (int*)p;  p += 256;
  u16* qkv   = (u16*)p;  p += (size_t)ROWS * 3072 * 2;

  k_prep<<<8448, 256, 0, stream>>>(x, ln1w, ln1b, hbuf, wqkv, wqkvT, wout, woutT, seq, bnd, cosb, sinb);
  k_gemm256<1><<<(ROWS / 128) * (3072 / 192), 512, 0, stream>>>(hbuf, wqkvT, (void*)qkv, ROWS, 3072, 1024);
  k_qkv_post<<<8192, 256, 0, stream>>>(qkv, qlnw, klnw, cosb, sinb, Qb, Kbuf, VTbuf);
  k_attn<<<BATCH * NHEAD * (LSEQ / 128), 512, 0, stream>>>(Qb, Kbuf, VTbuf, seq, bnd, ctxb);
  k_gemm_bt<0><<<(ROWS / 128) * (1024 / 128), 256, 0, stream>>>(ctxb, woutT, (void*)out, ROWS, 1024, 1024);
}

// Round 16
// 103.283 us; speedup vs baseline: 1.3554x; 1.0302x over previous
//
#include <hip/hip_runtime.h>
#include <hip/hip_bf16.h>
#include <cstdint>
#include <math.h>

#define LSEQ 2048
#define BATCH 2
#define NHEAD 16
#define DHEAD 64
#define DMODEL 1024
#define ROWS (BATCH*LSEQ)

typedef __bf16 bf16x8 __attribute__((ext_vector_type(8)));
typedef float f32x4 __attribute__((ext_vector_type(4)));
typedef unsigned short u16;

#define GLD(lds_base, src_g) \
  __builtin_amdgcn_global_load_lds((const __attribute__((address_space(1))) void*)(src_g), \
                                   (__attribute__((address_space(3))) void*)(lds_base), 16, 0, 0)
#define VM(n) asm volatile("s_waitcnt vmcnt(" #n ")" ::: "memory")

__device__ __forceinline__ u16 f2bf(float f) {
  unsigned int u = __float_as_uint(f);
  u += 0x7fffu + ((u >> 16) & 1u);
  return (u16)(u >> 16);
}
__device__ __forceinline__ float bf2f(u16 u) {
  return __uint_as_float(((unsigned)u) << 16);
}

// ---- fused prep: ln1 (4096) | wqkv^T (3072) | wout^T (1024) | rope+bnd (256) --
__global__ __launch_bounds__(256) void k_prep(const float* __restrict__ x, const float* __restrict__ ln1w,
                                              const float* __restrict__ ln1b, u16* __restrict__ hbuf,
                                              const float* __restrict__ wqkv, u16* __restrict__ wqkvT,
                                              const float* __restrict__ wout, u16* __restrict__ woutT,
                                              const int* __restrict__ seq, int* __restrict__ bnd,
                                              float* __restrict__ cosb, float* __restrict__ sinb) {
  __shared__ float tile[32][33];
  __shared__ float rb[2][4];
  const int bid = blockIdx.x, t = threadIdx.x;
  if (bid < 4096) {
    const int row = bid;
    const float4 xv = ((const float4*)(x + (size_t)row * DMODEL))[t];
    float s = xv.x + xv.y + xv.z + xv.w;
    float s2 = xv.x * xv.x + xv.y * xv.y + xv.z * xv.z + xv.w * xv.w;
#pragma unroll
    for (int m2 = 1; m2 < 64; m2 <<= 1) { s += __shfl_xor(s, m2); s2 += __shfl_xor(s2, m2); }
    int wv = t >> 6;
    if ((t & 63) == 0) { rb[0][wv] = s; rb[1][wv] = s2; }
    __syncthreads();
    s  = rb[0][0] + rb[0][1] + rb[0][2] + rb[0][3];
    s2 = rb[1][0] + rb[1][1] + rb[1][2] + rb[1][3];
    float mu = s * (1.0f / DMODEL);
    float rs = rsqrtf(s2 * (1.0f / DMODEL) - mu * mu + 1e-5f);
    const float4 wv4 = ((const float4*)ln1w)[t];
    const float4 bv4 = ((const float4*)ln1b)[t];
    ushort4 o;
    o.x = f2bf((xv.x - mu) * rs * wv4.x + bv4.x);
    o.y = f2bf((xv.y - mu) * rs * wv4.y + bv4.y);
    o.z = f2bf((xv.z - mu) * rs * wv4.z + bv4.z);
    o.w = f2bf((xv.w - mu) * rs * wv4.w + bv4.w);
    ((ushort4*)(hbuf + (size_t)row * DMODEL))[t] = o;
  } else if (bid < 4096 + 3072 + 1024) {
    const float* in; u16* out; int R, C, bx, by;
    if (bid < 4096 + 3072) { int rel = bid - 4096; in = wqkv; out = wqkvT; R = 1024; C = 3072; bx = rel % 96; by = rel / 96; }
    else                   { int rel = bid - 7168; in = wout; out = woutT; R = 1024; C = 1024; bx = rel % 32; by = rel / 32; }
    int c0 = bx * 32, r0 = by * 32;
    int tx = t & 31, ty = t >> 5;
#pragma unroll
    for (int i = 0; i < 32; i += 8)
      tile[ty + i][tx] = in[(size_t)(r0 + ty + i) * C + (c0 + tx)];
    __syncthreads();
#pragma unroll
    for (int i = 0; i < 32; i += 8)
      out[(size_t)(c0 + ty + i) * R + (r0 + tx)] = f2bf(tile[tx][ty + i]);
  } else {
    const int rel = bid - 8192;
    if (rel == 0 && t < BATCH * 5) {
      int b = t / 5, s = t % 5;
      const int* row = seq + b * LSEQ;
      int lo = 0, hi = LSEQ;
      while (lo < hi) { int mid = (lo + hi) >> 1; if (row[mid] < s) lo = mid + 1; else hi = mid; }
      bnd[b * 5 + s] = lo;
    }
    int idx = rel * 256 + t;
    if (idx < LSEQ * 32) {
      int l = idx >> 5, f = idx & 31;
      double inv = pow(10000.0, -(double)f / 32.0);
      float ang = (float)l * (float)inv;
      cosb[idx] = cosf(ang);
      sinb[idx] = sinf(ang);
    }
  }
}

// ============ 128x192 4-phase GEMM, C = A @ B^T (80 KB LDS -> 2 blocks/CU) =====
template<int OUTMODE>
__global__ __launch_bounds__(512, 4) void k_gemm256(const u16* __restrict__ A, const u16* __restrict__ B,
                                                    void* __restrict__ Cv, int M, int N, int K) {
  __shared__ __align__(16) u16 As[2][128 * 64];
  __shared__ __align__(16) u16 Bs[2][192 * 64];
  const int t = threadIdx.x, lane = t & 63, w = t >> 6;
  const int wr = w >> 2, wc = w & 3;
  const int nbx = N / 192;
  const int nwg = nbx * (M >> 7);
  const int cpx = nwg >> 3;
  const int bid = blockIdx.x;
  const int sw = (bid & 7) * cpx + (bid >> 3);
  const int m0 = (sw / nbx) * 128, n0 = (sw % nbx) * 192;
  const int NT = K >> 6;
  const int cg16 = (lane >> 4) * 16;

  f32x4 acc[4][3] = {};
  bf16x8 af_[2][2], bf_[3][2];
  const u16* Ap = A + (size_t)m0 * K;
  const u16* Bp = B + (size_t)n0 * K;
  const int rr0 = t >> 3;
  const int sz = ((t & 7) * 8) ^ ((rr0 & 7) << 3);
  const u16* pA[2] = { Ap + (size_t)rr0 * K + sz,
                       Ap + (size_t)(rr0 + 64) * K + sz };
  const u16* pB[3] = { Bp + (size_t)rr0 * K + sz,
                       Bp + (size_t)(rr0 + 64) * K + sz,
                       Bp + (size_t)(rr0 + 128) * K + sz };

#define SA1(b, h, EO) GLD((char*)As + (b)*16384 + (h)*8192 + w*1024, pA[h] + (EO))
#define SB3(b, EO) do { \
    GLD((char*)Bs + (b)*24576 +         w*1024, pB[0] + (EO)); \
    GLD((char*)Bs + (b)*24576 +  8192 + w*1024, pB[1] + (EO)); \
    GLD((char*)Bs + (b)*24576 + 16384 + w*1024, pB[2] + (EO)); \
  } while (0)

#define READ_AF(asb, mh) do { \
    _Pragma("unroll") for (int i2 = 0; i2 < 2; i2++) { \
      const int rowA = (((mh)*2 + i2)*2 + wr)*16 + (lane & 15); \
      const int sA = (rowA & 7) << 4; \
      _Pragma("unroll") for (int kk = 0; kk < 2; kk++) \
        af_[i2][kk] = *(const bf16x8*)((const char*)(asb) + (rowA & 63)*128 + ((kk*64 + cg16) ^ sA)); \
    } } while (0)
#define READ_BF(bsb) do { \
    _Pragma("unroll") for (int j2 = 0; j2 < 3; j2++) { \
      const int rowB = (j2*4 + wc)*16 + (lane & 15); \
      const int sB = (rowB & 7) << 4; \
      _Pragma("unroll") for (int kk = 0; kk < 2; kk++) \
        bf_[j2][kk] = *(const bf16x8*)((const char*)(bsb) + rowB*128 + ((kk*64 + cg16) ^ sB)); \
    } } while (0)
#define MFMA12(mh) do { \
    _Pragma("unroll") for (int kk = 0; kk < 2; kk++) \
      _Pragma("unroll") for (int i2 = 0; i2 < 2; i2++) \
        _Pragma("unroll") for (int j2 = 0; j2 < 3; j2++) \
          acc[(mh)*2+i2][j2] = __builtin_amdgcn_mfma_f32_16x16x32_bf16( \
              af_[i2][kk], bf_[j2][kk], acc[(mh)*2+i2][j2], 0, 0, 0); \
  } while (0)

  SA1(0, 0, 0); SA1(0, 1, 0); SB3(0, 0);
  SA1(1, 0, 64);
  VM(1);
  __builtin_amdgcn_s_barrier();

  const char* a0  = (const char*)As;
  const char* a0h = a0 + 8192;
  const char* a1  = a0 + 16384;
  const char* a1h = a0 + 24576;
  const char* b0  = (const char*)Bs;
  const char* b1  = b0 + 24576;
  const int NIT = NT >> 1;
  for (int i = 0; i < NIT; i++) {
    const bool lst = (i == NIT - 1);
    READ_AF(a0, 0); READ_BF(b0);
    SA1(1, 1, 64); SB3(1, 64);
    __builtin_amdgcn_s_barrier();
    asm volatile("s_waitcnt lgkmcnt(0)" ::: "memory");
    __builtin_amdgcn_s_setprio(1); MFMA12(0); __builtin_amdgcn_s_setprio(0);
    __builtin_amdgcn_s_barrier();
    READ_AF(a0h, 1);
    if (!lst) SA1(0, 0, 128);
    __builtin_amdgcn_s_barrier();
    asm volatile("s_waitcnt lgkmcnt(0)" ::: "memory");
    __builtin_amdgcn_s_setprio(1); MFMA12(1); __builtin_amdgcn_s_setprio(0);
    if (lst) VM(0); else VM(1);
    __builtin_amdgcn_s_barrier();
    READ_AF(a1, 0); READ_BF(b1);
    if (!lst) { SA1(0, 1, 128); SB3(0, 128); }
    __builtin_amdgcn_s_barrier();
    asm volatile("s_waitcnt lgkmcnt(0)" ::: "memory");
    __builtin_amdgcn_s_setprio(1); MFMA12(0); __builtin_amdgcn_s_setprio(0);
    __builtin_amdgcn_s_barrier();
    READ_AF(a1h, 1);
    if (!lst) SA1(1, 0, 192);
    __builtin_amdgcn_s_barrier();
    asm volatile("s_waitcnt lgkmcnt(0)" ::: "memory");
    __builtin_amdgcn_s_setprio(1); MFMA12(1); __builtin_amdgcn_s_setprio(0);
    if (!lst) VM(1);
    __builtin_amdgcn_s_barrier();
    pA[0] += 128; pA[1] += 128;
    pB[0] += 128; pB[1] += 128; pB[2] += 128;
  }
#undef MFMA12
#undef READ_BF
#undef READ_AF
#undef SA1
#undef SB3

  const int cr = (lane >> 4) * 4, cc = lane & 15;
#pragma unroll
  for (int fi = 0; fi < 4; fi++)
#pragma unroll
    for (int fj = 0; fj < 3; fj++) {
      const size_t roff = (size_t)(m0 + (fi * 2 + wr) * 16 + cr) * N + (n0 + (fj * 4 + wc) * 16 + cc);
      if (OUTMODE == 0) {
        float* Cp = (float*)Cv + roff;
#pragma unroll
        for (int r = 0; r < 4; r++) Cp[(size_t)r * N] = acc[fi][fj][r];
      } else {
        u16* Cp = (u16*)Cv + roff;
#pragma unroll
        for (int r = 0; r < 4; r++) Cp[(size_t)r * N] = f2bf(acc[fi][fj][r]);
      }
    }
}

// ---- bf16 GEMM 128x64 tile, chunked XCD swizzle, single-barrier loop (GEMM2) --
// grid = (M/128)*(N/64) = 512 blocks -> 2 blocks/CU. 4 waves (2M x 2N), per-wave
// 64x32, acc[4][2]. LDS 48 KB. Same stage/read formulas as proven template.
template<int OUTMODE>
__global__ __launch_bounds__(256) void k_gemm_bt(const u16* __restrict__ A, const u16* __restrict__ B,
                                                 void* __restrict__ Cv, int M, int N, int K) {
  __shared__ __align__(16) u16 As[2][128 * 64];   // 16 KB / buf
  __shared__ __align__(16) u16 Bs[2][64 * 64];    //  8 KB / buf
  const int t = threadIdx.x;
  const int lane = t & 63, w = t >> 6;
  const int nbx = N >> 6;                         // 16
  const int nwg = nbx * (M >> 7);                 // 512
  const int cpx = nwg >> 3;                       // 64
  const int bid = blockIdx.x;
  const int sw = (bid & 7) * cpx + (bid >> 3);    // chunked XCD swizzle (nwg%8==0)
  const int m0 = (sw / nbx) * 128, n0 = (sw % nbx) * 64;
  const int wm = (w >> 1) * 64, wn = (w & 1) * 32;
  const int NT = K >> 6;
  f32x4 acc[4][2] = {};
  const u16* Ap = A + (size_t)m0 * K;
  const u16* Bp = B + (size_t)n0 * K;
  const int cr0 = lane >> 3, cs = lane & 7;

#define GSTAGE(bb, kt_) do { \
    _Pragma("unroll") \
    for (int s2 = 0; s2 < 4; s2++) { \
      int ch = w * 4 + s2; \
      int row = ch * 8 + cr0; \
      int cb = cs ^ (row & 7); \
      GLD((char*)As[bb] + ch * 1024, Ap + (size_t)row * K + (kt_) * 64 + cb * 8); \
    } \
    _Pragma("unroll") \
    for (int s2 = 0; s2 < 2; s2++) { \
      int ch = w * 2 + s2; \
      int row = ch * 8 + cr0; \
      int cb = cs ^ (row & 7); \
      GLD((char*)Bs[bb] + ch * 1024, Bp + (size_t)row * K + (kt_) * 64 + cb * 8); \
    } } while (0)

  GSTAGE(0, 0);
  int cur = 0;
  for (int kt = 0; kt < NT; kt++) {
    VM(0);
    __builtin_amdgcn_s_barrier();
    __builtin_amdgcn_sched_barrier(0);
    if (kt + 1 < NT) GSTAGE(cur ^ 1, kt + 1);
    const u16* asb = As[cur];
    const u16* bsb = Bs[cur];
#pragma unroll
    for (int kk = 0; kk < 2; kk++) {
      bf16x8 af[4], bfr[2];
#pragma unroll
      for (int i = 0; i < 4; i++) {
        int rowa = wm + i * 16 + (lane & 15);
        af[i] = *(const bf16x8*)((const char*)asb + rowa * 128 + ((kk * 64 + (lane >> 4) * 16) ^ ((rowa & 7) << 4)));
      }
#pragma unroll
      for (int j = 0; j < 2; j++) {
        int rowb = wn + j * 16 + (lane & 15);
        bfr[j] = *(const bf16x8*)((const char*)bsb + rowb * 128 + ((kk * 64 + (lane >> 4) * 16) ^ ((rowb & 7) << 4)));
      }
      __builtin_amdgcn_s_setprio(1);
#pragma unroll
      for (int mf = 0; mf < 4; mf++)
#pragma unroll
        for (int nf = 0; nf < 2; nf++)
          acc[mf][nf] = __builtin_amdgcn_mfma_f32_16x16x32_bf16(af[mf], bfr[nf], acc[mf][nf], 0, 0, 0);
      __builtin_amdgcn_s_setprio(0);
    }
    __builtin_amdgcn_sched_barrier(0);
    cur ^= 1;
  }
#undef GSTAGE
  const int cr = (lane >> 4) * 4, cc = lane & 15;
#pragma unroll
  for (int mf = 0; mf < 4; mf++)
#pragma unroll
    for (int nf = 0; nf < 2; nf++) {
      if (OUTMODE == 0) {
        float* Cp = (float*)Cv + (size_t)(m0 + wm + mf * 16 + cr) * N + (n0 + wn + nf * 16 + cc);
#pragma unroll
        for (int r = 0; r < 4; r++) Cp[(size_t)r * N] = acc[mf][nf][r];
      } else {
        u16* Cp = (u16*)Cv + (size_t)(m0 + wm + mf * 16 + cr) * N + (n0 + wn + nf * 16 + cc);
#pragma unroll
        for (int r = 0; r < 4; r++) Cp[(size_t)r * N] = f2bf(acc[mf][nf][r]);
      }
    }
}

// ---- fused: q/k LN+RoPE+split (4096 blocks) | V^T from qkv (4096 blocks) ------
__global__ __launch_bounds__(256) void k_qkv_post(const u16* __restrict__ qkv,
                                                  const float* __restrict__ qw, const float* __restrict__ kw,
                                                  const float* __restrict__ cosb, const float* __restrict__ sinb,
                                                  u16* __restrict__ Q, u16* __restrict__ K, u16* __restrict__ VT) {
  const int bid = blockIdx.x, t = threadIdx.x;
  if (bid < 4096) {
    __shared__ float qs[1024], ks[1024];
    __shared__ float rb[4][4];
    int row = bid;
    int b = row >> 11, l = row & 2047;
    const u16* base = qkv + (size_t)row * 3072;
    ushort4 qu = ((const ushort4*)base)[t];
    ushort4 ku = ((const ushort4*)(base + 1024))[t];
    float qx = bf2f(qu.x), qy = bf2f(qu.y), qz = bf2f(qu.z), qw_ = bf2f(qu.w);
    float kx = bf2f(ku.x), ky = bf2f(ku.y), kz = bf2f(ku.z), kw_ = bf2f(ku.w);
    float red[4];
    red[0] = qx + qy + qz + qw_;
    red[1] = qx * qx + qy * qy + qz * qz + qw_ * qw_;
    red[2] = kx + ky + kz + kw_;
    red[3] = kx * kx + ky * ky + kz * kz + kw_ * kw_;
#pragma unroll
    for (int i = 0; i < 4; i++)
#pragma unroll
      for (int m2 = 1; m2 < 64; m2 <<= 1) red[i] += __shfl_xor(red[i], m2);
    int w = t >> 6;
    if ((t & 63) == 0) { rb[w][0] = red[0]; rb[w][1] = red[1]; rb[w][2] = red[2]; rb[w][3] = red[3]; }
    __syncthreads();
    float S1 = rb[0][0] + rb[1][0] + rb[2][0] + rb[3][0];
    float S2 = rb[0][1] + rb[1][1] + rb[2][1] + rb[3][1];
    float S3 = rb[0][2] + rb[1][2] + rb[2][2] + rb[3][2];
    float S4 = rb[0][3] + rb[1][3] + rb[2][3] + rb[3][3];
    float muq = S1 * (1.0f / DMODEL), rsq = rsqrtf(S2 * (1.0f / DMODEL) - muq * muq + 1e-5f);
    float muk = S3 * (1.0f / DMODEL), rsk = rsqrtf(S4 * (1.0f / DMODEL) - muk * muk + 1e-5f);
    float4 qwv = ((const float4*)qw)[t];
    float4 kwv = ((const float4*)kw)[t];
    qs[t * 4 + 0] = (qx - muq) * rsq * qwv.x;  ks[t * 4 + 0] = (kx - muk) * rsk * kwv.x;
    qs[t * 4 + 1] = (qy - muq) * rsq * qwv.y;  ks[t * 4 + 1] = (ky - muk) * rsk * kwv.y;
    qs[t * 4 + 2] = (qz - muq) * rsq * qwv.z;  ks[t * 4 + 2] = (kz - muk) * rsk * kwv.z;
    qs[t * 4 + 3] = (qw_ - muq) * rsq * qwv.w; ks[t * 4 + 3] = (kw_ - muk) * rsk * kwv.w;
    __syncthreads();
    int d0 = t * 4;
    int hh = d0 >> 6;
    union { ushort4 v4; u16 e[4]; } qo, ko;
#pragma unroll
    for (int i = 0; i < 4; i++) {
      int d = d0 + i, dd = d & 63, fr = dd & 31;
      float c = cosb[l * 32 + fr], s = sinb[l * 32 + fr];
      float q1 = qs[d], q2 = (dd < 32) ? -qs[d + 32] : qs[d - 32];
      float k1 = ks[d], k2 = (dd < 32) ? -ks[d + 32] : ks[d - 32];
      qo.e[i] = f2bf(q1 * c + q2 * s);
      ko.e[i] = f2bf(k1 * c + k2 * s);
    }
    size_t oidx = ((size_t)(b * NHEAD + hh) * LSEQ + l) * DHEAD + (d0 & 63);
    *(ushort4*)(Q + oidx) = qo.v4;
    *(ushort4*)(K + oidx) = ko.v4;
  } else {
    __shared__ u16 vtile[32][33];
    const int rel = bid - 4096;
    const int hd = rel >> 7;
    const int tl = rel & 127;
    const int d0 = (tl & 1) * 32, l0 = (tl >> 1) * 32;
    const int gl = (hd >> 4) * LSEQ;
    const u16* ip = qkv + (size_t)(gl + l0) * 3072 + 2048 + (hd & 15) * 64 + d0;
    u16* op = VT + (size_t)hd * LSEQ * DHEAD + (size_t)d0 * LSEQ + l0;
    int tx = t & 31, ty = t >> 5;
#pragma unroll
    for (int i = 0; i < 32; i += 8)
      vtile[ty + i][tx] = ip[(size_t)(ty + i) * 3072 + tx];
    __syncthreads();
#pragma unroll
    for (int i = 0; i < 32; i += 8)
      op[(size_t)(ty + i) * LSEQ + tx] = vtile[tx][ty + i];
  }
}

// -- segment-masked flash attention: QBLK=128, 8 waves, single-barrier 2-deep ---
__global__ __launch_bounds__(512) void k_attn(const u16* __restrict__ Q, const u16* __restrict__ Kb,
                                              const u16* __restrict__ VTb, const int* __restrict__ seq,
                                              const int* __restrict__ bnd, u16* __restrict__ ctx) {
  __shared__ __align__(16) u16 Ks[2][64 * 64];
  __shared__ __align__(16) u16 Vs[2][64 * 64];
  __shared__ __align__(16) u16 Pw[8][16 * 64];

  const int bid = blockIdx.x;
  const int sw = (bid & 7) * 64 + (bid >> 3);
  const int qt = sw & 15, h = (sw >> 4) & 15, b = sw >> 8;
  const int t = threadIdx.x, l = t & 63, w = t >> 6;
  const int c = l & 15, g = l >> 4;
  const int q0 = qt * 128;
  const size_t hoff = (size_t)(b * NHEAD + h) * LSEQ * DHEAD;
  const u16* Qg = Q + hoff;
  const u16* Kg = Kb + hoff;
  const u16* Vg = VTb + hoff;   // [d][l]
  const int* seqb = seq + b * LSEQ;
  const int* bnd5 = bnd + b * 5;

  const int qw0 = q0 + w * 16;
  const int myq = qw0 + c;
  const int sq = seqb[myq];
  const int lo = bnd5[sq], hi = bnd5[sq + 1];
  const int wlo = bnd5[seqb[qw0]];
  const int whi = bnd5[seqb[qw0 + 15] + 1];
  int kbeg = bnd5[seqb[q0]] & ~63;
  int kend = (bnd5[seqb[q0 + 127] + 1] + 63) & ~63;
  if (kend > LSEQ) kend = LSEQ;

  bf16x8 qf[2];
  qf[0] = *(const bf16x8*)(Qg + (size_t)myq * 64 + g * 8);
  qf[1] = *(const bf16x8*)(Qg + (size_t)myq * 64 + 32 + g * 8);

  f32x4 acc[4] = {};
  float lsum = 0.f;

  const int rr = t >> 3;
  const int szk = ((t & 7) * 8) ^ ((rr & 7) << 3);
  const u16* pK = Kg + (size_t)rr * 64 + szk;
  const u16* pV = Vg + (size_t)rr * LSEQ + szk;

#define STAGE(bb, kt_) do { \
    GLD((char*)Ks[bb] + w * 1024, pK + (size_t)(kt_) * 64); \
    GLD((char*)Vs[bb] + w * 1024, pV + (kt_)); \
  } while (0)

  STAGE(0, kbeg);
  int cur = 0;
  for (int kt = kbeg; kt < kend; kt += 64) {
    VM(0);
    __builtin_amdgcn_s_barrier();
    __builtin_amdgcn_sched_barrier(0);
    if (kt + 64 < kend) STAGE(cur ^ 1, kt + 64);
    if (kt < whi && kt + 64 > wlo) {
      const u16* ksb = Ks[cur];
      const u16* vsb = Vs[cur];
      f32x4 st[4] = {};
#pragma unroll
      for (int kk = 0; kk < 2; kk++) {
        bf16x8 kf[4];
#pragma unroll
        for (int i = 0; i < 4; i++) {
          int row = i * 16 + c;
          kf[i] = *(const bf16x8*)((const char*)ksb + row * 128 + ((kk * 64 + g * 16) ^ ((row & 7) << 4)));
        }
        __builtin_amdgcn_s_setprio(1);
#pragma unroll
        for (int i = 0; i < 4; i++)
          st[i] = __builtin_amdgcn_mfma_f32_16x16x32_bf16(kf[i], qf[kk], st[i], 0, 0, 0);
        __builtin_amdgcn_s_setprio(0);
      }
      const int kb0 = kt + g * 4;
#pragma unroll
      for (int i = 0; i < 4; i++) {
        float p[4];
#pragma unroll
        for (int r = 0; r < 4; r++) {
          int kglob = kb0 + i * 16 + r;
          bool ok = ((unsigned)(kglob - lo)) < ((unsigned)(hi - lo));
          float x = ok ? fmaf(st[i][r], 0.125f, -8.0f) : -1e30f;
          p[r] = __expf(x);
          lsum += p[r];
        }
        unsigned w0, w1;
        asm("v_cvt_pk_bf16_f32 %0, %1, %2" : "=v"(w0) : "v"(p[0]), "v"(p[1]));
        asm("v_cvt_pk_bf16_f32 %0, %1, %2" : "=v"(w1) : "v"(p[2]), "v"(p[3]));
        uint2 wp; wp.x = w0; wp.y = w1;
        *(uint2*)((char*)Pw[w] + c * 128 + ((i * 32 + g * 8) ^ ((c & 7) << 4))) = wp;
      }
#pragma unroll
      for (int kk = 0; kk < 2; kk++) {
        bf16x8 pa = *(const bf16x8*)((char*)Pw[w] + c * 128 + ((kk * 64 + g * 16) ^ ((c & 7) << 4)));
        bf16x8 vf[4];
#pragma unroll
        for (int df = 0; df < 4; df++) {
          int row = df * 16 + c;
          vf[df] = *(const bf16x8*)((const char*)vsb + row * 128 + ((kk * 64 + g * 16) ^ ((row & 7) << 4)));
        }
        __builtin_amdgcn_s_setprio(1);
#pragma unroll
        for (int df = 0; df < 4; df++)
          acc[df] = __builtin_amdgcn_mfma_f32_16x16x32_bf16(pa, vf[df], acc[df], 0, 0, 0);
        __builtin_amdgcn_s_setprio(0);
      }
    }
    __builtin_amdgcn_sched_barrier(0);
    cur ^= 1;
  }
#undef STAGE

  lsum += __shfl_xor(lsum, 16);
  lsum += __shfl_xor(lsum, 32);
#pragma unroll
  for (int r = 0; r < 4; r++) {
    float lr = __shfl(lsum, g * 4 + r, 64);
    float rls = 1.0f / lr;
    int qrow = qw0 + g * 4 + r;
    u16* op = ctx + (size_t)(b * LSEQ + qrow) * DMODEL + h * 64 + c;
#pragma unroll
    for (int df = 0; df < 4; df++)
      op[df * 16] = f2bf(acc[df][r] * rls);
  }
}

// ---------------- launch --------------------------------------------------------
extern "C" void kernel_launch(void* const* d_in, const int* in_sizes, int n_in,
                              void* d_out, int out_size, void* d_ws, size_t ws_size,
                              hipStream_t stream) {
  const float* x    = (const float*)d_in[0];
  const int*   seq  = (const int*)d_in[1];
  const float* ln1w = (const float*)d_in[2];
  const float* ln1b = (const float*)d_in[3];
  const float* wqkv = (const float*)d_in[4];
  const float* qlnw = (const float*)d_in[5];
  const float* klnw = (const float*)d_in[6];
  const float* wout = (const float*)d_in[7];
  float* out = (float*)d_out;

  char* p = (char*)d_ws;
  u16* wqkvT = (u16*)p;  p += (size_t)3072 * 1024 * 2;
  u16* woutT = (u16*)p;  p += (size_t)1024 * 1024 * 2;
  u16* hbuf  = (u16*)p;  p += (size_t)ROWS * DMODEL * 2;
  u16* Qb    = (u16*)p;  p += (size_t)ROWS * DMODEL * 2;
  u16* Kbuf  = (u16*)p;  p += (size_t)ROWS * DMODEL * 2;
  u16* VTbuf = (u16*)p;  p += (size_t)ROWS * DMODEL * 2;
  u16* ctxb  = (u16*)p;  p += (size_t)ROWS * DMODEL * 2;
  float* cosb = (float*)p; p += (size_t)LSEQ * 32 * 4;
  float* sinb = (float*)p; p += (size_t)LSEQ * 32 * 4;
  int* bnd   = (int*)p;  p += 256;
  u16* qkv   = (u16*)p;  p += (size_t)ROWS * 3072 * 2;

  k_prep<<<8448, 256, 0, stream>>>(x, ln1w, ln1b, hbuf, wqkv, wqkvT, wout, woutT, seq, bnd, cosb, sinb);
  k_gemm256<1><<<(ROWS / 128) * (3072 / 192), 512, 0, stream>>>(hbuf, wqkvT, (void*)qkv, ROWS, 3072, 1024);
  k_qkv_post<<<8192, 256, 0, stream>>>(qkv, qlnw, klnw, cosb, sinb, Qb, Kbuf, VTbuf);
  k_attn<<<BATCH * NHEAD * (LSEQ / 128), 512, 0, stream>>>(Qb, Kbuf, VTbuf, seq, bnd, ctxb);
  k_gemm_bt<0><<<(ROWS / 128) * (1024 / 64), 256, 0, stream>>>(ctxb, woutT, (void*)out, ROWS, 1024, 1024);
}

// Round 17
// 101.272 us; speedup vs baseline: 1.3823x; 1.0199x over previous
//
#include <hip/hip_runtime.h>
#include <hip/hip_bf16.h>
#include <cstdint>
#include <math.h>

#define LSEQ 2048
#define BATCH 2
#define NHEAD 16
#define DHEAD 64
#define DMODEL 1024
#define ROWS (BATCH*LSEQ)

typedef __bf16 bf16x8 __attribute__((ext_vector_type(8)));
typedef float f32x4 __attribute__((ext_vector_type(4)));
typedef unsigned short u16;

#define GLD(lds_base, src_g) \
  __builtin_amdgcn_global_load_lds((const __attribute__((address_space(1))) void*)(src_g), \
                                   (__attribute__((address_space(3))) void*)(lds_base), 16, 0, 0)
#define VM(n) asm volatile("s_waitcnt vmcnt(" #n ")" ::: "memory")

__device__ __forceinline__ u16 f2bf(float f) {
  unsigned int u = __float_as_uint(f);
  u += 0x7fffu + ((u >> 16) & 1u);
  return (u16)(u >> 16);
}
__device__ __forceinline__ float bf2f(u16 u) {
  return __uint_as_float(((unsigned)u) << 16);
}

// ---- fused prep: ln1 (4096) | wqkv^T (3072) | wout^T (1024) | rope+bnd (256) --
__global__ __launch_bounds__(256) void k_prep(const float* __restrict__ x, const float* __restrict__ ln1w,
                                              const float* __restrict__ ln1b, u16* __restrict__ hbuf,
                                              const float* __restrict__ wqkv, u16* __restrict__ wqkvT,
                                              const float* __restrict__ wout, u16* __restrict__ woutT,
                                              const int* __restrict__ seq, int* __restrict__ bnd,
                                              float* __restrict__ cosb, float* __restrict__ sinb) {
  __shared__ float tile[32][33];
  __shared__ float rb[2][4];
  const int bid = blockIdx.x, t = threadIdx.x;
  if (bid < 4096) {
    const int row = bid;
    const float4 xv = ((const float4*)(x + (size_t)row * DMODEL))[t];
    float s = xv.x + xv.y + xv.z + xv.w;
    float s2 = xv.x * xv.x + xv.y * xv.y + xv.z * xv.z + xv.w * xv.w;
#pragma unroll
    for (int m2 = 1; m2 < 64; m2 <<= 1) { s += __shfl_xor(s, m2); s2 += __shfl_xor(s2, m2); }
    int wv = t >> 6;
    if ((t & 63) == 0) { rb[0][wv] = s; rb[1][wv] = s2; }
    __syncthreads();
    s  = rb[0][0] + rb[0][1] + rb[0][2] + rb[0][3];
    s2 = rb[1][0] + rb[1][1] + rb[1][2] + rb[1][3];
    float mu = s * (1.0f / DMODEL);
    float rs = rsqrtf(s2 * (1.0f / DMODEL) - mu * mu + 1e-5f);
    const float4 wv4 = ((const float4*)ln1w)[t];
    const float4 bv4 = ((const float4*)ln1b)[t];
    ushort4 o;
    o.x = f2bf((xv.x - mu) * rs * wv4.x + bv4.x);
    o.y = f2bf((xv.y - mu) * rs * wv4.y + bv4.y);
    o.z = f2bf((xv.z - mu) * rs * wv4.z + bv4.z);
    o.w = f2bf((xv.w - mu) * rs * wv4.w + bv4.w);
    ((ushort4*)(hbuf + (size_t)row * DMODEL))[t] = o;
  } else if (bid < 4096 + 3072 + 1024) {
    const float* in; u16* out; int R, C, bx, by;
    if (bid < 4096 + 3072) { int rel = bid - 4096; in = wqkv; out = wqkvT; R = 1024; C = 3072; bx = rel % 96; by = rel / 96; }
    else                   { int rel = bid - 7168; in = wout; out = woutT; R = 1024; C = 1024; bx = rel % 32; by = rel / 32; }
    int c0 = bx * 32, r0 = by * 32;
    int tx = t & 31, ty = t >> 5;
#pragma unroll
    for (int i = 0; i < 32; i += 8)
      tile[ty + i][tx] = in[(size_t)(r0 + ty + i) * C + (c0 + tx)];
    __syncthreads();
#pragma unroll
    for (int i = 0; i < 32; i += 8)
      out[(size_t)(c0 + ty + i) * R + (r0 + tx)] = f2bf(tile[tx][ty + i]);
  } else {
    const int rel = bid - 8192;
    if (rel == 0 && t < BATCH * 5) {
      int b = t / 5, s = t % 5;
      const int* row = seq + b * LSEQ;
      int lo = 0, hi = LSEQ;
      while (lo < hi) { int mid = (lo + hi) >> 1; if (row[mid] < s) lo = mid + 1; else hi = mid; }
      bnd[b * 5 + s] = lo;
    }
    int idx = rel * 256 + t;
    if (idx < LSEQ * 32) {
      int l = idx >> 5, f = idx & 31;
      double inv = pow(10000.0, -(double)f / 32.0);
      float ang = (float)l * (float)inv;
      cosb[idx] = cosf(ang);
      sinb[idx] = sinf(ang);
    }
  }
}

// ============ 128x192 4-phase GEMM, C = A @ B^T (80 KB LDS -> 2 blocks/CU) =====
template<int OUTMODE>
__global__ __launch_bounds__(512, 4) void k_gemm256(const u16* __restrict__ A, const u16* __restrict__ B,
                                                    void* __restrict__ Cv, int M, int N, int K) {
  __shared__ __align__(16) u16 As[2][128 * 64];
  __shared__ __align__(16) u16 Bs[2][192 * 64];
  const int t = threadIdx.x, lane = t & 63, w = t >> 6;
  const int wr = w >> 2, wc = w & 3;
  const int nbx = N / 192;
  const int nwg = nbx * (M >> 7);
  const int cpx = nwg >> 3;
  const int bid = blockIdx.x;
  const int sw = (bid & 7) * cpx + (bid >> 3);
  const int m0 = (sw / nbx) * 128, n0 = (sw % nbx) * 192;
  const int NT = K >> 6;
  const int cg16 = (lane >> 4) * 16;

  f32x4 acc[4][3] = {};
  bf16x8 af_[2][2], bf_[3][2];
  const u16* Ap = A + (size_t)m0 * K;
  const u16* Bp = B + (size_t)n0 * K;
  const int rr0 = t >> 3;
  const int sz = ((t & 7) * 8) ^ ((rr0 & 7) << 3);
  const u16* pA[2] = { Ap + (size_t)rr0 * K + sz,
                       Ap + (size_t)(rr0 + 64) * K + sz };
  const u16* pB[3] = { Bp + (size_t)rr0 * K + sz,
                       Bp + (size_t)(rr0 + 64) * K + sz,
                       Bp + (size_t)(rr0 + 128) * K + sz };

#define SA1(b, h, EO) GLD((char*)As + (b)*16384 + (h)*8192 + w*1024, pA[h] + (EO))
#define SB3(b, EO) do { \
    GLD((char*)Bs + (b)*24576 +         w*1024, pB[0] + (EO)); \
    GLD((char*)Bs + (b)*24576 +  8192 + w*1024, pB[1] + (EO)); \
    GLD((char*)Bs + (b)*24576 + 16384 + w*1024, pB[2] + (EO)); \
  } while (0)

#define READ_AF(asb, mh) do { \
    _Pragma("unroll") for (int i2 = 0; i2 < 2; i2++) { \
      const int rowA = (((mh)*2 + i2)*2 + wr)*16 + (lane & 15); \
      const int sA = (rowA & 7) << 4; \
      _Pragma("unroll") for (int kk = 0; kk < 2; kk++) \
        af_[i2][kk] = *(const bf16x8*)((const char*)(asb) + (rowA & 63)*128 + ((kk*64 + cg16) ^ sA)); \
    } } while (0)
#define READ_BF(bsb) do { \
    _Pragma("unroll") for (int j2 = 0; j2 < 3; j2++) { \
      const int rowB = (j2*4 + wc)*16 + (lane & 15); \
      const int sB = (rowB & 7) << 4; \
      _Pragma("unroll") for (int kk = 0; kk < 2; kk++) \
        bf_[j2][kk] = *(const bf16x8*)((const char*)(bsb) + rowB*128 + ((kk*64 + cg16) ^ sB)); \
    } } while (0)
#define MFMA12(mh) do { \
    _Pragma("unroll") for (int kk = 0; kk < 2; kk++) \
      _Pragma("unroll") for (int i2 = 0; i2 < 2; i2++) \
        _Pragma("unroll") for (int j2 = 0; j2 < 3; j2++) \
          acc[(mh)*2+i2][j2] = __builtin_amdgcn_mfma_f32_16x16x32_bf16( \
              af_[i2][kk], bf_[j2][kk], acc[(mh)*2+i2][j2], 0, 0, 0); \
  } while (0)

  SA1(0, 0, 0); SA1(0, 1, 0); SB3(0, 0);
  SA1(1, 0, 64);
  VM(1);
  __builtin_amdgcn_s_barrier();

  const char* a0  = (const char*)As;
  const char* a0h = a0 + 8192;
  const char* a1  = a0 + 16384;
  const char* a1h = a0 + 24576;
  const char* b0  = (const char*)Bs;
  const char* b1  = b0 + 24576;
  const int NIT = NT >> 1;
  for (int i = 0; i < NIT; i++) {
    const bool lst = (i == NIT - 1);
    READ_AF(a0, 0); READ_BF(b0);
    SA1(1, 1, 64); SB3(1, 64);
    __builtin_amdgcn_s_barrier();
    asm volatile("s_waitcnt lgkmcnt(0)" ::: "memory");
    __builtin_amdgcn_s_setprio(1); MFMA12(0); __builtin_amdgcn_s_setprio(0);
    __builtin_amdgcn_s_barrier();
    READ_AF(a0h, 1);
    if (!lst) SA1(0, 0, 128);
    __builtin_amdgcn_s_barrier();
    asm volatile("s_waitcnt lgkmcnt(0)" ::: "memory");
    __builtin_amdgcn_s_setprio(1); MFMA12(1); __builtin_amdgcn_s_setprio(0);
    if (lst) VM(0); else VM(1);
    __builtin_amdgcn_s_barrier();
    READ_AF(a1, 0); READ_BF(b1);
    if (!lst) { SA1(0, 1, 128); SB3(0, 128); }
    __builtin_amdgcn_s_barrier();
    asm volatile("s_waitcnt lgkmcnt(0)" ::: "memory");
    __builtin_amdgcn_s_setprio(1); MFMA12(0); __builtin_amdgcn_s_setprio(0);
    __builtin_amdgcn_s_barrier();
    READ_AF(a1h, 1);
    if (!lst) SA1(1, 0, 192);
    __builtin_amdgcn_s_barrier();
    asm volatile("s_waitcnt lgkmcnt(0)" ::: "memory");
    __builtin_amdgcn_s_setprio(1); MFMA12(1); __builtin_amdgcn_s_setprio(0);
    if (!lst) VM(1);
    __builtin_amdgcn_s_barrier();
    pA[0] += 128; pA[1] += 128;
    pB[0] += 128; pB[1] += 128; pB[2] += 128;
  }
#undef MFMA12
#undef READ_BF
#undef READ_AF
#undef SA1
#undef SB3

  const int cr = (lane >> 4) * 4, cc = lane & 15;
#pragma unroll
  for (int fi = 0; fi < 4; fi++)
#pragma unroll
    for (int fj = 0; fj < 3; fj++) {
      const size_t roff = (size_t)(m0 + (fi * 2 + wr) * 16 + cr) * N + (n0 + (fj * 4 + wc) * 16 + cc);
      if (OUTMODE == 0) {
        float* Cp = (float*)Cv + roff;
#pragma unroll
        for (int r = 0; r < 4; r++) Cp[(size_t)r * N] = acc[fi][fj][r];
      } else {
        u16* Cp = (u16*)Cv + roff;
#pragma unroll
        for (int r = 0; r < 4; r++) Cp[(size_t)r * N] = f2bf(acc[fi][fj][r]);
      }
    }
}

// ---- bf16 GEMM 128x64 tile, chunked XCD swizzle, single-barrier loop (GEMM2) --
template<int OUTMODE>
__global__ __launch_bounds__(256) void k_gemm_bt(const u16* __restrict__ A, const u16* __restrict__ B,
                                                 void* __restrict__ Cv, int M, int N, int K) {
  __shared__ __align__(16) u16 As[2][128 * 64];
  __shared__ __align__(16) u16 Bs[2][64 * 64];
  const int t = threadIdx.x;
  const int lane = t & 63, w = t >> 6;
  const int nbx = N >> 6;
  const int nwg = nbx * (M >> 7);
  const int cpx = nwg >> 3;
  const int bid = blockIdx.x;
  const int sw = (bid & 7) * cpx + (bid >> 3);
  const int m0 = (sw / nbx) * 128, n0 = (sw % nbx) * 64;
  const int wm = (w >> 1) * 64, wn = (w & 1) * 32;
  const int NT = K >> 6;
  f32x4 acc[4][2] = {};
  const u16* Ap = A + (size_t)m0 * K;
  const u16* Bp = B + (size_t)n0 * K;
  const int cr0 = lane >> 3, cs = lane & 7;

#define GSTAGE(bb, kt_) do { \
    _Pragma("unroll") \
    for (int s2 = 0; s2 < 4; s2++) { \
      int ch = w * 4 + s2; \
      int row = ch * 8 + cr0; \
      int cb = cs ^ (row & 7); \
      GLD((char*)As[bb] + ch * 1024, Ap + (size_t)row * K + (kt_) * 64 + cb * 8); \
    } \
    _Pragma("unroll") \
    for (int s2 = 0; s2 < 2; s2++) { \
      int ch = w * 2 + s2; \
      int row = ch * 8 + cr0; \
      int cb = cs ^ (row & 7); \
      GLD((char*)Bs[bb] + ch * 1024, Bp + (size_t)row * K + (kt_) * 64 + cb * 8); \
    } } while (0)

  GSTAGE(0, 0);
  int cur = 0;
  for (int kt = 0; kt < NT; kt++) {
    VM(0);
    __builtin_amdgcn_s_barrier();
    __builtin_amdgcn_sched_barrier(0);
    if (kt + 1 < NT) GSTAGE(cur ^ 1, kt + 1);
    const u16* asb = As[cur];
    const u16* bsb = Bs[cur];
#pragma unroll
    for (int kk = 0; kk < 2; kk++) {
      bf16x8 af[4], bfr[2];
#pragma unroll
      for (int i = 0; i < 4; i++) {
        int rowa = wm + i * 16 + (lane & 15);
        af[i] = *(const bf16x8*)((const char*)asb + rowa * 128 + ((kk * 64 + (lane >> 4) * 16) ^ ((rowa & 7) << 4)));
      }
#pragma unroll
      for (int j = 0; j < 2; j++) {
        int rowb = wn + j * 16 + (lane & 15);
        bfr[j] = *(const bf16x8*)((const char*)bsb + rowb * 128 + ((kk * 64 + (lane >> 4) * 16) ^ ((rowb & 7) << 4)));
      }
      __builtin_amdgcn_s_setprio(1);
#pragma unroll
      for (int mf = 0; mf < 4; mf++)
#pragma unroll
        for (int nf = 0; nf < 2; nf++)
          acc[mf][nf] = __builtin_amdgcn_mfma_f32_16x16x32_bf16(af[mf], bfr[nf], acc[mf][nf], 0, 0, 0);
      __builtin_amdgcn_s_setprio(0);
    }
    __builtin_amdgcn_sched_barrier(0);
    cur ^= 1;
  }
#undef GSTAGE
  const int cr = (lane >> 4) * 4, cc = lane & 15;
#pragma unroll
  for (int mf = 0; mf < 4; mf++)
#pragma unroll
    for (int nf = 0; nf < 2; nf++) {
      if (OUTMODE == 0) {
        float* Cp = (float*)Cv + (size_t)(m0 + wm + mf * 16 + cr) * N + (n0 + wn + nf * 16 + cc);
#pragma unroll
        for (int r = 0; r < 4; r++) Cp[(size_t)r * N] = acc[mf][nf][r];
      } else {
        u16* Cp = (u16*)Cv + (size_t)(m0 + wm + mf * 16 + cr) * N + (n0 + wn + nf * 16 + cc);
#pragma unroll
        for (int r = 0; r < 4; r++) Cp[(size_t)r * N] = f2bf(acc[mf][nf][r]);
      }
    }
}

// ---- fused: q/k LN+RoPE+split (4096 blocks, shfl-based) | V^T (4096 blocks) ---
__global__ __launch_bounds__(256) void k_qkv_post(const u16* __restrict__ qkv,
                                                  const float* __restrict__ qw, const float* __restrict__ kw,
                                                  const float* __restrict__ cosb, const float* __restrict__ sinb,
                                                  u16* __restrict__ Q, u16* __restrict__ K, u16* __restrict__ VT) {
  const int bid = blockIdx.x, t = threadIdx.x;
  if (bid < 4096) {
    __shared__ float rb[4][4];
    int row = bid;
    int b = row >> 11, l = row & 2047;
    const u16* base = qkv + (size_t)row * 3072;
    ushort4 qu = ((const ushort4*)base)[t];
    ushort4 ku = ((const ushort4*)(base + 1024))[t];
    float qx = bf2f(qu.x), qy = bf2f(qu.y), qz = bf2f(qu.z), qw_ = bf2f(qu.w);
    float kx = bf2f(ku.x), ky = bf2f(ku.y), kz = bf2f(ku.z), kw_ = bf2f(ku.w);
    float red[4];
    red[0] = qx + qy + qz + qw_;
    red[1] = qx * qx + qy * qy + qz * qz + qw_ * qw_;
    red[2] = kx + ky + kz + kw_;
    red[3] = kx * kx + ky * ky + kz * kz + kw_ * kw_;
#pragma unroll
    for (int i = 0; i < 4; i++)
#pragma unroll
      for (int m2 = 1; m2 < 64; m2 <<= 1) red[i] += __shfl_xor(red[i], m2);
    int w = t >> 6;
    if ((t & 63) == 0) { rb[w][0] = red[0]; rb[w][1] = red[1]; rb[w][2] = red[2]; rb[w][3] = red[3]; }
    __syncthreads();
    float S1 = rb[0][0] + rb[1][0] + rb[2][0] + rb[3][0];
    float S2 = rb[0][1] + rb[1][1] + rb[2][1] + rb[3][1];
    float S3 = rb[0][2] + rb[1][2] + rb[2][2] + rb[3][2];
    float S4 = rb[0][3] + rb[1][3] + rb[2][3] + rb[3][3];
    float muq = S1 * (1.0f / DMODEL), rsq = rsqrtf(S2 * (1.0f / DMODEL) - muq * muq + 1e-5f);
    float muk = S3 * (1.0f / DMODEL), rsk = rsqrtf(S4 * (1.0f / DMODEL) - muk * muk + 1e-5f);
    float4 qwv = ((const float4*)qw)[t];
    float4 kwv = ((const float4*)kw)[t];
    float qn[4], kn[4];
    qn[0] = (qx - muq) * rsq * qwv.x;  kn[0] = (kx - muk) * rsk * kwv.x;
    qn[1] = (qy - muq) * rsq * qwv.y;  kn[1] = (ky - muk) * rsk * kwv.y;
    qn[2] = (qz - muq) * rsq * qwv.z;  kn[2] = (kz - muk) * rsk * kwv.z;
    qn[3] = (qw_ - muq) * rsq * qwv.w; kn[3] = (kw_ - muk) * rsk * kwv.w;
    // rotate-half partner lives at lane t^8 (same wave: 16-thread head group);
    // sign: dd<32 (t&8==0) -> -partner, dd>=32 -> +partner. cos/sin idx fr = dd&31.
    const float sgn = (t & 8) ? 1.0f : -1.0f;
    int d0 = t * 4;
    int hh = d0 >> 6;
    union { ushort4 v4; u16 e[4]; } qo, ko;
#pragma unroll
    for (int i = 0; i < 4; i++) {
      int fr = (t & 7) * 4 + i;
      float c = cosb[l * 32 + fr], s = sinb[l * 32 + fr];
      float q2 = sgn * __shfl_xor(qn[i], 8);
      float k2 = sgn * __shfl_xor(kn[i], 8);
      qo.e[i] = f2bf(qn[i] * c + q2 * s);
      ko.e[i] = f2bf(kn[i] * c + k2 * s);
    }
    size_t oidx = ((size_t)(b * NHEAD + hh) * LSEQ + l) * DHEAD + (d0 & 63);
    *(ushort4*)(Q + oidx) = qo.v4;
    *(ushort4*)(K + oidx) = ko.v4;
  } else {
    __shared__ u16 vtile[32][33];
    const int rel = bid - 4096;
    const int hd = rel >> 7;
    const int tl = rel & 127;
    const int d0 = (tl & 1) * 32, l0 = (tl >> 1) * 32;
    const int gl = (hd >> 4) * LSEQ;
    const u16* ip = qkv + (size_t)(gl + l0) * 3072 + 2048 + (hd & 15) * 64 + d0;
    u16* op = VT + (size_t)hd * LSEQ * DHEAD + (size_t)d0 * LSEQ + l0;
    int tx = t & 31, ty = t >> 5;
#pragma unroll
    for (int i = 0; i < 32; i += 8)
      vtile[ty + i][tx] = ip[(size_t)(ty + i) * 3072 + tx];
    __syncthreads();
#pragma unroll
    for (int i = 0; i < 32; i += 8)
      op[(size_t)(ty + i) * LSEQ + tx] = vtile[tx][ty + i];
  }
}

// -- segment-masked flash attention: QBLK=128, 8 waves, single-barrier 2-deep ---
__global__ __launch_bounds__(512) void k_attn(const u16* __restrict__ Q, const u16* __restrict__ Kb,
                                              const u16* __restrict__ VTb, const int* __restrict__ seq,
                                              const int* __restrict__ bnd, u16* __restrict__ ctx) {
  __shared__ __align__(16) u16 Ks[2][64 * 64];
  __shared__ __align__(16) u16 Vs[2][64 * 64];
  __shared__ __align__(16) u16 Pw[8][16 * 64];

  const int bid = blockIdx.x;
  const int sw = (bid & 7) * 64 + (bid >> 3);
  const int qt = sw & 15, h = (sw >> 4) & 15, b = sw >> 8;
  const int t = threadIdx.x, l = t & 63, w = t >> 6;
  const int c = l & 15, g = l >> 4;
  const int q0 = qt * 128;
  const size_t hoff = (size_t)(b * NHEAD + h) * LSEQ * DHEAD;
  const u16* Qg = Q + hoff;
  const u16* Kg = Kb + hoff;
  const u16* Vg = VTb + hoff;   // [d][l]
  const int* seqb = seq + b * LSEQ;
  const int* bnd5 = bnd + b * 5;

  const int qw0 = q0 + w * 16;
  const int myq = qw0 + c;
  const int sq = seqb[myq];
  const int lo = bnd5[sq], hi = bnd5[sq + 1];
  const int wlo = bnd5[seqb[qw0]];
  const int whi = bnd5[seqb[qw0 + 15] + 1];
  int kbeg = bnd5[seqb[q0]] & ~63;
  int kend = (bnd5[seqb[q0 + 127] + 1] + 63) & ~63;
  if (kend > LSEQ) kend = LSEQ;

  bf16x8 qf[2];
  qf[0] = *(const bf16x8*)(Qg + (size_t)myq * 64 + g * 8);
  qf[1] = *(const bf16x8*)(Qg + (size_t)myq * 64 + 32 + g * 8);

  f32x4 acc[4] = {};
  float lsum = 0.f;

  const int rr = t >> 3;
  const int szk = ((t & 7) * 8) ^ ((rr & 7) << 3);
  const u16* pK = Kg + (size_t)rr * 64 + szk;
  const u16* pV = Vg + (size_t)rr * LSEQ + szk;

#define STAGE(bb, kt_) do { \
    GLD((char*)Ks[bb] + w * 1024, pK + (size_t)(kt_) * 64); \
    GLD((char*)Vs[bb] + w * 1024, pV + (kt_)); \
  } while (0)

  STAGE(0, kbeg);
  int cur = 0;
  for (int kt = kbeg; kt < kend; kt += 64) {
    VM(0);
    __builtin_amdgcn_s_barrier();
    __builtin_amdgcn_sched_barrier(0);
    if (kt + 64 < kend) STAGE(cur ^ 1, kt + 64);
    if (kt < whi && kt + 64 > wlo) {
      const u16* ksb = Ks[cur];
      const u16* vsb = Vs[cur];
      f32x4 st[4] = {};
#pragma unroll
      for (int kk = 0; kk < 2; kk++) {
        bf16x8 kf[4];
#pragma unroll
        for (int i = 0; i < 4; i++) {
          int row = i * 16 + c;
          kf[i] = *(const bf16x8*)((const char*)ksb + row * 128 + ((kk * 64 + g * 16) ^ ((row & 7) << 4)));
        }
        __builtin_amdgcn_s_setprio(1);
#pragma unroll
        for (int i = 0; i < 4; i++)
          st[i] = __builtin_amdgcn_mfma_f32_16x16x32_bf16(kf[i], qf[kk], st[i], 0, 0, 0);
        __builtin_amdgcn_s_setprio(0);
      }
      const int kb0 = kt + g * 4;
#pragma unroll
      for (int i = 0; i < 4; i++) {
        float p[4];
#pragma unroll
        for (int r = 0; r < 4; r++) {
          int kglob = kb0 + i * 16 + r;
          bool ok = ((unsigned)(kglob - lo)) < ((unsigned)(hi - lo));
          float x = ok ? fmaf(st[i][r], 0.125f, -8.0f) : -1e30f;
          p[r] = __expf(x);
          lsum += p[r];
        }
        unsigned w0, w1;
        asm("v_cvt_pk_bf16_f32 %0, %1, %2" : "=v"(w0) : "v"(p[0]), "v"(p[1]));
        asm("v_cvt_pk_bf16_f32 %0, %1, %2" : "=v"(w1) : "v"(p[2]), "v"(p[3]));
        uint2 wp; wp.x = w0; wp.y = w1;
        *(uint2*)((char*)Pw[w] + c * 128 + ((i * 32 + g * 8) ^ ((c & 7) << 4))) = wp;
      }
#pragma unroll
      for (int kk = 0; kk < 2; kk++) {
        bf16x8 pa = *(const bf16x8*)((char*)Pw[w] + c * 128 + ((kk * 64 + g * 16) ^ ((c & 7) << 4)));
        bf16x8 vf[4];
#pragma unroll
        for (int df = 0; df < 4; df++) {
          int row = df * 16 + c;
          vf[df] = *(const bf16x8*)((const char*)vsb + row * 128 + ((kk * 64 + g * 16) ^ ((row & 7) << 4)));
        }
        __builtin_amdgcn_s_setprio(1);
#pragma unroll
        for (int df = 0; df < 4; df++)
          acc[df] = __builtin_amdgcn_mfma_f32_16x16x32_bf16(pa, vf[df], acc[df], 0, 0, 0);
        __builtin_amdgcn_s_setprio(0);
      }
    }
    __builtin_amdgcn_sched_barrier(0);
    cur ^= 1;
  }
#undef STAGE

  lsum += __shfl_xor(lsum, 16);
  lsum += __shfl_xor(lsum, 32);
#pragma unroll
  for (int r = 0; r < 4; r++) {
    float lr = __shfl(lsum, g * 4 + r, 64);
    float rls = 1.0f / lr;
    int qrow = qw0 + g * 4 + r;
    u16* op = ctx + (size_t)(b * LSEQ + qrow) * DMODEL + h * 64 + c;
#pragma unroll
    for (int df = 0; df < 4; df++)
      op[df * 16] = f2bf(acc[df][r] * rls);
  }
}

// ---------------- launch --------------------------------------------------------
extern "C" void kernel_launch(void* const* d_in, const int* in_sizes, int n_in,
                              void* d_out, int out_size, void* d_ws, size_t ws_size,
                              hipStream_t stream) {
  const float* x    = (const float*)d_in[0];
  const int*   seq  = (const int*)d_in[1];
  const float* ln1w = (const float*)d_in[2];
  const float* ln1b = (const float*)d_in[3];
  const float* wqkv = (const float*)d_in[4];
  const float* qlnw = (const float*)d_in[5];
  const float* klnw = (const float*)d_in[6];
  const float* wout = (const float*)d_in[7];
  float* out = (float*)d_out;

  char* p = (char*)d_ws;
  u16* wqkvT = (u16*)p;  p += (size_t)3072 * 1024 * 2;
  u16* woutT = (u16*)p;  p += (size_t)1024 * 1024 * 2;
  u16* hbuf  = (u16*)p;  p += (size_t)ROWS * DMODEL * 2;
  u16* Qb    = (u16*)p;  p += (size_t)ROWS * DMODEL * 2;
  u16* Kbuf  = (u16*)p;  p += (size_t)ROWS * DMODEL * 2;
  u16* VTbuf = (u16*)p;  p += (size_t)ROWS * DMODEL * 2;
  u16* ctxb  = (u16*)p;  p += (size_t)ROWS * DMODEL * 2;
  float* cosb = (float*)p; p += (size_t)LSEQ * 32 * 4;
  float* sinb = (float*)p; p += (size_t)LSEQ * 32 * 4;
  int* bnd   = (int*)p;  p += 256;
  u16* qkv   = (u16*)p;  p += (size_t)ROWS * 3072 * 2;

  k_prep<<<8448, 256, 0, stream>>>(x, ln1w, ln1b, hbuf, wqkv, wqkvT, wout, woutT, seq, bnd, cosb, sinb);
  k_gemm256<1><<<(ROWS / 128) * (3072 / 192), 512, 0, stream>>>(hbuf, wqkvT, (void*)qkv, ROWS, 3072, 1024);
  k_qkv_post<<<8192, 256, 0, stream>>>(qkv, qlnw, klnw, cosb, sinb, Qb, Kbuf, VTbuf);
  k_attn<<<BATCH * NHEAD * (LSEQ / 128), 512, 0, stream>>>(Qb, Kbuf, VTbuf, seq, bnd, ctxb);
  k_gemm_bt<0><<<(ROWS / 128) * (1024 / 64), 256, 0, stream>>>(ctxb, woutT, (void*)out, ROWS, 1024, 1024);
}